// Round 2
// baseline (691.493 us; speedup 1.0000x reference)
//
#include <hip/hip_runtime.h>
#include <hip/hip_bf16.h>
#include <math.h>

#define NNODES 20000
#define NEDGES 320000
#define HDIM   128
#define INDIM  256
#define INV_SCALE (1.0f/30.0f)
#define LN_EPS 1e-5f

typedef __bf16 bf16x8 __attribute__((ext_vector_type(8)));
typedef float  f32x4  __attribute__((ext_vector_type(4)));
typedef _Float16 half4_t __attribute__((ext_vector_type(4)));
typedef _Float16 half8_t __attribute__((ext_vector_type(8)));
typedef unsigned short ushort_t;

__device__ __forceinline__ unsigned short f2bf(float f) {
    union { __hip_bfloat16 h; unsigned short u; } c;
    c.h = __float2bfloat16(f);
    return c.u;
}

// Fast gelu: x * sigmoid(1.5957691*x + 0.0713548*x^3)  (tanh-form, max |err| ~1e-3)
__device__ __forceinline__ float gelu_fast(float x) {
    const float z = x * (1.595769122f + 0.071354816f * x * x);
    return x / (1.0f + __expf(-z));
}

__device__ __forceinline__ f32x4 mfma_bf16(bf16x8 a, bf16x8 b, f32x4 c) {
    return __builtin_amdgcn_mfma_f32_16x16x32_bf16(a, b, c, 0, 0, 0);
}

// ---------------------------------------------------------------------------
// Weight prep. B-fragment order for mfma_f32_16x16x32_bf16: frag (s,t), lane L,
// elem j holds W[k = s*32 + (L>>4)*8 + j][n = t*16 + (L&15)]; each lane's 8 bf16
// are contiguous (one 16B load). Fragment f stored at Wsw[(f*64 + L)*8 + j].
// Edge weights: W1 f=s*8+t (base 0), W2 (base 32768), W3 (base 49152).
//
// W3 SPECIAL: output columns PERMUTED so the message store (and the tier-2
// packed-fp16 atomic scatter) pack adjacent column pairs per lane:
// fragment col (t,l16) -> actual col n3 = 2*((t&3)*16 + l16) + (t>>2).
// Acc pair (t, t+4) = actual cols (2*(t*16+l16), 2*(t*16+l16)+1).
// ---------------------------------------------------------------------------
__global__ void prep_edge_weights(const float* __restrict__ W1,
                                  const float* __restrict__ W2,
                                  const float* __restrict__ W3,
                                  ushort_t* __restrict__ Wsw) {
    const int id = blockIdx.x * 256 + threadIdx.x;   // 0..65535
    const float* W; int base, idx; bool perm = false;
    if (id < 32768)      { W = W1; base = 0;     idx = id; }
    else if (id < 49152) { W = W2; base = 32768; idx = id - 32768; }
    else                 { W = W3; base = 49152; idx = id - 49152; perm = true; }
    const int j = idx & 7, lane = (idx >> 3) & 63, t = (idx >> 9) & 7, s = idx >> 12;
    const int k = s * 32 + (lane >> 4) * 8 + j;
    const int n = perm ? (2 * ((t & 3) * 16 + (lane & 15)) + (t >> 2))
                       : (t * 16 + (lane & 15));
    Wsw[base + idx] = f2bf(W[k * HDIM + n]);
}

// Node weights: D1 (128x512): f = s*32+t (s<4, t<32). D2 (512x128): f = s*8+t (s<16, t<8).
__global__ void prep_node_weights(const float* __restrict__ D1,
                                  const float* __restrict__ D2,
                                  ushort_t* __restrict__ D1sw,
                                  ushort_t* __restrict__ D2sw) {
    const int id = blockIdx.x * 256 + threadIdx.x;   // 0..131071
    if (id < 65536) {
        const int idx = id;
        const int j = idx & 7, lane = (idx >> 3) & 63, f = idx >> 9;   // f = s*32+t
        const int t = f & 31, s = f >> 5;
        const int k = s * 32 + (lane >> 4) * 8 + j;
        const int n = t * 16 + (lane & 15);
        D1sw[idx] = f2bf(D1[k * 512 + n]);
    } else {
        const int idx = id - 65536;
        const int j = idx & 7, lane = (idx >> 3) & 63, f = idx >> 9;   // f = s*8+t
        const int t = f & 7, s = f >> 3;
        const int k = s * 32 + (lane >> 4) * 8 + j;
        const int n = t * 16 + (lane & 15);
        D2sw[idx] = f2bf(D2[k * HDIM + n]);
    }
}

// ---------------------------------------------------------------------------
// Counting sort of edges by source node (CSR build).
// ---------------------------------------------------------------------------
__global__ void edge_hist(const int* __restrict__ src, int* __restrict__ cnt) {
    const int e = blockIdx.x * 256 + threadIdx.x;
    if (e < NEDGES) atomicAdd(&cnt[src[e]], 1);
}

__launch_bounds__(1024)
__global__ void scan_counts(const int* __restrict__ cnt,
                            int* __restrict__ off, int* __restrict__ off2) {
    __shared__ int tot[1024];
    const int t = threadIdx.x;
    const int base = t * 20;                 // 1024*20 = 20480 >= NNODES
    int local[20]; int s = 0;
    #pragma unroll
    for (int i = 0; i < 20; ++i) {
        const int v = (base + i < NNODES) ? cnt[base + i] : 0;
        local[i] = s; s += v;
    }
    tot[t] = s;
    __syncthreads();
    for (int d = 1; d < 1024; d <<= 1) {
        const int v = (t >= d) ? tot[t - d] : 0;
        __syncthreads();
        tot[t] += v;
        __syncthreads();
    }
    const int excl = (t == 0) ? 0 : tot[t - 1];
    #pragma unroll
    for (int i = 0; i < 20; ++i)
        if (base + i < NNODES) { off[base + i] = excl + local[i]; off2[base + i] = excl + local[i]; }
    if (t == 1023) off[NNODES] = NEDGES;
}

__global__ void fill_perm(const int* __restrict__ src, int* __restrict__ off2,
                          int* __restrict__ perm) {
    const int e = blockIdx.x * 256 + threadIdx.x;
    if (e < NEDGES) {
        const int p = atomicAdd(&off2[src[e]], 1);
        perm[p] = e;
    }
}

// ---------------------------------------------------------------------------
// Edge MLP (sorted-gather variant). Block = 128 sorted positions, 4 waves;
// wave owns 32 positions (2 row-tiles) x 128 ch. h_E rows gathered via perm
// (random 128B-granule reads); messages stored CONTIGUOUSLY at the sorted
// position in fp16 (plain coalesced stores, ZERO atomics).
// ---------------------------------------------------------------------------
#define SY 136   // A2 row stride (bf16): 128 + 8 pad

__launch_bounds__(256, 4)
__global__ void edge_mlp_sorted(const float* __restrict__ hE,
                                const int* __restrict__ perm,
                                const ushort_t* __restrict__ Wsw,
                                const float* __restrict__ b1,
                                const float* __restrict__ b2,
                                const float* __restrict__ b3,
                                _Float16* __restrict__ msg) {
    __shared__ ushort_t A2[4][32 * SY];   // 34816 B total, per-wave regions

    const int tid = threadIdx.x;
    const int wave = tid >> 6, lane = tid & 63;
    const int quad = lane >> 4, l16 = lane & 15;
    const size_t e0 = (size_t)blockIdx.x * 128 + wave * 32;
    ushort_t* Aw = A2[wave];

    const int pe[2] = { perm[e0 + l16], perm[e0 + 16 + l16] };

    f32x4 acc[2][8];

    // ---- layer 1: [32x256] x [256x128], A gathered from global via perm ----
    #pragma unroll
    for (int t = 0; t < 8; ++t) {
        const float bv = b1[t * 16 + l16];
        acc[0][t] = (f32x4){bv, bv, bv, bv};
        acc[1][t] = acc[0][t];
    }
    #pragma unroll
    for (int s = 0; s < 8; ++s) {
        bf16x8 a[2];
        #pragma unroll
        for (int rt = 0; rt < 2; ++rt) {
            const float4* p = (const float4*)(hE + (size_t)pe[rt] * INDIM + s * 32 + quad * 8);
            const float4 v0 = p[0], v1 = p[1];
            union { bf16x8 v; ushort_t u[8]; } c;
            c.u[0] = f2bf(v0.x); c.u[1] = f2bf(v0.y); c.u[2] = f2bf(v0.z); c.u[3] = f2bf(v0.w);
            c.u[4] = f2bf(v1.x); c.u[5] = f2bf(v1.y); c.u[6] = f2bf(v1.z); c.u[7] = f2bf(v1.w);
            a[rt] = c.v;
        }
        #pragma unroll
        for (int t = 0; t < 8; ++t) {
            const bf16x8 b = *(const bf16x8*)(Wsw + (size_t)((s * 8 + t) * 64 + lane) * 8);
            acc[0][t] = mfma_bf16(a[0], b, acc[0][t]);
            acc[1][t] = mfma_bf16(a[1], b, acc[1][t]);
        }
    }
    #pragma unroll
    for (int rt = 0; rt < 2; ++rt)
        #pragma unroll
        for (int t = 0; t < 8; ++t)
            #pragma unroll
            for (int r = 0; r < 4; ++r)
                Aw[(rt * 16 + quad * 4 + r) * SY + t * 16 + l16] = f2bf(gelu_fast(acc[rt][t][r]));

    // ---- layer 2: [32x128] x [128x128] ----
    #pragma unroll
    for (int t = 0; t < 8; ++t) {
        const float bv = b2[t * 16 + l16];
        acc[0][t] = (f32x4){bv, bv, bv, bv};
        acc[1][t] = acc[0][t];
    }
    #pragma unroll
    for (int s = 0; s < 4; ++s) {
        bf16x8 a[2];
        #pragma unroll
        for (int rt = 0; rt < 2; ++rt)
            a[rt] = *(const bf16x8*)(Aw + (rt * 16 + l16) * SY + s * 32 + quad * 8);
        #pragma unroll
        for (int t = 0; t < 8; ++t) {
            const bf16x8 b = *(const bf16x8*)(Wsw + 32768 + (size_t)((s * 8 + t) * 64 + lane) * 8);
            acc[0][t] = mfma_bf16(a[0], b, acc[0][t]);
            acc[1][t] = mfma_bf16(a[1], b, acc[1][t]);
        }
    }
    #pragma unroll
    for (int rt = 0; rt < 2; ++rt)
        #pragma unroll
        for (int t = 0; t < 8; ++t)
            #pragma unroll
            for (int r = 0; r < 4; ++r)
                Aw[(rt * 16 + quad * 4 + r) * SY + t * 16 + l16] = f2bf(gelu_fast(acc[rt][t][r]));

    // ---- layer 3: [32x128] x [128x128], PERMUTED output cols ----
    #pragma unroll
    for (int t = 0; t < 8; ++t) {
        const float bv = b3[2 * ((t & 3) * 16 + l16) + (t >> 2)];
        acc[0][t] = (f32x4){bv, bv, bv, bv};
        acc[1][t] = acc[0][t];
    }
    #pragma unroll
    for (int s = 0; s < 4; ++s) {
        bf16x8 a[2];
        #pragma unroll
        for (int rt = 0; rt < 2; ++rt)
            a[rt] = *(const bf16x8*)(Aw + (rt * 16 + l16) * SY + s * 32 + quad * 8);
        #pragma unroll
        for (int t = 0; t < 8; ++t) {
            const bf16x8 b = *(const bf16x8*)(Wsw + 49152 + (size_t)((s * 8 + t) * 64 + lane) * 8);
            acc[0][t] = mfma_bf16(a[0], b, acc[0][t]);
            acc[1][t] = mfma_bf16(a[1], b, acc[1][t]);
        }
    }

    // ---- store messages at sorted positions (contiguous, no atomics) ----
    #pragma unroll
    for (int rt = 0; rt < 2; ++rt)
        #pragma unroll
        for (int r = 0; r < 4; ++r) {
            const size_t row = e0 + rt * 16 + quad * 4 + r;
            unsigned int* mrow = (unsigned int*)(msg + row * HDIM);
            #pragma unroll
            for (int t = 0; t < 4; ++t) {
                union { _Float16 h[2]; unsigned int u; } pk;
                pk.h[0] = (_Float16)acc[rt][t][r];       // col 2*(t*16+l16)
                pk.h[1] = (_Float16)acc[rt][t + 4][r];   // col 2*(t*16+l16)+1
                mrow[t * 16 + l16] = pk.u;
            }
        }
}

// ---------------------------------------------------------------------------
// Edge MLP (tier-2 fallback): packed-fp16 atomic scatter into dh.
// ---------------------------------------------------------------------------
__launch_bounds__(256, 4)
__global__ void edge_mlp_mfma(const float* __restrict__ hE,
                              const int* __restrict__ edge_idx,
                              const ushort_t* __restrict__ Wsw,
                              const float* __restrict__ b1,
                              const float* __restrict__ b2,
                              const float* __restrict__ b3,
                              _Float16* __restrict__ dh) {
    __shared__ ushort_t A2[4][32 * SY];

    const int tid = threadIdx.x;
    const int wave = tid >> 6, lane = tid & 63;
    const int quad = lane >> 4, l16 = lane & 15;
    const size_t e0 = (size_t)blockIdx.x * 128 + wave * 32;
    ushort_t* Aw = A2[wave];

    f32x4 acc[2][8];

    #pragma unroll
    for (int t = 0; t < 8; ++t) {
        const float bv = b1[t * 16 + l16];
        acc[0][t] = (f32x4){bv, bv, bv, bv};
        acc[1][t] = acc[0][t];
    }
    #pragma unroll
    for (int s = 0; s < 8; ++s) {
        bf16x8 a[2];
        #pragma unroll
        for (int rt = 0; rt < 2; ++rt) {
            const float4* p = (const float4*)(hE + (e0 + rt * 16 + l16) * INDIM + s * 32 + quad * 8);
            const float4 v0 = p[0], v1 = p[1];
            union { bf16x8 v; ushort_t u[8]; } c;
            c.u[0] = f2bf(v0.x); c.u[1] = f2bf(v0.y); c.u[2] = f2bf(v0.z); c.u[3] = f2bf(v0.w);
            c.u[4] = f2bf(v1.x); c.u[5] = f2bf(v1.y); c.u[6] = f2bf(v1.z); c.u[7] = f2bf(v1.w);
            a[rt] = c.v;
        }
        #pragma unroll
        for (int t = 0; t < 8; ++t) {
            const bf16x8 b = *(const bf16x8*)(Wsw + (size_t)((s * 8 + t) * 64 + lane) * 8);
            acc[0][t] = mfma_bf16(a[0], b, acc[0][t]);
            acc[1][t] = mfma_bf16(a[1], b, acc[1][t]);
        }
    }
    #pragma unroll
    for (int rt = 0; rt < 2; ++rt)
        #pragma unroll
        for (int t = 0; t < 8; ++t)
            #pragma unroll
            for (int r = 0; r < 4; ++r)
                Aw[(rt * 16 + quad * 4 + r) * SY + t * 16 + l16] = f2bf(gelu_fast(acc[rt][t][r]));

    #pragma unroll
    for (int t = 0; t < 8; ++t) {
        const float bv = b2[t * 16 + l16];
        acc[0][t] = (f32x4){bv, bv, bv, bv};
        acc[1][t] = acc[0][t];
    }
    #pragma unroll
    for (int s = 0; s < 4; ++s) {
        bf16x8 a[2];
        #pragma unroll
        for (int rt = 0; rt < 2; ++rt)
            a[rt] = *(const bf16x8*)(Aw + (rt * 16 + l16) * SY + s * 32 + quad * 8);
        #pragma unroll
        for (int t = 0; t < 8; ++t) {
            const bf16x8 b = *(const bf16x8*)(Wsw + 32768 + (size_t)((s * 8 + t) * 64 + lane) * 8);
            acc[0][t] = mfma_bf16(a[0], b, acc[0][t]);
            acc[1][t] = mfma_bf16(a[1], b, acc[1][t]);
        }
    }
    #pragma unroll
    for (int rt = 0; rt < 2; ++rt)
        #pragma unroll
        for (int t = 0; t < 8; ++t)
            #pragma unroll
            for (int r = 0; r < 4; ++r)
                Aw[(rt * 16 + quad * 4 + r) * SY + t * 16 + l16] = f2bf(gelu_fast(acc[rt][t][r]));

    #pragma unroll
    for (int t = 0; t < 8; ++t) {
        const float bv = b3[2 * ((t & 3) * 16 + l16) + (t >> 2)];
        acc[0][t] = (f32x4){bv, bv, bv, bv};
        acc[1][t] = acc[0][t];
    }
    #pragma unroll
    for (int s = 0; s < 4; ++s) {
        bf16x8 a[2];
        #pragma unroll
        for (int rt = 0; rt < 2; ++rt)
            a[rt] = *(const bf16x8*)(Aw + (rt * 16 + l16) * SY + s * 32 + quad * 8);
        #pragma unroll
        for (int t = 0; t < 8; ++t) {
            const bf16x8 b = *(const bf16x8*)(Wsw + 49152 + (size_t)((s * 8 + t) * 64 + lane) * 8);
            acc[0][t] = mfma_bf16(a[0], b, acc[0][t]);
            acc[1][t] = mfma_bf16(a[1], b, acc[1][t]);
        }
    }

    #pragma unroll
    for (int rt = 0; rt < 2; ++rt)
        #pragma unroll
        for (int r = 0; r < 4; ++r) {
            const int e = (int)e0 + rt * 16 + quad * 4 + r;
            const int s = edge_idx[e];
            _Float16* dst = dh + (size_t)s * HDIM;
            #pragma unroll
            for (int t = 0; t < 4; ++t) {
                const int c = 2 * (t * 16 + l16);
                union { _Float16 h[2]; unsigned int u; } pk;
                pk.h[0] = (_Float16)acc[rt][t][r];
                pk.h[1] = (_Float16)acc[rt][t + 4][r];
                asm volatile("global_atomic_pk_add_f16 %0, %1, off"
                             :: "v"(dst + c), "v"(pk.u) : "memory");
            }
        }
}

// ---------------------------------------------------------------------------
// Node update (gather variant). Block = 32 nodes, 4 waves. Step 1 gathers the
// node's contiguous msg segment (8 threads/node, fp32 accum in regs).
// ---------------------------------------------------------------------------
__launch_bounds__(256)
__global__ void node_mfma_gather(const float* __restrict__ hV,
                                 const _Float16* __restrict__ msg,
                                 const int* __restrict__ off,
                                 const float* __restrict__ n1g, const float* __restrict__ n1b,
                                 const ushort_t* __restrict__ D1sw, const float* __restrict__ D1b,
                                 const ushort_t* __restrict__ D2sw, const float* __restrict__ D2b,
                                 const float* __restrict__ n2g, const float* __restrict__ n2b,
                                 float* __restrict__ out) {
    __shared__ __align__(16) float xs[32 * HDIM];
    __shared__ __align__(16) ushort_t h1a[32 * SY];
    __shared__ __align__(16) ushort_t ua[32 * 520];
    __shared__ float mu_s[32], rs_s[32];

    const int tid = threadIdx.x;
    const int wave = tid >> 6, lane = tid & 63;
    const int quad = lane >> 4, l16 = lane & 15;
    const int n0 = blockIdx.x * 32;

    // 1: x = hV + (segment-sum of msg)/30   (8 threads per node, 16 ch each)
    {
        const int node = tid >> 3, q = tid & 7;
        const int j0 = off[n0 + node], j1 = off[n0 + node + 1];
        float a[16];
        #pragma unroll
        for (int k = 0; k < 16; ++k) a[k] = 0.f;
        int j = j0;
        for (; j + 1 < j1; j += 2) {
            const half8_t* r0p = (const half8_t*)(msg + (size_t)j * HDIM + q * 16);
            const half8_t* r1p = (const half8_t*)(msg + (size_t)(j + 1) * HDIM + q * 16);
            const half8_t a0 = r0p[0], a1 = r0p[1], b0 = r1p[0], b1 = r1p[1];
            #pragma unroll
            for (int k = 0; k < 8; ++k) {
                a[k]     += (float)a0[k] + (float)b0[k];
                a[8 + k] += (float)a1[k] + (float)b1[k];
            }
        }
        if (j < j1) {
            const half8_t* rp = (const half8_t*)(msg + (size_t)j * HDIM + q * 16);
            const half8_t r0 = rp[0], r1 = rp[1];
            #pragma unroll
            for (int k = 0; k < 8; ++k) { a[k] += (float)r0[k]; a[8 + k] += (float)r1[k]; }
        }
        const float4* hvp = (const float4*)(hV + (size_t)(n0 + node) * HDIM + q * 16);
        #pragma unroll
        for (int k4 = 0; k4 < 4; ++k4) {
            const float4 hv = hvp[k4];
            float* xp = xs + node * HDIM + q * 16 + k4 * 4;
            xp[0] = hv.x + a[k4 * 4 + 0] * INV_SCALE;
            xp[1] = hv.y + a[k4 * 4 + 1] * INV_SCALE;
            xp[2] = hv.z + a[k4 * 4 + 2] * INV_SCALE;
            xp[3] = hv.w + a[k4 * 4 + 3] * INV_SCALE;
        }
    }
    __syncthreads();

    // 2: LN1 stats
    {
        const int row = tid >> 3, q = tid & 7;
        float s = 0.f, s2 = 0.f;
        #pragma unroll
        for (int c = 0; c < 16; ++c) { const float v = xs[row * HDIM + q * 16 + c]; s += v; s2 += v * v; }
        #pragma unroll
        for (int o = 1; o < 8; o <<= 1) { s += __shfl_xor(s, o); s2 += __shfl_xor(s2, o); }
        if (q == 0) {
            const float m = s * (1.0f / HDIM);
            mu_s[row] = m;
            rs_s[row] = rsqrtf(s2 * (1.0f / HDIM) - m * m + LN_EPS);
        }
    }
    __syncthreads();

    // 3: h1 (bf16, A-layout)
    #pragma unroll
    for (int it = 0; it < 2; ++it) {
        const int g = it * 256 + tid;
        const int row = g >> 4, col = (g & 15) * 8;
        const float mu = mu_s[row], rs = rs_s[row];
        union { bf16x8 v; ushort_t u[8]; } c;
        #pragma unroll
        for (int jj = 0; jj < 8; ++jj) {
            const float h1 = (xs[row * HDIM + col + jj] - mu) * rs * n1g[col + jj] + n1b[col + jj];
            c.u[jj] = f2bf(h1);
        }
        *(bf16x8*)(h1a + row * SY + col) = c.v;
    }
    __syncthreads();

    // 4: u = gelu(h1 @ D1 + b1)
    {
        f32x4 acc1[2][8];
        #pragma unroll
        for (int t = 0; t < 8; ++t) {
            const float bv = D1b[wave * 128 + t * 16 + l16];
            acc1[0][t] = (f32x4){bv, bv, bv, bv};
            acc1[1][t] = acc1[0][t];
        }
        #pragma unroll
        for (int s = 0; s < 4; ++s) {
            bf16x8 a[2];
            #pragma unroll
            for (int rt = 0; rt < 2; ++rt)
                a[rt] = *(const bf16x8*)(h1a + (rt * 16 + l16) * SY + s * 32 + quad * 8);
            #pragma unroll
            for (int t = 0; t < 8; ++t) {
                const bf16x8 b = *(const bf16x8*)(D1sw + (size_t)((s * 32 + wave * 8 + t) * 64 + lane) * 8);
                acc1[0][t] = mfma_bf16(a[0], b, acc1[0][t]);
                acc1[1][t] = mfma_bf16(a[1], b, acc1[1][t]);
            }
        }
        #pragma unroll
        for (int rt = 0; rt < 2; ++rt)
            #pragma unroll
            for (int t = 0; t < 8; ++t)
                #pragma unroll
                for (int r = 0; r < 4; ++r)
                    ua[(rt * 16 + quad * 4 + r) * 520 + wave * 128 + t * 16 + l16] =
                        f2bf(gelu_fast(acc1[rt][t][r]));
    }
    __syncthreads();

    // 6: v = u @ D2
    f32x4 acc2[2][2];
    acc2[0][0] = (f32x4){0,0,0,0}; acc2[0][1] = acc2[0][0];
    acc2[1][0] = acc2[0][0];       acc2[1][1] = acc2[0][0];
    #pragma unroll
    for (int s = 0; s < 16; ++s) {
        bf16x8 a[2];
        #pragma unroll
        for (int rt = 0; rt < 2; ++rt)
            a[rt] = *(const bf16x8*)(ua + (rt * 16 + l16) * 520 + s * 32 + quad * 8);
        #pragma unroll
        for (int tt = 0; tt < 2; ++tt) {
            const bf16x8 b = *(const bf16x8*)(D2sw + (size_t)((s * 8 + wave * 2 + tt) * 64 + lane) * 8);
            acc2[0][tt] = mfma_bf16(a[0], b, acc2[0][tt]);
            acc2[1][tt] = mfma_bf16(a[1], b, acc2[1][tt]);
        }
    }
    __syncthreads();

    // 7: y = h1 + v + b2 (fp32) into yf (aliases ua)
    float* yf = (float*)ua;
    #pragma unroll
    for (int rt = 0; rt < 2; ++rt)
        #pragma unroll
        for (int tt = 0; tt < 2; ++tt)
            #pragma unroll
            for (int r = 0; r < 4; ++r) {
                const int row = rt * 16 + quad * 4 + r;
                const int col = wave * 32 + tt * 16 + l16;
                const float h1 = (xs[row * HDIM + col] - mu_s[row]) * rs_s[row] * n1g[col] + n1b[col];
                yf[row * HDIM + col] = h1 + acc2[rt][tt][r] + D2b[col];
            }
    __syncthreads();

    // 8: LN2 stats
    {
        const int row = tid >> 3, q = tid & 7;
        float s = 0.f, s2 = 0.f;
        #pragma unroll
        for (int c = 0; c < 16; ++c) { const float v = yf[row * HDIM + q * 16 + c]; s += v; s2 += v * v; }
        #pragma unroll
        for (int o = 1; o < 8; o <<= 1) { s += __shfl_xor(s, o); s2 += __shfl_xor(s2, o); }
        if (q == 0) {
            const float m = s * (1.0f / HDIM);
            mu_s[row] = m;
            rs_s[row] = rsqrtf(s2 * (1.0f / HDIM) - m * m + LN_EPS);
        }
    }
    __syncthreads();

    // 9: out = LN2(y)
    #pragma unroll
    for (int it = 0; it < 4; ++it) {
        const int f4 = it * 256 + tid;
        const int row = f4 >> 5, col = (f4 & 31) * 4;
        const float4 y = ((const float4*)yf)[f4];
        const float mu = mu_s[row], rs = rs_s[row];
        float4 o;
        o.x = (y.x - mu) * rs * n2g[col + 0] + n2b[col + 0];
        o.y = (y.y - mu) * rs * n2g[col + 1] + n2b[col + 1];
        o.z = (y.z - mu) * rs * n2g[col + 2] + n2b[col + 2];
        o.w = (y.w - mu) * rs * n2g[col + 3] + n2b[col + 3];
        ((float4*)(out + (size_t)n0 * HDIM))[f4] = o;
    }
}

// ---------------------------------------------------------------------------
// Node update (tier-2: reads fp16 dh directly).
// ---------------------------------------------------------------------------
__launch_bounds__(256)
__global__ void node_mfma(const float* __restrict__ hV, const _Float16* __restrict__ dh,
                          const float* __restrict__ n1g, const float* __restrict__ n1b,
                          const ushort_t* __restrict__ D1sw, const float* __restrict__ D1b,
                          const ushort_t* __restrict__ D2sw, const float* __restrict__ D2b,
                          const float* __restrict__ n2g, const float* __restrict__ n2b,
                          float* __restrict__ out) {
    __shared__ __align__(16) float xs[32 * HDIM];
    __shared__ __align__(16) ushort_t h1a[32 * SY];
    __shared__ __align__(16) ushort_t ua[32 * 520];
    __shared__ float mu_s[32], rs_s[32];

    const int tid = threadIdx.x;
    const int wave = tid >> 6, lane = tid & 63;
    const int quad = lane >> 4, l16 = lane & 15;
    const int n0 = blockIdx.x * 32;

    #pragma unroll
    for (int it = 0; it < 4; ++it) {
        const int f4 = it * 256 + tid;
        const float4 hv = ((const float4*)(hV + (size_t)n0 * HDIM))[f4];
        const half4_t dv = ((const half4_t*)(dh + (size_t)n0 * HDIM))[f4];
        ((float4*)xs)[f4] = (float4){hv.x + (float)dv[0] * INV_SCALE,
                                     hv.y + (float)dv[1] * INV_SCALE,
                                     hv.z + (float)dv[2] * INV_SCALE,
                                     hv.w + (float)dv[3] * INV_SCALE};
    }
    __syncthreads();

    {
        const int row = tid >> 3, q = tid & 7;
        float s = 0.f, s2 = 0.f;
        #pragma unroll
        for (int c = 0; c < 16; ++c) { const float v = xs[row * HDIM + q * 16 + c]; s += v; s2 += v * v; }
        #pragma unroll
        for (int o = 1; o < 8; o <<= 1) { s += __shfl_xor(s, o); s2 += __shfl_xor(s2, o); }
        if (q == 0) {
            const float m = s * (1.0f / HDIM);
            mu_s[row] = m;
            rs_s[row] = rsqrtf(s2 * (1.0f / HDIM) - m * m + LN_EPS);
        }
    }
    __syncthreads();

    #pragma unroll
    for (int it = 0; it < 2; ++it) {
        const int g = it * 256 + tid;
        const int row = g >> 4, col = (g & 15) * 8;
        const float mu = mu_s[row], rs = rs_s[row];
        union { bf16x8 v; ushort_t u[8]; } c;
        #pragma unroll
        for (int jj = 0; jj < 8; ++jj) {
            const float h1 = (xs[row * HDIM + col + jj] - mu) * rs * n1g[col + jj] + n1b[col + jj];
            c.u[jj] = f2bf(h1);
        }
        *(bf16x8*)(h1a + row * SY + col) = c.v;
    }
    __syncthreads();

    {
        f32x4 acc1[2][8];
        #pragma unroll
        for (int t = 0; t < 8; ++t) {
            const float bv = D1b[wave * 128 + t * 16 + l16];
            acc1[0][t] = (f32x4){bv, bv, bv, bv};
            acc1[1][t] = acc1[0][t];
        }
        #pragma unroll
        for (int s = 0; s < 4; ++s) {
            bf16x8 a[2];
            #pragma unroll
            for (int rt = 0; rt < 2; ++rt)
                a[rt] = *(const bf16x8*)(h1a + (rt * 16 + l16) * SY + s * 32 + quad * 8);
            #pragma unroll
            for (int t = 0; t < 8; ++t) {
                const bf16x8 b = *(const bf16x8*)(D1sw + (size_t)((s * 32 + wave * 8 + t) * 64 + lane) * 8);
                acc1[0][t] = mfma_bf16(a[0], b, acc1[0][t]);
                acc1[1][t] = mfma_bf16(a[1], b, acc1[1][t]);
            }
        }
        #pragma unroll
        for (int rt = 0; rt < 2; ++rt)
            #pragma unroll
            for (int t = 0; t < 8; ++t)
                #pragma unroll
                for (int r = 0; r < 4; ++r)
                    ua[(rt * 16 + quad * 4 + r) * 520 + wave * 128 + t * 16 + l16] =
                        f2bf(gelu_fast(acc1[rt][t][r]));
    }
    __syncthreads();

    f32x4 acc2[2][2];
    acc2[0][0] = (f32x4){0,0,0,0}; acc2[0][1] = acc2[0][0];
    acc2[1][0] = acc2[0][0];       acc2[1][1] = acc2[0][0];
    #pragma unroll
    for (int s = 0; s < 16; ++s) {
        bf16x8 a[2];
        #pragma unroll
        for (int rt = 0; rt < 2; ++rt)
            a[rt] = *(const bf16x8*)(ua + (rt * 16 + l16) * 520 + s * 32 + quad * 8);
        #pragma unroll
        for (int tt = 0; tt < 2; ++tt) {
            const bf16x8 b = *(const bf16x8*)(D2sw + (size_t)((s * 8 + wave * 2 + tt) * 64 + lane) * 8);
            acc2[0][tt] = mfma_bf16(a[0], b, acc2[0][tt]);
            acc2[1][tt] = mfma_bf16(a[1], b, acc2[1][tt]);
        }
    }
    __syncthreads();

    float* yf = (float*)ua;
    #pragma unroll
    for (int rt = 0; rt < 2; ++rt)
        #pragma unroll
        for (int tt = 0; tt < 2; ++tt)
            #pragma unroll
            for (int r = 0; r < 4; ++r) {
                const int row = rt * 16 + quad * 4 + r;
                const int col = wave * 32 + tt * 16 + l16;
                const float h1 = (xs[row * HDIM + col] - mu_s[row]) * rs_s[row] * n1g[col] + n1b[col];
                yf[row * HDIM + col] = h1 + acc2[rt][tt][r] + D2b[col];
            }
    __syncthreads();

    {
        const int row = tid >> 3, q = tid & 7;
        float s = 0.f, s2 = 0.f;
        #pragma unroll
        for (int c = 0; c < 16; ++c) { const float v = yf[row * HDIM + q * 16 + c]; s += v; s2 += v * v; }
        #pragma unroll
        for (int o = 1; o < 8; o <<= 1) { s += __shfl_xor(s, o); s2 += __shfl_xor(s2, o); }
        if (q == 0) {
            const float m = s * (1.0f / HDIM);
            mu_s[row] = m;
            rs_s[row] = rsqrtf(s2 * (1.0f / HDIM) - m * m + LN_EPS);
        }
    }
    __syncthreads();

    #pragma unroll
    for (int it = 0; it < 4; ++it) {
        const int f4 = it * 256 + tid;
        const int row = f4 >> 5, col = (f4 & 31) * 4;
        const float4 y = ((const float4*)yf)[f4];
        const float mu = mu_s[row], rs = rs_s[row];
        float4 o;
        o.x = (y.x - mu) * rs * n2g[col + 0] + n2b[col + 0];
        o.y = (y.y - mu) * rs * n2g[col + 1] + n2b[col + 1];
        o.z = (y.z - mu) * rs * n2g[col + 2] + n2b[col + 2];
        o.w = (y.w - mu) * rs * n2g[col + 3] + n2b[col + 3];
        ((float4*)(out + (size_t)n0 * HDIM))[f4] = o;
    }
}

// ---------------------------------------------------------------------------
// Tier-3 fp32 node fallback.
// ---------------------------------------------------------------------------
#define NT 8
__device__ __forceinline__ void ln_stats32(const float* __restrict__ buf,
                                           float* __restrict__ mu_s,
                                           float* __restrict__ rs_s, int tid) {
    const int g = tid >> 5, lane = tid & 31;
    float s = 0.f, s2 = 0.f;
    #pragma unroll
    for (int c = lane; c < HDIM; c += 32) { const float v = buf[g * HDIM + c]; s += v; s2 += v * v; }
    #pragma unroll
    for (int o = 16; o; o >>= 1) { s += __shfl_xor(s, o, 32); s2 += __shfl_xor(s2, o, 32); }
    if (lane == 0) {
        const float m = s * (1.0f / HDIM);
        mu_s[g] = m;
        rs_s[g] = rsqrtf(s2 * (1.0f / HDIM) - m * m + LN_EPS);
    }
}

__launch_bounds__(256)
__global__ void node_update_f32(const float* __restrict__ hV, const _Float16* __restrict__ dh,
                                const float* __restrict__ n1g, const float* __restrict__ n1b,
                                const float* __restrict__ D1w, const float* __restrict__ D1b,
                                const float* __restrict__ D2w, const float* __restrict__ D2b,
                                const float* __restrict__ n2g, const float* __restrict__ n2b,
                                float* __restrict__ out) {
    __shared__ float h1s[NT * HDIM];
    __shared__ float us[NT * 512];
    __shared__ float vs[2 * NT * HDIM];
    __shared__ float mu_s[NT], rs_s[NT];
    const int tid = threadIdx.x;
    const int n0 = blockIdx.x * NT;
    for (int idx = tid; idx < NT * HDIM; idx += 256) {
        const int i = idx >> 7, c = idx & 127;
        const size_t g = (size_t)(n0 + i) * HDIM + c;
        h1s[idx] = hV[g] + (float)dh[g] * INV_SCALE;
    }
    __syncthreads();
    ln_stats32(h1s, mu_s, rs_s, tid);
    __syncthreads();
    for (int idx = tid; idx < NT * HDIM; idx += 256) {
        const int i = idx >> 7, c = idx & 127;
        h1s[idx] = (h1s[idx] - mu_s[i]) * rs_s[i] * n1g[c] + n1b[c];
    }
    __syncthreads();
    {
        const int o = 2 * tid;
        const float2 bv = *(const float2*)(D1b + o);
        float a0[NT], a1[NT];
        #pragma unroll
        for (int i = 0; i < NT; ++i) { a0[i] = bv.x; a1[i] = bv.y; }
        for (int k = 0; k < HDIM; ++k) {
            const float2 w = *(const float2*)(D1w + (size_t)k * 512 + o);
            #pragma unroll
            for (int i = 0; i < NT; ++i) {
                const float xv = h1s[i * HDIM + k];
                a0[i] += xv * w.x; a1[i] += xv * w.y;
            }
        }
        #pragma unroll
        for (int i = 0; i < NT; ++i) {
            us[i * 512 + o]     = gelu_fast(a0[i]);
            us[i * 512 + o + 1] = gelu_fast(a1[i]);
        }
    }
    __syncthreads();
    {
        const int o = tid & 127, half = tid >> 7;
        float a[NT];
        #pragma unroll
        for (int i = 0; i < NT; ++i) a[i] = 0.f;
        const int k0 = half * 256;
        for (int k = k0; k < k0 + 256; ++k) {
            const float w = D2w[(size_t)k * HDIM + o];
            #pragma unroll
            for (int i = 0; i < NT; ++i) a[i] += us[i * 512 + k] * w;
        }
        #pragma unroll
        for (int i = 0; i < NT; ++i) vs[(half * NT + i) * HDIM + o] = a[i];
    }
    __syncthreads();
    float* ys = us;
    for (int idx = tid; idx < NT * HDIM; idx += 256) {
        const int i = idx >> 7, c = idx & 127;
        ys[idx] = h1s[idx] + vs[i * HDIM + c] + vs[(NT + i) * HDIM + c] + D2b[c];
    }
    __syncthreads();
    ln_stats32(ys, mu_s, rs_s, tid);
    __syncthreads();
    for (int idx = tid; idx < NT * HDIM; idx += 256) {
        const int i = idx >> 7, c = idx & 127;
        out[(size_t)(n0 + i) * HDIM + c] = (ys[idx] - mu_s[i]) * rs_s[i] * n2g[c] + n2b[c];
    }
}

extern "C" void kernel_launch(void* const* d_in, const int* in_sizes, int n_in,
                              void* d_out, int out_size, void* d_ws, size_t ws_size,
                              hipStream_t stream) {
    const float* hV  = (const float*)d_in[0];
    const float* hE  = (const float*)d_in[1];
    const int*  eidx = (const int*)d_in[2];
    const float* W1w = (const float*)d_in[3];
    const float* W1b = (const float*)d_in[4];
    const float* W2w = (const float*)d_in[5];
    const float* W2b = (const float*)d_in[6];
    const float* W3w = (const float*)d_in[7];
    const float* W3b = (const float*)d_in[8];
    const float* n1g = (const float*)d_in[9];
    const float* n1b = (const float*)d_in[10];
    const float* D1w = (const float*)d_in[11];
    const float* D1b = (const float*)d_in[12];
    const float* D2w = (const float*)d_in[13];
    const float* D2b = (const float*)d_in[14];
    const float* n2g = (const float*)d_in[15];
    const float* n2b = (const float*)d_in[16];
    float* out = (float*)d_out;

    // ---- tier-1 layout: msg | WswE | D1sw | D2sw | perm | cnt | off | off2 ----
    const size_t MSG_BYTES = (size_t)NEDGES * HDIM * sizeof(_Float16);  // 81,920,000
    const size_t EW_BYTES  = 65536 * 2;
    const size_t T1_BYTES  = MSG_BYTES + 3 * EW_BYTES
                           + (size_t)NEDGES * 4            // perm
                           + (size_t)NNODES * 4            // cnt
                           + (size_t)(NNODES + 1) * 4      // off
                           + (size_t)NNODES * 4;           // off2
    const size_t DH_BYTES  = (size_t)NNODES * HDIM * sizeof(_Float16);  // 5,120,000
    const size_t T2_BYTES  = DH_BYTES + 3 * EW_BYTES;

    if (ws_size >= T1_BYTES) {
        char* p = (char*)d_ws;
        _Float16* msg  = (_Float16*)p;            p += MSG_BYTES;
        ushort_t* WswE = (ushort_t*)p;            p += EW_BYTES;
        ushort_t* D1sw = (ushort_t*)p;            p += EW_BYTES;
        ushort_t* D2sw = (ushort_t*)p;            p += EW_BYTES;
        int* perm = (int*)p;                      p += (size_t)NEDGES * 4;
        int* cnt  = (int*)p;                      p += (size_t)NNODES * 4;
        int* off  = (int*)p;                      p += (size_t)(NNODES + 1) * 4;
        int* off2 = (int*)p;

        hipMemsetAsync(cnt, 0, (size_t)NNODES * 4, stream);
        prep_edge_weights<<<256, 256, 0, stream>>>(W1w, W2w, W3w, WswE);
        prep_node_weights<<<512, 256, 0, stream>>>(D1w, D2w, D1sw, D2sw);
        edge_hist<<<(NEDGES + 255) / 256, 256, 0, stream>>>(eidx, cnt);
        scan_counts<<<1, 1024, 0, stream>>>(cnt, off, off2);
        fill_perm<<<(NEDGES + 255) / 256, 256, 0, stream>>>(eidx, off2, perm);
        edge_mlp_sorted<<<NEDGES / 128, 256, 0, stream>>>(hE, perm, WswE, W1b, W2b, W3b, msg);
        node_mfma_gather<<<NNODES / 32, 256, 0, stream>>>(hV, msg, off, n1g, n1b,
                                                          D1sw, D1b, D2sw, D2b, n2g, n2b, out);
    } else if (ws_size >= T2_BYTES) {
        _Float16* dh = (_Float16*)d_ws;
        ushort_t* WswE = (ushort_t*)((char*)d_ws + DH_BYTES);
        ushort_t* D1sw = (ushort_t*)((char*)d_ws + DH_BYTES + EW_BYTES);
        ushort_t* D2sw = (ushort_t*)((char*)d_ws + DH_BYTES + 2 * EW_BYTES);
        hipMemsetAsync(dh, 0, DH_BYTES, stream);
        prep_edge_weights<<<256, 256, 0, stream>>>(W1w, W2w, W3w, WswE);
        prep_node_weights<<<512, 256, 0, stream>>>(D1w, D2w, D1sw, D2sw);
        edge_mlp_mfma<<<NEDGES / 128, 256, 0, stream>>>(hE, eidx, WswE, W1b, W2b, W3b, dh);
        node_mfma<<<NNODES / 32, 256, 0, stream>>>(hV, dh, n1g, n1b, D1sw, D1b, D2sw, D2b, n2g, n2b, out);
    } else {
        _Float16* dh = (_Float16*)d_ws;
        ushort_t* WswE = (ushort_t*)((char*)d_out + (size_t)out_size * 4 - EW_BYTES);
        hipMemsetAsync(dh, 0, DH_BYTES, stream);
        prep_edge_weights<<<256, 256, 0, stream>>>(W1w, W2w, W3w, WswE);
        edge_mlp_mfma<<<NEDGES / 128, 256, 0, stream>>>(hE, eidx, WswE, W1b, W2b, W3b, dh);
        node_update_f32<<<NNODES / NT, 256, 0, stream>>>(hV, dh, n1g, n1b, D1w, D1b, D2w, D2b, n2g, n2b, out);
    }
}

// Round 4
// 683.210 us; speedup vs baseline: 1.0121x; 1.0121x over previous
//
#include <hip/hip_runtime.h>
#include <hip/hip_bf16.h>
#include <math.h>

#define NNODES 20000
#define NEDGES 320000
#define HDIM   128
#define INDIM  256
#define INV_SCALE (1.0f/30.0f)
#define LN_EPS 1e-5f

typedef __bf16 bf16x8 __attribute__((ext_vector_type(8)));
typedef float  f32x4  __attribute__((ext_vector_type(4)));
typedef _Float16 half4_t __attribute__((ext_vector_type(4)));
typedef _Float16 half8_t __attribute__((ext_vector_type(8)));
typedef unsigned short ushort_t;

__device__ __forceinline__ unsigned short f2bf(float f) {
    union { __hip_bfloat16 h; unsigned short u; } c;
    c.h = __float2bfloat16(f);
    return c.u;
}

// Fast gelu: x * sigmoid(1.5957691*x + 0.0713548*x^3)  (tanh-form, max |err| ~1e-3)
__device__ __forceinline__ float gelu_fast(float x) {
    const float z = x * (1.595769122f + 0.071354816f * x * x);
    return x / (1.0f + __expf(-z));
}

__device__ __forceinline__ f32x4 mfma_bf16(bf16x8 a, bf16x8 b, f32x4 c) {
    return __builtin_amdgcn_mfma_f32_16x16x32_bf16(a, b, c, 0, 0, 0);
}

// ---------------------------------------------------------------------------
// Weight prep. B-fragment order for mfma_f32_16x16x32_bf16: frag (s,t), lane L,
// elem j holds W[k = s*32 + (L>>4)*8 + j][n = t*16 + (L&15)]; each lane's 8 bf16
// are contiguous (one 16B load). Fragment f stored at Wsw[(f*64 + L)*8 + j].
// Edge weights: W1 f=s*8+t (base 0), W2 (base 32768), W3 (base 49152).
//
// W3: output columns PERMUTED so message stores pack adjacent column pairs per
// lane: fragment col (t,l16) -> actual col n3 = 2*((t&3)*16 + l16) + (t>>2).
// Acc pair (t, t+4) = actual cols (2*(t*16+l16), 2*(t*16+l16)+1) -> msg rows
// end up in plain linear col order in memory.
// ---------------------------------------------------------------------------
__global__ void prep_edge_weights(const float* __restrict__ W1,
                                  const float* __restrict__ W2,
                                  const float* __restrict__ W3,
                                  ushort_t* __restrict__ Wsw) {
    const int id = blockIdx.x * 256 + threadIdx.x;   // 0..65535
    const float* W; int base, idx; bool perm = false;
    if (id < 32768)      { W = W1; base = 0;     idx = id; }
    else if (id < 49152) { W = W2; base = 32768; idx = id - 32768; }
    else                 { W = W3; base = 49152; idx = id - 49152; perm = true; }
    const int j = idx & 7, lane = (idx >> 3) & 63, t = (idx >> 9) & 7, s = idx >> 12;
    const int k = s * 32 + (lane >> 4) * 8 + j;
    const int n = perm ? (2 * ((t & 3) * 16 + (lane & 15)) + (t >> 2))
                       : (t * 16 + (lane & 15));
    Wsw[base + idx] = f2bf(W[k * HDIM + n]);
}

// Node weights: D1 (128x512): f = s*32+t (s<4, t<32). D2 (512x128): f = s*8+t (s<16, t<8).
__global__ void prep_node_weights(const float* __restrict__ D1,
                                  const float* __restrict__ D2,
                                  ushort_t* __restrict__ D1sw,
                                  ushort_t* __restrict__ D2sw) {
    const int id = blockIdx.x * 256 + threadIdx.x;   // 0..131071
    if (id < 65536) {
        const int idx = id;
        const int j = idx & 7, lane = (idx >> 3) & 63, f = idx >> 9;   // f = s*32+t
        const int t = f & 31, s = f >> 5;
        const int k = s * 32 + (lane >> 4) * 8 + j;
        const int n = t * 16 + (lane & 15);
        D1sw[idx] = f2bf(D1[k * 512 + n]);
    } else {
        const int idx = id - 65536;
        const int j = idx & 7, lane = (idx >> 3) & 63, f = idx >> 9;   // f = s*8+t
        const int t = f & 7, s = f >> 3;
        const int k = s * 32 + (lane >> 4) * 8 + j;
        const int n = t * 16 + (lane & 15);
        D2sw[idx] = f2bf(D2[k * HDIM + n]);
    }
}

// ---------------------------------------------------------------------------
// Counting sort of edges by source node (CSR build).
// ---------------------------------------------------------------------------
__global__ void edge_hist(const int* __restrict__ src, int* __restrict__ cnt) {
    const int e = blockIdx.x * 256 + threadIdx.x;
    if (e < NEDGES) atomicAdd(&cnt[src[e]], 1);
}

__launch_bounds__(1024)
__global__ void scan_counts(const int* __restrict__ cnt,
                            int* __restrict__ off, int* __restrict__ off2) {
    __shared__ int tot[1024];
    const int t = threadIdx.x;
    const int base = t * 20;                 // 1024*20 = 20480 >= NNODES
    int local[20]; int s = 0;
    #pragma unroll
    for (int i = 0; i < 20; ++i) {
        const int v = (base + i < NNODES) ? cnt[base + i] : 0;
        local[i] = s; s += v;
    }
    tot[t] = s;
    __syncthreads();
    for (int d = 1; d < 1024; d <<= 1) {
        const int v = (t >= d) ? tot[t - d] : 0;
        __syncthreads();
        tot[t] += v;
        __syncthreads();
    }
    const int excl = (t == 0) ? 0 : tot[t - 1];
    #pragma unroll
    for (int i = 0; i < 20; ++i)
        if (base + i < NNODES) { off[base + i] = excl + local[i]; off2[base + i] = excl + local[i]; }
    if (t == 1023) off[NNODES] = NEDGES;
}

__global__ void fill_perm(const int* __restrict__ src, int* __restrict__ off2,
                          int* __restrict__ perm) {
    const int e = blockIdx.x * 256 + threadIdx.x;
    if (e < NEDGES) {
        const int p = atomicAdd(&off2[src[e]], 1);
        perm[p] = e;
    }
}

// ---------------------------------------------------------------------------
// Edge MLP (streaming, ORIGINAL edge order). Block = 128 edges, 4 waves; wave
// owns 32 edges (2 row-tiles) x 128 ch. hE reads are sequential; msg stores
// coalesced at the original edge index. ZERO atomics. Layer-1 loads run a
// depth-3 register pipeline (static rotation, no dynamic indexing).
// ---------------------------------------------------------------------------
#define SY 136   // A2 row stride (bf16): 128 + 8 pad

#define CVT8(dst, v0, v1) { union { bf16x8 v; ushort_t u[8]; } c_; \
    c_.u[0] = f2bf((v0).x); c_.u[1] = f2bf((v0).y); c_.u[2] = f2bf((v0).z); c_.u[3] = f2bf((v0).w); \
    c_.u[4] = f2bf((v1).x); c_.u[5] = f2bf((v1).y); c_.u[6] = f2bf((v1).z); c_.u[7] = f2bf((v1).w); \
    (dst) = c_.v; }

#define L1_LOAD(S, sa, sb) { \
    sa[0] = pb0[(S) * 8]; sb[0] = pb0[(S) * 8 + 1]; \
    sa[1] = pb1[(S) * 8]; sb[1] = pb1[(S) * 8 + 1]; }

#define L1_STEP(S, sa, sb) { \
    bf16x8 a0_, a1_; CVT8(a0_, sa[0], sb[0]); CVT8(a1_, sa[1], sb[1]); \
    _Pragma("unroll") \
    for (int t = 0; t < 8; ++t) { \
        const bf16x8 b_ = *(const bf16x8*)(Wsw + (size_t)(((S) * 8 + t) * 64 + lane) * 8); \
        acc[0][t] = mfma_bf16(a0_, b_, acc[0][t]); \
        acc[1][t] = mfma_bf16(a1_, b_, acc[1][t]); } }

__launch_bounds__(256, 3)
__global__ void edge_mlp_stream(const float* __restrict__ hE,
                                const ushort_t* __restrict__ Wsw,
                                const float* __restrict__ b1,
                                const float* __restrict__ b2,
                                const float* __restrict__ b3,
                                _Float16* __restrict__ msg) {
    __shared__ ushort_t A2[4][32 * SY];   // 34816 B total, per-wave regions

    const int tid = threadIdx.x;
    const int wave = tid >> 6, lane = tid & 63;
    const int quad = lane >> 4, l16 = lane & 15;
    const size_t e0 = (size_t)blockIdx.x * 128 + wave * 32;
    ushort_t* Aw = A2[wave];

    f32x4 acc[2][8];

    // ---- layer 1: [32x256] x [256x128], depth-3 pipelined loads ----
    #pragma unroll
    for (int t = 0; t < 8; ++t) {
        const float bv = b1[t * 16 + l16];
        acc[0][t] = (f32x4){bv, bv, bv, bv};
        acc[1][t] = acc[0][t];
    }
    {
        const float4* pb0 = (const float4*)hE + (e0 + l16) * (INDIM / 4) + quad * 2;
        const float4* pb1 = (const float4*)hE + (e0 + 16 + l16) * (INDIM / 4) + quad * 2;
        float4 xa[2], xb[2], ya[2], yb[2], za[2], zb[2];
        L1_LOAD(0, xa, xb); L1_LOAD(1, ya, yb); L1_LOAD(2, za, zb);
        L1_STEP(0, xa, xb); L1_LOAD(3, xa, xb);
        L1_STEP(1, ya, yb); L1_LOAD(4, ya, yb);
        L1_STEP(2, za, zb); L1_LOAD(5, za, zb);
        L1_STEP(3, xa, xb); L1_LOAD(6, xa, xb);
        L1_STEP(4, ya, yb); L1_LOAD(7, ya, yb);
        L1_STEP(5, za, zb);
        L1_STEP(6, xa, xb);
        L1_STEP(7, ya, yb);
    }
    #pragma unroll
    for (int rt = 0; rt < 2; ++rt)
        #pragma unroll
        for (int t = 0; t < 8; ++t)
            #pragma unroll
            for (int r = 0; r < 4; ++r)
                Aw[(rt * 16 + quad * 4 + r) * SY + t * 16 + l16] = f2bf(gelu_fast(acc[rt][t][r]));

    // ---- layer 2: [32x128] x [128x128] ----
    #pragma unroll
    for (int t = 0; t < 8; ++t) {
        const float bv = b2[t * 16 + l16];
        acc[0][t] = (f32x4){bv, bv, bv, bv};
        acc[1][t] = acc[0][t];
    }
    #pragma unroll
    for (int s = 0; s < 4; ++s) {
        bf16x8 a[2];
        #pragma unroll
        for (int rt = 0; rt < 2; ++rt)
            a[rt] = *(const bf16x8*)(Aw + (rt * 16 + l16) * SY + s * 32 + quad * 8);
        #pragma unroll
        for (int t = 0; t < 8; ++t) {
            const bf16x8 b = *(const bf16x8*)(Wsw + 32768 + (size_t)((s * 8 + t) * 64 + lane) * 8);
            acc[0][t] = mfma_bf16(a[0], b, acc[0][t]);
            acc[1][t] = mfma_bf16(a[1], b, acc[1][t]);
        }
    }
    #pragma unroll
    for (int rt = 0; rt < 2; ++rt)
        #pragma unroll
        for (int t = 0; t < 8; ++t)
            #pragma unroll
            for (int r = 0; r < 4; ++r)
                Aw[(rt * 16 + quad * 4 + r) * SY + t * 16 + l16] = f2bf(gelu_fast(acc[rt][t][r]));

    // ---- layer 3: [32x128] x [128x128], PERMUTED output cols ----
    #pragma unroll
    for (int t = 0; t < 8; ++t) {
        const float bv = b3[2 * ((t & 3) * 16 + l16) + (t >> 2)];
        acc[0][t] = (f32x4){bv, bv, bv, bv};
        acc[1][t] = acc[0][t];
    }
    #pragma unroll
    for (int s = 0; s < 4; ++s) {
        bf16x8 a[2];
        #pragma unroll
        for (int rt = 0; rt < 2; ++rt)
            a[rt] = *(const bf16x8*)(Aw + (rt * 16 + l16) * SY + s * 32 + quad * 8);
        #pragma unroll
        for (int t = 0; t < 8; ++t) {
            const bf16x8 b = *(const bf16x8*)(Wsw + 49152 + (size_t)((s * 8 + t) * 64 + lane) * 8);
            acc[0][t] = mfma_bf16(a[0], b, acc[0][t]);
            acc[1][t] = mfma_bf16(a[1], b, acc[1][t]);
        }
    }

    // ---- store messages at ORIGINAL edge index (coalesced, no atomics) ----
    #pragma unroll
    for (int rt = 0; rt < 2; ++rt)
        #pragma unroll
        for (int r = 0; r < 4; ++r) {
            const size_t row = e0 + rt * 16 + quad * 4 + r;
            unsigned int* mrow = (unsigned int*)(msg + row * HDIM);
            #pragma unroll
            for (int t = 0; t < 4; ++t) {
                union { _Float16 h[2]; unsigned int u; } pk;
                pk.h[0] = (_Float16)acc[rt][t][r];       // col 2*(t*16+l16)
                pk.h[1] = (_Float16)acc[rt][t + 4][r];   // col 2*(t*16+l16)+1
                mrow[t * 16 + l16] = pk.u;
            }
        }
}

// ---------------------------------------------------------------------------
// Segment-sum gather: x = hV + (sum of node's msg rows)/30, written to xout.
// 32 lanes per node (4 ch/lane), 8 nodes/block, 2500 blocks, zero LDS ->
// high occupancy; latency hidden by TLP.
// ---------------------------------------------------------------------------
__launch_bounds__(256)
__global__ void gather_sum(const _Float16* __restrict__ msg,
                           const int* __restrict__ perm,
                           const int* __restrict__ off,
                           const float* __restrict__ hV,
                           float* __restrict__ xout) {
    const int tid = threadIdx.x;
    const int slot = tid >> 5, l32 = tid & 31;
    const int node = blockIdx.x * 8 + slot;
    const int j0 = off[node], j1 = off[node + 1];
    float a0 = 0.f, a1 = 0.f, a2 = 0.f, a3 = 0.f;
    int j = j0;
    for (; j + 1 < j1; j += 2) {
        const int ea = perm[j], eb = perm[j + 1];
        const half4_t ma = *(const half4_t*)(msg + (size_t)ea * HDIM + l32 * 4);
        const half4_t mb = *(const half4_t*)(msg + (size_t)eb * HDIM + l32 * 4);
        a0 += (float)ma[0] + (float)mb[0];
        a1 += (float)ma[1] + (float)mb[1];
        a2 += (float)ma[2] + (float)mb[2];
        a3 += (float)ma[3] + (float)mb[3];
    }
    if (j < j1) {
        const int ea = perm[j];
        const half4_t ma = *(const half4_t*)(msg + (size_t)ea * HDIM + l32 * 4);
        a0 += (float)ma[0]; a1 += (float)ma[1]; a2 += (float)ma[2]; a3 += (float)ma[3];
    }
    const float4 hv = *(const float4*)(hV + (size_t)node * HDIM + l32 * 4);
    const float4 o = {hv.x + a0 * INV_SCALE, hv.y + a1 * INV_SCALE,
                      hv.z + a2 * INV_SCALE, hv.w + a3 * INV_SCALE};
    *(float4*)(xout + (size_t)node * HDIM + l32 * 4) = o;
}

// ---------------------------------------------------------------------------
// Node update reading precomputed x (= hV + dh/30) from xin. xin aliases out:
// each block reads only its own 32 rows, then overwrites them at the end.
// ---------------------------------------------------------------------------
__launch_bounds__(256)
__global__ void node_mfma_x(const float* __restrict__ xin,
                            const float* __restrict__ n1g, const float* __restrict__ n1b,
                            const ushort_t* __restrict__ D1sw, const float* __restrict__ D1b,
                            const ushort_t* __restrict__ D2sw, const float* __restrict__ D2b,
                            const float* __restrict__ n2g, const float* __restrict__ n2b,
                            float* __restrict__ out) {
    __shared__ __align__(16) float xs[32 * HDIM];
    __shared__ __align__(16) ushort_t h1a[32 * SY];
    __shared__ __align__(16) ushort_t ua[32 * 520];
    __shared__ float mu_s[32], rs_s[32];

    const int tid = threadIdx.x;
    const int wave = tid >> 6, lane = tid & 63;
    const int quad = lane >> 4, l16 = lane & 15;
    const int n0 = blockIdx.x * 32;

    // 1: stage x
    #pragma unroll
    for (int it = 0; it < 4; ++it) {
        const int f4 = it * 256 + tid;
        ((float4*)xs)[f4] = ((const float4*)(xin + (size_t)n0 * HDIM))[f4];
    }
    __syncthreads();

    // 2: LN1 stats
    {
        const int row = tid >> 3, q = tid & 7;
        float s = 0.f, s2 = 0.f;
        #pragma unroll
        for (int c = 0; c < 16; ++c) { const float v = xs[row * HDIM + q * 16 + c]; s += v; s2 += v * v; }
        #pragma unroll
        for (int o = 1; o < 8; o <<= 1) { s += __shfl_xor(s, o); s2 += __shfl_xor(s2, o); }
        if (q == 0) {
            const float m = s * (1.0f / HDIM);
            mu_s[row] = m;
            rs_s[row] = rsqrtf(s2 * (1.0f / HDIM) - m * m + LN_EPS);
        }
    }
    __syncthreads();

    // 3: h1 (bf16, A-layout)
    #pragma unroll
    for (int it = 0; it < 2; ++it) {
        const int g = it * 256 + tid;
        const int row = g >> 4, col = (g & 15) * 8;
        const float mu = mu_s[row], rs = rs_s[row];
        union { bf16x8 v; ushort_t u[8]; } c;
        #pragma unroll
        for (int jj = 0; jj < 8; ++jj) {
            const float h1 = (xs[row * HDIM + col + jj] - mu) * rs * n1g[col + jj] + n1b[col + jj];
            c.u[jj] = f2bf(h1);
        }
        *(bf16x8*)(h1a + row * SY + col) = c.v;
    }
    __syncthreads();

    // 4: u = gelu(h1 @ D1 + b1)
    {
        f32x4 acc1[2][8];
        #pragma unroll
        for (int t = 0; t < 8; ++t) {
            const float bv = D1b[wave * 128 + t * 16 + l16];
            acc1[0][t] = (f32x4){bv, bv, bv, bv};
            acc1[1][t] = acc1[0][t];
        }
        #pragma unroll
        for (int s = 0; s < 4; ++s) {
            bf16x8 a[2];
            #pragma unroll
            for (int rt = 0; rt < 2; ++rt)
                a[rt] = *(const bf16x8*)(h1a + (rt * 16 + l16) * SY + s * 32 + quad * 8);
            #pragma unroll
            for (int t = 0; t < 8; ++t) {
                const bf16x8 b = *(const bf16x8*)(D1sw + (size_t)((s * 32 + wave * 8 + t) * 64 + lane) * 8);
                acc1[0][t] = mfma_bf16(a[0], b, acc1[0][t]);
                acc1[1][t] = mfma_bf16(a[1], b, acc1[1][t]);
            }
        }
        #pragma unroll
        for (int rt = 0; rt < 2; ++rt)
            #pragma unroll
            for (int t = 0; t < 8; ++t)
                #pragma unroll
                for (int r = 0; r < 4; ++r)
                    ua[(rt * 16 + quad * 4 + r) * 520 + wave * 128 + t * 16 + l16] =
                        f2bf(gelu_fast(acc1[rt][t][r]));
    }
    __syncthreads();

    // 6: v = u @ D2
    f32x4 acc2[2][2];
    acc2[0][0] = (f32x4){0,0,0,0}; acc2[0][1] = acc2[0][0];
    acc2[1][0] = acc2[0][0];       acc2[1][1] = acc2[0][0];
    #pragma unroll
    for (int s = 0; s < 16; ++s) {
        bf16x8 a[2];
        #pragma unroll
        for (int rt = 0; rt < 2; ++rt)
            a[rt] = *(const bf16x8*)(ua + (rt * 16 + l16) * 520 + s * 32 + quad * 8);
        #pragma unroll
        for (int tt = 0; tt < 2; ++tt) {
            const bf16x8 b = *(const bf16x8*)(D2sw + (size_t)((s * 8 + wave * 2 + tt) * 64 + lane) * 8);
            acc2[0][tt] = mfma_bf16(a[0], b, acc2[0][tt]);
            acc2[1][tt] = mfma_bf16(a[1], b, acc2[1][tt]);
        }
    }
    __syncthreads();   // all ua reads done before yf aliases it

    // 7: y = h1 + v + b2 (fp32) into yf (aliases ua)
    float* yf = (float*)ua;
    #pragma unroll
    for (int rt = 0; rt < 2; ++rt)
        #pragma unroll
        for (int tt = 0; tt < 2; ++tt)
            #pragma unroll
            for (int r = 0; r < 4; ++r) {
                const int row = rt * 16 + quad * 4 + r;
                const int col = wave * 32 + tt * 16 + l16;
                const float h1 = (xs[row * HDIM + col] - mu_s[row]) * rs_s[row] * n1g[col] + n1b[col];
                yf[row * HDIM + col] = h1 + acc2[rt][tt][r] + D2b[col];
            }
    __syncthreads();

    // 8: LN2 stats
    {
        const int row = tid >> 3, q = tid & 7;
        float s = 0.f, s2 = 0.f;
        #pragma unroll
        for (int c = 0; c < 16; ++c) { const float v = yf[row * HDIM + q * 16 + c]; s += v; s2 += v * v; }
        #pragma unroll
        for (int o = 1; o < 8; o <<= 1) { s += __shfl_xor(s, o); s2 += __shfl_xor(s2, o); }
        if (q == 0) {
            const float m = s * (1.0f / HDIM);
            mu_s[row] = m;
            rs_s[row] = rsqrtf(s2 * (1.0f / HDIM) - m * m + LN_EPS);
        }
    }
    __syncthreads();

    // 9: out = LN2(y)
    #pragma unroll
    for (int it = 0; it < 4; ++it) {
        const int f4 = it * 256 + tid;
        const int row = f4 >> 5, col = (f4 & 31) * 4;
        const float4 y = ((const float4*)yf)[f4];
        const float mu = mu_s[row], rs = rs_s[row];
        float4 o;
        o.x = (y.x - mu) * rs * n2g[col + 0] + n2b[col + 0];
        o.y = (y.y - mu) * rs * n2g[col + 1] + n2b[col + 1];
        o.z = (y.z - mu) * rs * n2g[col + 2] + n2b[col + 2];
        o.w = (y.w - mu) * rs * n2g[col + 3] + n2b[col + 3];
        ((float4*)(out + (size_t)n0 * HDIM))[f4] = o;
    }
}

// ---------------------------------------------------------------------------
// Tier-2: packed-fp16 atomic scatter edge kernel + node kernel reading dh.
// ---------------------------------------------------------------------------
__launch_bounds__(256, 4)
__global__ void edge_mlp_mfma(const float* __restrict__ hE,
                              const int* __restrict__ edge_idx,
                              const ushort_t* __restrict__ Wsw,
                              const float* __restrict__ b1,
                              const float* __restrict__ b2,
                              const float* __restrict__ b3,
                              _Float16* __restrict__ dh) {
    __shared__ ushort_t A2[4][32 * SY];

    const int tid = threadIdx.x;
    const int wave = tid >> 6, lane = tid & 63;
    const int quad = lane >> 4, l16 = lane & 15;
    const size_t e0 = (size_t)blockIdx.x * 128 + wave * 32;
    ushort_t* Aw = A2[wave];

    f32x4 acc[2][8];

    #pragma unroll
    for (int t = 0; t < 8; ++t) {
        const float bv = b1[t * 16 + l16];
        acc[0][t] = (f32x4){bv, bv, bv, bv};
        acc[1][t] = acc[0][t];
    }
    #pragma unroll
    for (int s = 0; s < 8; ++s) {
        bf16x8 a[2];
        #pragma unroll
        for (int rt = 0; rt < 2; ++rt) {
            const float4* p = (const float4*)(hE + (e0 + rt * 16 + l16) * INDIM + s * 32 + quad * 8);
            const float4 v0 = p[0], v1 = p[1];
            bf16x8 av; CVT8(av, v0, v1);
            a[rt] = av;
        }
        #pragma unroll
        for (int t = 0; t < 8; ++t) {
            const bf16x8 b = *(const bf16x8*)(Wsw + (size_t)((s * 8 + t) * 64 + lane) * 8);
            acc[0][t] = mfma_bf16(a[0], b, acc[0][t]);
            acc[1][t] = mfma_bf16(a[1], b, acc[1][t]);
        }
    }
    #pragma unroll
    for (int rt = 0; rt < 2; ++rt)
        #pragma unroll
        for (int t = 0; t < 8; ++t)
            #pragma unroll
            for (int r = 0; r < 4; ++r)
                Aw[(rt * 16 + quad * 4 + r) * SY + t * 16 + l16] = f2bf(gelu_fast(acc[rt][t][r]));

    #pragma unroll
    for (int t = 0; t < 8; ++t) {
        const float bv = b2[t * 16 + l16];
        acc[0][t] = (f32x4){bv, bv, bv, bv};
        acc[1][t] = acc[0][t];
    }
    #pragma unroll
    for (int s = 0; s < 4; ++s) {
        bf16x8 a[2];
        #pragma unroll
        for (int rt = 0; rt < 2; ++rt)
            a[rt] = *(const bf16x8*)(Aw + (rt * 16 + l16) * SY + s * 32 + quad * 8);
        #pragma unroll
        for (int t = 0; t < 8; ++t) {
            const bf16x8 b = *(const bf16x8*)(Wsw + 32768 + (size_t)((s * 8 + t) * 64 + lane) * 8);
            acc[0][t] = mfma_bf16(a[0], b, acc[0][t]);
            acc[1][t] = mfma_bf16(a[1], b, acc[1][t]);
        }
    }
    #pragma unroll
    for (int rt = 0; rt < 2; ++rt)
        #pragma unroll
        for (int t = 0; t < 8; ++t)
            #pragma unroll
            for (int r = 0; r < 4; ++r)
                Aw[(rt * 16 + quad * 4 + r) * SY + t * 16 + l16] = f2bf(gelu_fast(acc[rt][t][r]));

    #pragma unroll
    for (int t = 0; t < 8; ++t) {
        const float bv = b3[2 * ((t & 3) * 16 + l16) + (t >> 2)];
        acc[0][t] = (f32x4){bv, bv, bv, bv};
        acc[1][t] = acc[0][t];
    }
    #pragma unroll
    for (int s = 0; s < 4; ++s) {
        bf16x8 a[2];
        #pragma unroll
        for (int rt = 0; rt < 2; ++rt)
            a[rt] = *(const bf16x8*)(Aw + (rt * 16 + l16) * SY + s * 32 + quad * 8);
        #pragma unroll
        for (int t = 0; t < 8; ++t) {
            const bf16x8 b = *(const bf16x8*)(Wsw + 49152 + (size_t)((s * 8 + t) * 64 + lane) * 8);
            acc[0][t] = mfma_bf16(a[0], b, acc[0][t]);
            acc[1][t] = mfma_bf16(a[1], b, acc[1][t]);
        }
    }

    #pragma unroll
    for (int rt = 0; rt < 2; ++rt)
        #pragma unroll
        for (int r = 0; r < 4; ++r) {
            const int e = (int)e0 + rt * 16 + quad * 4 + r;
            const int s = edge_idx[e];
            _Float16* dst = dh + (size_t)s * HDIM;
            #pragma unroll
            for (int t = 0; t < 4; ++t) {
                const int c = 2 * (t * 16 + l16);
                union { _Float16 h[2]; unsigned int u; } pk;
                pk.h[0] = (_Float16)acc[rt][t][r];
                pk.h[1] = (_Float16)acc[rt][t + 4][r];
                asm volatile("global_atomic_pk_add_f16 %0, %1, off"
                             :: "v"(dst + c), "v"(pk.u) : "memory");
            }
        }
}

__launch_bounds__(256)
__global__ void node_mfma(const float* __restrict__ hV, const _Float16* __restrict__ dh,
                          const float* __restrict__ n1g, const float* __restrict__ n1b,
                          const ushort_t* __restrict__ D1sw, const float* __restrict__ D1b,
                          const ushort_t* __restrict__ D2sw, const float* __restrict__ D2b,
                          const float* __restrict__ n2g, const float* __restrict__ n2b,
                          float* __restrict__ out) {
    __shared__ __align__(16) float xs[32 * HDIM];
    __shared__ __align__(16) ushort_t h1a[32 * SY];
    __shared__ __align__(16) ushort_t ua[32 * 520];
    __shared__ float mu_s[32], rs_s[32];

    const int tid = threadIdx.x;
    const int wave = tid >> 6, lane = tid & 63;
    const int quad = lane >> 4, l16 = lane & 15;
    const int n0 = blockIdx.x * 32;

    #pragma unroll
    for (int it = 0; it < 4; ++it) {
        const int f4 = it * 256 + tid;
        const float4 hv = ((const float4*)(hV + (size_t)n0 * HDIM))[f4];
        const half4_t dv = ((const half4_t*)(dh + (size_t)n0 * HDIM))[f4];
        ((float4*)xs)[f4] = (float4){hv.x + (float)dv[0] * INV_SCALE,
                                     hv.y + (float)dv[1] * INV_SCALE,
                                     hv.z + (float)dv[2] * INV_SCALE,
                                     hv.w + (float)dv[3] * INV_SCALE};
    }
    __syncthreads();

    {
        const int row = tid >> 3, q = tid & 7;
        float s = 0.f, s2 = 0.f;
        #pragma unroll
        for (int c = 0; c < 16; ++c) { const float v = xs[row * HDIM + q * 16 + c]; s += v; s2 += v * v; }
        #pragma unroll
        for (int o = 1; o < 8; o <<= 1) { s += __shfl_xor(s, o); s2 += __shfl_xor(s2, o); }
        if (q == 0) {
            const float m = s * (1.0f / HDIM);
            mu_s[row] = m;
            rs_s[row] = rsqrtf(s2 * (1.0f / HDIM) - m * m + LN_EPS);
        }
    }
    __syncthreads();

    #pragma unroll
    for (int it = 0; it < 2; ++it) {
        const int g = it * 256 + tid;
        const int row = g >> 4, col = (g & 15) * 8;
        const float mu = mu_s[row], rs = rs_s[row];
        union { bf16x8 v; ushort_t u[8]; } c;
        #pragma unroll
        for (int jj = 0; jj < 8; ++jj) {
            const float h1 = (xs[row * HDIM + col + jj] - mu) * rs * n1g[col + jj] + n1b[col + jj];
            c.u[jj] = f2bf(h1);
        }
        *(bf16x8*)(h1a + row * SY + col) = c.v;
    }
    __syncthreads();

    {
        f32x4 acc1[2][8];
        #pragma unroll
        for (int t = 0; t < 8; ++t) {
            const float bv = D1b[wave * 128 + t * 16 + l16];
            acc1[0][t] = (f32x4){bv, bv, bv, bv};
            acc1[1][t] = acc1[0][t];
        }
        #pragma unroll
        for (int s = 0; s < 4; ++s) {
            bf16x8 a[2];
            #pragma unroll
            for (int rt = 0; rt < 2; ++rt)
                a[rt] = *(const bf16x8*)(h1a + (rt * 16 + l16) * SY + s * 32 + quad * 8);
            #pragma unroll
            for (int t = 0; t < 8; ++t) {
                const bf16x8 b = *(const bf16x8*)(D1sw + (size_t)((s * 32 + wave * 8 + t) * 64 + lane) * 8);
                acc1[0][t] = mfma_bf16(a[0], b, acc1[0][t]);
                acc1[1][t] = mfma_bf16(a[1], b, acc1[1][t]);
            }
        }
        #pragma unroll
        for (int rt = 0; rt < 2; ++rt)
            #pragma unroll
            for (int t = 0; t < 8; ++t)
                #pragma unroll
                for (int r = 0; r < 4; ++r)
                    ua[(rt * 16 + quad * 4 + r) * 520 + wave * 128 + t * 16 + l16] =
                        f2bf(gelu_fast(acc1[rt][t][r]));
    }
    __syncthreads();

    f32x4 acc2[2][2];
    acc2[0][0] = (f32x4){0,0,0,0}; acc2[0][1] = acc2[0][0];
    acc2[1][0] = acc2[0][0];       acc2[1][1] = acc2[0][0];
    #pragma unroll
    for (int s = 0; s < 16; ++s) {
        bf16x8 a[2];
        #pragma unroll
        for (int rt = 0; rt < 2; ++rt)
            a[rt] = *(const bf16x8*)(ua + (rt * 16 + l16) * 520 + s * 32 + quad * 8);
        #pragma unroll
        for (int tt = 0; tt < 2; ++tt) {
            const bf16x8 b = *(const bf16x8*)(D2sw + (size_t)((s * 8 + wave * 2 + tt) * 64 + lane) * 8);
            acc2[0][tt] = mfma_bf16(a[0], b, acc2[0][tt]);
            acc2[1][tt] = mfma_bf16(a[1], b, acc2[1][tt]);
        }
    }
    __syncthreads();

    float* yf = (float*)ua;
    #pragma unroll
    for (int rt = 0; rt < 2; ++rt)
        #pragma unroll
        for (int tt = 0; tt < 2; ++tt)
            #pragma unroll
            for (int r = 0; r < 4; ++r) {
                const int row = rt * 16 + quad * 4 + r;
                const int col = wave * 32 + tt * 16 + l16;
                const float h1 = (xs[row * HDIM + col] - mu_s[row]) * rs_s[row] * n1g[col] + n1b[col];
                yf[row * HDIM + col] = h1 + acc2[rt][tt][r] + D2b[col];
            }
    __syncthreads();

    {
        const int row = tid >> 3, q = tid & 7;
        float s = 0.f, s2 = 0.f;
        #pragma unroll
        for (int c = 0; c < 16; ++c) { const float v = yf[row * HDIM + q * 16 + c]; s += v; s2 += v * v; }
        #pragma unroll
        for (int o = 1; o < 8; o <<= 1) { s += __shfl_xor(s, o); s2 += __shfl_xor(s2, o); }
        if (q == 0) {
            const float m = s * (1.0f / HDIM);
            mu_s[row] = m;
            rs_s[row] = rsqrtf(s2 * (1.0f / HDIM) - m * m + LN_EPS);
        }
    }
    __syncthreads();

    #pragma unroll
    for (int it = 0; it < 4; ++it) {
        const int f4 = it * 256 + tid;
        const int row = f4 >> 5, col = (f4 & 31) * 4;
        const float4 y = ((const float4*)yf)[f4];
        const float mu = mu_s[row], rs = rs_s[row];
        float4 o;
        o.x = (y.x - mu) * rs * n2g[col + 0] + n2b[col + 0];
        o.y = (y.y - mu) * rs * n2g[col + 1] + n2b[col + 1];
        o.z = (y.z - mu) * rs * n2g[col + 2] + n2b[col + 2];
        o.w = (y.w - mu) * rs * n2g[col + 3] + n2b[col + 3];
        ((float4*)(out + (size_t)n0 * HDIM))[f4] = o;
    }
}

// ---------------------------------------------------------------------------
// Tier-3 fp32 node fallback.
// ---------------------------------------------------------------------------
#define NT 8
__device__ __forceinline__ void ln_stats32(const float* __restrict__ buf,
                                           float* __restrict__ mu_s,
                                           float* __restrict__ rs_s, int tid) {
    const int g = tid >> 5, lane = tid & 31;
    float s = 0.f, s2 = 0.f;
    #pragma unroll
    for (int c = lane; c < HDIM; c += 32) { const float v = buf[g * HDIM + c]; s += v; s2 += v * v; }
    #pragma unroll
    for (int o = 16; o; o >>= 1) { s += __shfl_xor(s, o, 32); s2 += __shfl_xor(s2, o, 32); }
    if (lane == 0) {
        const float m = s * (1.0f / HDIM);
        mu_s[g] = m;
        rs_s[g] = rsqrtf(s2 * (1.0f / HDIM) - m * m + LN_EPS);
    }
}

__launch_bounds__(256)
__global__ void node_update_f32(const float* __restrict__ hV, const _Float16* __restrict__ dh,
                                const float* __restrict__ n1g, const float* __restrict__ n1b,
                                const float* __restrict__ D1w, const float* __restrict__ D1b,
                                const float* __restrict__ D2w, const float* __restrict__ D2b,
                                const float* __restrict__ n2g, const float* __restrict__ n2b,
                                float* __restrict__ out) {
    __shared__ float h1s[NT * HDIM];
    __shared__ float us[NT * 512];
    __shared__ float vs[2 * NT * HDIM];
    __shared__ float mu_s[NT], rs_s[NT];
    const int tid = threadIdx.x;
    const int n0 = blockIdx.x * NT;
    for (int idx = tid; idx < NT * HDIM; idx += 256) {
        const int i = idx >> 7, c = idx & 127;
        const size_t g = (size_t)(n0 + i) * HDIM + c;
        h1s[idx] = hV[g] + (float)dh[g] * INV_SCALE;
    }
    __syncthreads();
    ln_stats32(h1s, mu_s, rs_s, tid);
    __syncthreads();
    for (int idx = tid; idx < NT * HDIM; idx += 256) {
        const int i = idx >> 7, c = idx & 127;
        h1s[idx] = (h1s[idx] - mu_s[i]) * rs_s[i] * n1g[c] + n1b[c];
    }
    __syncthreads();
    {
        const int o = 2 * tid;
        const float2 bv = *(const float2*)(D1b + o);
        float a0[NT], a1[NT];
        #pragma unroll
        for (int i = 0; i < NT; ++i) { a0[i] = bv.x; a1[i] = bv.y; }
        for (int k = 0; k < HDIM; ++k) {
            const float2 w = *(const float2*)(D1w + (size_t)k * 512 + o);
            #pragma unroll
            for (int i = 0; i < NT; ++i) {
                const float xv = h1s[i * HDIM + k];
                a0[i] += xv * w.x; a1[i] += xv * w.y;
            }
        }
        #pragma unroll
        for (int i = 0; i < NT; ++i) {
            us[i * 512 + o]     = gelu_fast(a0[i]);
            us[i * 512 + o + 1] = gelu_fast(a1[i]);
        }
    }
    __syncthreads();
    {
        const int o = tid & 127, half = tid >> 7;
        float a[NT];
        #pragma unroll
        for (int i = 0; i < NT; ++i) a[i] = 0.f;
        const int k0 = half * 256;
        for (int k = k0; k < k0 + 256; ++k) {
            const float w = D2w[(size_t)k * HDIM + o];
            #pragma unroll
            for (int i = 0; i < NT; ++i) a[i] += us[i * 512 + k] * w;
        }
        #pragma unroll
        for (int i = 0; i < NT; ++i) vs[(half * NT + i) * HDIM + o] = a[i];
    }
    __syncthreads();
    float* ys = us;
    for (int idx = tid; idx < NT * HDIM; idx += 256) {
        const int i = idx >> 7, c = idx & 127;
        ys[idx] = h1s[idx] + vs[i * HDIM + c] + vs[(NT + i) * HDIM + c] + D2b[c];
    }
    __syncthreads();
    ln_stats32(ys, mu_s, rs_s, tid);
    __syncthreads();
    for (int idx = tid; idx < NT * HDIM; idx += 256) {
        const int i = idx >> 7, c = idx & 127;
        out[(size_t)(n0 + i) * HDIM + c] = (ys[idx] - mu_s[i]) * rs_s[i] * n2g[c] + n2b[c];
    }
}

extern "C" void kernel_launch(void* const* d_in, const int* in_sizes, int n_in,
                              void* d_out, int out_size, void* d_ws, size_t ws_size,
                              hipStream_t stream) {
    const float* hV  = (const float*)d_in[0];
    const float* hE  = (const float*)d_in[1];
    const int*  eidx = (const int*)d_in[2];
    const float* W1w = (const float*)d_in[3];
    const float* W1b = (const float*)d_in[4];
    const float* W2w = (const float*)d_in[5];
    const float* W2b = (const float*)d_in[6];
    const float* W3w = (const float*)d_in[7];
    const float* W3b = (const float*)d_in[8];
    const float* n1g = (const float*)d_in[9];
    const float* n1b = (const float*)d_in[10];
    const float* D1w = (const float*)d_in[11];
    const float* D1b = (const float*)d_in[12];
    const float* D2w = (const float*)d_in[13];
    const float* D2b = (const float*)d_in[14];
    const float* n2g = (const float*)d_in[15];
    const float* n2b = (const float*)d_in[16];
    float* out = (float*)d_out;

    // tier-1 layout: msg | WswE | D1sw | D2sw | perm | cnt | off | off2
    // (x-buffer lives in d_out: gather_sum writes it, node_mfma_x rewrites it)
    const size_t MSG_BYTES = (size_t)NEDGES * HDIM * sizeof(_Float16);  // 81,920,000
    const size_t EW_BYTES  = 65536 * 2;
    const size_t T1_BYTES  = MSG_BYTES + 3 * EW_BYTES
                           + (size_t)NEDGES * 4 + (size_t)NNODES * 4
                           + (size_t)(NNODES + 1) * 4 + (size_t)NNODES * 4;
    const size_t DH_BYTES  = (size_t)NNODES * HDIM * sizeof(_Float16);  // 5,120,000
    const size_t T2_BYTES  = DH_BYTES + 3 * EW_BYTES;

    if (ws_size >= T1_BYTES) {
        char* p = (char*)d_ws;
        _Float16* msg  = (_Float16*)p;            p += MSG_BYTES;
        ushort_t* WswE = (ushort_t*)p;            p += EW_BYTES;
        ushort_t* D1sw = (ushort_t*)p;            p += EW_BYTES;
        ushort_t* D2sw = (ushort_t*)p;            p += EW_BYTES;
        int* perm = (int*)p;                      p += (size_t)NEDGES * 4;
        int* cnt  = (int*)p;                      p += (size_t)NNODES * 4;
        int* off  = (int*)p;                      p += (size_t)(NNODES + 1) * 4;
        int* off2 = (int*)p;

        hipMemsetAsync(cnt, 0, (size_t)NNODES * 4, stream);
        prep_edge_weights<<<256, 256, 0, stream>>>(W1w, W2w, W3w, WswE);
        prep_node_weights<<<512, 256, 0, stream>>>(D1w, D2w, D1sw, D2sw);
        edge_hist<<<(NEDGES + 255) / 256, 256, 0, stream>>>(eidx, cnt);
        scan_counts<<<1, 1024, 0, stream>>>(cnt, off, off2);
        fill_perm<<<(NEDGES + 255) / 256, 256, 0, stream>>>(eidx, off2, perm);
        edge_mlp_stream<<<NEDGES / 128, 256, 0, stream>>>(hE, WswE, W1b, W2b, W3b, msg);
        gather_sum<<<NNODES / 8, 256, 0, stream>>>(msg, perm, off, hV, out);
        node_mfma_x<<<NNODES / 32, 256, 0, stream>>>(out, n1g, n1b,
                                                     D1sw, D1b, D2sw, D2b, n2g, n2b, out);
    } else if (ws_size >= T2_BYTES) {
        _Float16* dh = (_Float16*)d_ws;
        ushort_t* WswE = (ushort_t*)((char*)d_ws + DH_BYTES);
        ushort_t* D1sw = (ushort_t*)((char*)d_ws + DH_BYTES + EW_BYTES);
        ushort_t* D2sw = (ushort_t*)((char*)d_ws + DH_BYTES + 2 * EW_BYTES);
        hipMemsetAsync(dh, 0, DH_BYTES, stream);
        prep_edge_weights<<<256, 256, 0, stream>>>(W1w, W2w, W3w, WswE);
        prep_node_weights<<<512, 256, 0, stream>>>(D1w, D2w, D1sw, D2sw);
        edge_mlp_mfma<<<NEDGES / 128, 256, 0, stream>>>(hE, eidx, WswE, W1b, W2b, W3b, dh);
        node_mfma<<<NNODES / 32, 256, 0, stream>>>(hV, dh, n1g, n1b, D1sw, D1b, D2sw, D2b, n2g, n2b, out);
    } else {
        _Float16* dh = (_Float16*)d_ws;
        ushort_t* WswE = (ushort_t*)((char*)d_out + (size_t)out_size * 4 - EW_BYTES);
        hipMemsetAsync(dh, 0, DH_BYTES, stream);
        prep_edge_weights<<<256, 256, 0, stream>>>(W1w, W2w, W3w, WswE);
        edge_mlp_mfma<<<NEDGES / 128, 256, 0, stream>>>(hE, eidx, WswE, W1b, W2b, W3b, dh);
        node_update_f32<<<NNODES / NT, 256, 0, stream>>>(hV, dh, n1g, n1b, D1w, D1b, D2w, D2b, n2g, n2b, out);
    }
}

// Round 5
// 627.810 us; speedup vs baseline: 1.1014x; 1.0882x over previous
//
#include <hip/hip_runtime.h>
#include <hip/hip_bf16.h>
#include <math.h>

#define NNODES 20000
#define NEDGES 320000
#define HDIM   128
#define INDIM  256
#define INV_SCALE (1.0f/30.0f)
#define LN_EPS 1e-5f

typedef __bf16 bf16x8 __attribute__((ext_vector_type(8)));
typedef float  f32x4  __attribute__((ext_vector_type(4)));
typedef _Float16 half4_t __attribute__((ext_vector_type(4)));
typedef _Float16 half8_t __attribute__((ext_vector_type(8)));
typedef unsigned short ushort_t;

__device__ __forceinline__ unsigned short f2bf(float f) {
    union { __hip_bfloat16 h; unsigned short u; } c;
    c.h = __float2bfloat16(f);
    return c.u;
}

// Fast gelu: x * sigmoid(1.5957691*x + 0.0713548*x^3)  (tanh-form, max |err| ~1e-3)
__device__ __forceinline__ float gelu_fast(float x) {
    const float z = x * (1.595769122f + 0.071354816f * x * x);
    return x / (1.0f + __expf(-z));
}

__device__ __forceinline__ f32x4 mfma_bf16(bf16x8 a, bf16x8 b, f32x4 c) {
    return __builtin_amdgcn_mfma_f32_16x16x32_bf16(a, b, c, 0, 0, 0);
}

#define CVT8(dst, v0, v1) { union { bf16x8 v; ushort_t u[8]; } c_; \
    c_.u[0] = f2bf((v0).x); c_.u[1] = f2bf((v0).y); c_.u[2] = f2bf((v0).z); c_.u[3] = f2bf((v0).w); \
    c_.u[4] = f2bf((v1).x); c_.u[5] = f2bf((v1).y); c_.u[6] = f2bf((v1).z); c_.u[7] = f2bf((v1).w); \
    (dst) = c_.v; }

// ---------------------------------------------------------------------------
// Combined prep: edge weights + node weights + edge histogram in one launch.
// B-fragment order for mfma_f32_16x16x32_bf16: frag (s,T), lane L, elem j holds
// W[k = s*32 + (L>>4)*8 + j][n], lane's 8 bf16 contiguous. Frag f at
// Wsw[(f*64+L)*8+j], f = s*8+T. W1 base 0, W2 base 32768, W3 base 49152.
//
// W3 col permutation (for dword-packed msg stores, wave-sliced edge kernel):
// frag T, fragment col l16 -> actual col n3 = 2*((T>>1)*16 + l16) + (T&1).
// So frag pair (2u, 2u+1) = adjacent actual cols (2*(u*16+l16), +1).
// ---------------------------------------------------------------------------
__global__ void prep_all(const float* __restrict__ W1, const float* __restrict__ W2,
                         const float* __restrict__ W3, ushort_t* __restrict__ WswE,
                         const float* __restrict__ D1, const float* __restrict__ D2,
                         ushort_t* __restrict__ D1sw, ushort_t* __restrict__ D2sw,
                         const int* __restrict__ src, int* __restrict__ cnt) {
    const int id = blockIdx.x * 256 + threadIdx.x;
    if (id < 65536) {
        const float* W; int base, idx; bool perm = false;
        if (id < 32768)      { W = W1; base = 0;     idx = id; }
        else if (id < 49152) { W = W2; base = 32768; idx = id - 32768; }
        else                 { W = W3; base = 49152; idx = id - 49152; perm = true; }
        const int j = idx & 7, lane = (idx >> 3) & 63, t = (idx >> 9) & 7, s = idx >> 12;
        const int k = s * 32 + (lane >> 4) * 8 + j;
        const int n = perm ? (2 * ((t >> 1) * 16 + (lane & 15)) + (t & 1))
                           : (t * 16 + (lane & 15));
        WswE[base + idx] = f2bf(W[k * HDIM + n]);
    } else if (id < 196608) {
        const int nid = id - 65536;   // 0..131071
        if (nid < 65536) {
            const int idx = nid;
            const int j = idx & 7, lane = (idx >> 3) & 63, f = idx >> 9;   // f = s*32+t
            const int t = f & 31, s = f >> 5;
            const int k = s * 32 + (lane >> 4) * 8 + j;
            const int n = t * 16 + (lane & 15);
            D1sw[idx] = f2bf(D1[k * 512 + n]);
        } else {
            const int idx = nid - 65536;
            const int j = idx & 7, lane = (idx >> 3) & 63, f = idx >> 9;   // f = s*8+t
            const int t = f & 7, s = f >> 3;
            const int k = s * 32 + (lane >> 4) * 8 + j;
            const int n = t * 16 + (lane & 15);
            D2sw[idx] = f2bf(D2[k * HDIM + n]);
        }
    } else {
        const int e = id - 196608;
        if (e < NEDGES) atomicAdd(&cnt[src[e]], 1);
    }
}

// ---------------------------------------------------------------------------
// CSR scan + perm fill.
// ---------------------------------------------------------------------------
__launch_bounds__(1024)
__global__ void scan_counts(const int* __restrict__ cnt,
                            int* __restrict__ off, int* __restrict__ off2) {
    __shared__ int tot[1024];
    const int t = threadIdx.x;
    const int base = t * 20;                 // 1024*20 = 20480 >= NNODES
    int local[20]; int s = 0;
    #pragma unroll
    for (int i = 0; i < 20; ++i) {
        const int v = (base + i < NNODES) ? cnt[base + i] : 0;
        local[i] = s; s += v;
    }
    tot[t] = s;
    __syncthreads();
    for (int d = 1; d < 1024; d <<= 1) {
        const int v = (t >= d) ? tot[t - d] : 0;
        __syncthreads();
        tot[t] += v;
        __syncthreads();
    }
    const int excl = (t == 0) ? 0 : tot[t - 1];
    #pragma unroll
    for (int i = 0; i < 20; ++i)
        if (base + i < NNODES) { off[base + i] = excl + local[i]; off2[base + i] = excl + local[i]; }
    if (t == 1023) off[NNODES] = NEDGES;
}

__global__ void fill_perm(const int* __restrict__ src, int* __restrict__ off2,
                          int* __restrict__ perm) {
    const int e = blockIdx.x * 256 + threadIdx.x;
    if (e < NEDGES) {
        const int p = atomicAdd(&off2[src[e]], 1);
        perm[p] = e;
    }
}

// ---------------------------------------------------------------------------
// Edge MLP v2: block = 64 edges, 4 waves. hE staged to LDS once as bf16 (all
// loads issued upfront, streaming). Each wave owns a 32-col output slice for
// ALL 64 edges -> only 32 B-fragment loads per wave (4x MFMA reuse each),
// explicitly double-buffered. A-fragments via ds_read_b128. Zero atomics.
// LDS 52.2 KB -> 3 blocks/CU.
// ---------------------------------------------------------------------------
#define A1S 272   // A1 row stride (bf16): 256 + 16 pad (544 B: row bank step 8 -> 2-way, free)
#define SY  136   // A2 row stride (bf16): 128 + 8 pad

__launch_bounds__(256, 3)
__global__ void edge_mlp_v2(const float* __restrict__ hE,
                            const ushort_t* __restrict__ Wsw,
                            const float* __restrict__ b1,
                            const float* __restrict__ b2,
                            const float* __restrict__ b3,
                            _Float16* __restrict__ msg) {
    __shared__ __align__(16) ushort_t A1[64 * A1S];   // 34816 B
    __shared__ __align__(16) ushort_t A2[64 * SY];    // 17408 B

    const int tid = threadIdx.x;
    const int wave = tid >> 6, lane = tid & 63;
    const int quad = lane >> 4, l16 = lane & 15;
    const size_t e0 = (size_t)blockIdx.x * 64;
    const int T0 = wave * 2;                 // wave's two global col-frags: T0, T0+1

    // ---- stage hE (fp32 -> bf16) into A1: thread = (row, quarter of 64 ch) ----
    {
        const int row = tid >> 2, q = tid & 3;
        const float4* src = (const float4*)(hE + (e0 + row) * INDIM + q * 64);
        ushort_t* dst = A1 + row * A1S + q * 64;
        #pragma unroll
        for (int i = 0; i < 8; ++i) {
            const float4 v0 = src[2 * i], v1 = src[2 * i + 1];
            bf16x8 a; CVT8(a, v0, v1);
            *(bf16x8*)(dst + i * 8) = a;
        }
    }

    f32x4 acc[4][2];
    bf16x8 bcur[2], bnxt[2];

    // ---- layer 1: [64x256] x [256 x 32-slice], B depth-2 prefetch ----
    #pragma unroll
    for (int t = 0; t < 2; ++t) {
        const float bv = b1[(T0 + t) * 16 + l16];
        #pragma unroll
        for (int rt = 0; rt < 4; ++rt) acc[rt][t] = (f32x4){bv, bv, bv, bv};
    }
    bcur[0] = *(const bf16x8*)(Wsw + (size_t)((0 * 8 + T0 + 0) * 64 + lane) * 8);
    bcur[1] = *(const bf16x8*)(Wsw + (size_t)((0 * 8 + T0 + 1) * 64 + lane) * 8);
    __syncthreads();
    #pragma unroll
    for (int s = 0; s < 8; ++s) {
        if (s < 7) {
            bnxt[0] = *(const bf16x8*)(Wsw + (size_t)(((s + 1) * 8 + T0 + 0) * 64 + lane) * 8);
            bnxt[1] = *(const bf16x8*)(Wsw + (size_t)(((s + 1) * 8 + T0 + 1) * 64 + lane) * 8);
        }
        bf16x8 a[4];
        #pragma unroll
        for (int rt = 0; rt < 4; ++rt)
            a[rt] = *(const bf16x8*)(A1 + (rt * 16 + l16) * A1S + s * 32 + quad * 8);
        #pragma unroll
        for (int rt = 0; rt < 4; ++rt) {
            acc[rt][0] = mfma_bf16(a[rt], bcur[0], acc[rt][0]);
            acc[rt][1] = mfma_bf16(a[rt], bcur[1], acc[rt][1]);
        }
        bcur[0] = bnxt[0]; bcur[1] = bnxt[1];
    }
    // write gelu(h1) slice: col (T0+t)*16+l16, row rt*16+quad*4+r
    #pragma unroll
    for (int rt = 0; rt < 4; ++rt)
        #pragma unroll
        for (int t = 0; t < 2; ++t)
            #pragma unroll
            for (int r = 0; r < 4; ++r)
                A2[(rt * 16 + quad * 4 + r) * SY + (T0 + t) * 16 + l16] =
                    f2bf(gelu_fast(acc[rt][t][r]));
    __syncthreads();

    // ---- layer 2: [64x128] x [128 x 32-slice] ----
    #pragma unroll
    for (int t = 0; t < 2; ++t) {
        const float bv = b2[(T0 + t) * 16 + l16];
        #pragma unroll
        for (int rt = 0; rt < 4; ++rt) acc[rt][t] = (f32x4){bv, bv, bv, bv};
    }
    bcur[0] = *(const bf16x8*)(Wsw + 32768 + (size_t)((0 * 8 + T0 + 0) * 64 + lane) * 8);
    bcur[1] = *(const bf16x8*)(Wsw + 32768 + (size_t)((0 * 8 + T0 + 1) * 64 + lane) * 8);
    #pragma unroll
    for (int s = 0; s < 4; ++s) {
        if (s < 3) {
            bnxt[0] = *(const bf16x8*)(Wsw + 32768 + (size_t)(((s + 1) * 8 + T0 + 0) * 64 + lane) * 8);
            bnxt[1] = *(const bf16x8*)(Wsw + 32768 + (size_t)(((s + 1) * 8 + T0 + 1) * 64 + lane) * 8);
        }
        bf16x8 a[4];
        #pragma unroll
        for (int rt = 0; rt < 4; ++rt)
            a[rt] = *(const bf16x8*)(A2 + (rt * 16 + l16) * SY + s * 32 + quad * 8);
        #pragma unroll
        for (int rt = 0; rt < 4; ++rt) {
            acc[rt][0] = mfma_bf16(a[rt], bcur[0], acc[rt][0]);
            acc[rt][1] = mfma_bf16(a[rt], bcur[1], acc[rt][1]);
        }
        bcur[0] = bnxt[0]; bcur[1] = bnxt[1];
    }
    __syncthreads();   // all waves' h1 reads complete before overwrite
    #pragma unroll
    for (int rt = 0; rt < 4; ++rt)
        #pragma unroll
        for (int t = 0; t < 2; ++t)
            #pragma unroll
            for (int r = 0; r < 4; ++r)
                A2[(rt * 16 + quad * 4 + r) * SY + (T0 + t) * 16 + l16] =
                    f2bf(gelu_fast(acc[rt][t][r]));
    __syncthreads();

    // ---- layer 3: PERMUTED cols; acc[.][0]/acc[.][1] = adjacent actual cols ----
    #pragma unroll
    for (int t = 0; t < 2; ++t) {
        const float bv = b3[2 * (wave * 16 + l16) + t];
        #pragma unroll
        for (int rt = 0; rt < 4; ++rt) acc[rt][t] = (f32x4){bv, bv, bv, bv};
    }
    bcur[0] = *(const bf16x8*)(Wsw + 49152 + (size_t)((0 * 8 + T0 + 0) * 64 + lane) * 8);
    bcur[1] = *(const bf16x8*)(Wsw + 49152 + (size_t)((0 * 8 + T0 + 1) * 64 + lane) * 8);
    #pragma unroll
    for (int s = 0; s < 4; ++s) {
        if (s < 3) {
            bnxt[0] = *(const bf16x8*)(Wsw + 49152 + (size_t)(((s + 1) * 8 + T0 + 0) * 64 + lane) * 8);
            bnxt[1] = *(const bf16x8*)(Wsw + 49152 + (size_t)(((s + 1) * 8 + T0 + 1) * 64 + lane) * 8);
        }
        bf16x8 a[4];
        #pragma unroll
        for (int rt = 0; rt < 4; ++rt)
            a[rt] = *(const bf16x8*)(A2 + (rt * 16 + l16) * SY + s * 32 + quad * 8);
        #pragma unroll
        for (int rt = 0; rt < 4; ++rt) {
            acc[rt][0] = mfma_bf16(a[rt], bcur[0], acc[rt][0]);
            acc[rt][1] = mfma_bf16(a[rt], bcur[1], acc[rt][1]);
        }
        bcur[0] = bnxt[0]; bcur[1] = bnxt[1];
    }

    // ---- store msg: dword (cols 2*(wave*16+l16), +1) per (rt,r) row ----
    #pragma unroll
    for (int rt = 0; rt < 4; ++rt)
        #pragma unroll
        for (int r = 0; r < 4; ++r) {
            const size_t row = e0 + rt * 16 + quad * 4 + r;
            union { _Float16 h[2]; unsigned int u; } pk;
            pk.h[0] = (_Float16)acc[rt][0][r];
            pk.h[1] = (_Float16)acc[rt][1][r];
            ((unsigned int*)(msg + row * HDIM))[wave * 16 + l16] = pk.u;
        }
}

// ---------------------------------------------------------------------------
// Segment-sum gather: x = hV + (sum of node's msg rows)/30, written to xout.
// 32 lanes per node (4 ch/lane), 8 nodes/block, zero LDS -> high occupancy.
// ---------------------------------------------------------------------------
__launch_bounds__(256)
__global__ void gather_sum(const _Float16* __restrict__ msg,
                           const int* __restrict__ perm,
                           const int* __restrict__ off,
                           const float* __restrict__ hV,
                           float* __restrict__ xout) {
    const int tid = threadIdx.x;
    const int slot = tid >> 5, l32 = tid & 31;
    const int node = blockIdx.x * 8 + slot;
    const int j0 = off[node], j1 = off[node + 1];
    float a0 = 0.f, a1 = 0.f, a2 = 0.f, a3 = 0.f;
    int j = j0;
    for (; j + 1 < j1; j += 2) {
        const int ea = perm[j], eb = perm[j + 1];
        const half4_t ma = *(const half4_t*)(msg + (size_t)ea * HDIM + l32 * 4);
        const half4_t mb = *(const half4_t*)(msg + (size_t)eb * HDIM + l32 * 4);
        a0 += (float)ma[0] + (float)mb[0];
        a1 += (float)ma[1] + (float)mb[1];
        a2 += (float)ma[2] + (float)mb[2];
        a3 += (float)ma[3] + (float)mb[3];
    }
    if (j < j1) {
        const int ea = perm[j];
        const half4_t ma = *(const half4_t*)(msg + (size_t)ea * HDIM + l32 * 4);
        a0 += (float)ma[0]; a1 += (float)ma[1]; a2 += (float)ma[2]; a3 += (float)ma[3];
    }
    const float4 hv = *(const float4*)(hV + (size_t)node * HDIM + l32 * 4);
    const float4 o = {hv.x + a0 * INV_SCALE, hv.y + a1 * INV_SCALE,
                      hv.z + a2 * INV_SCALE, hv.w + a3 * INV_SCALE};
    *(float4*)(xout + (size_t)node * HDIM + l32 * 4) = o;
}

// ---------------------------------------------------------------------------
// Node update reading precomputed x (= hV + dh/30) from xin. xin aliases out:
// each block reads only its own 32 rows, then overwrites them at the end.
// ---------------------------------------------------------------------------
__launch_bounds__(256)
__global__ void node_mfma_x(const float* __restrict__ xin,
                            const float* __restrict__ n1g, const float* __restrict__ n1b,
                            const ushort_t* __restrict__ D1sw, const float* __restrict__ D1b,
                            const ushort_t* __restrict__ D2sw, const float* __restrict__ D2b,
                            const float* __restrict__ n2g, const float* __restrict__ n2b,
                            float* __restrict__ out) {
    __shared__ __align__(16) float xs[32 * HDIM];
    __shared__ __align__(16) ushort_t h1a[32 * SY];
    __shared__ __align__(16) ushort_t ua[32 * 520];
    __shared__ float mu_s[32], rs_s[32];

    const int tid = threadIdx.x;
    const int wave = tid >> 6, lane = tid & 63;
    const int quad = lane >> 4, l16 = lane & 15;
    const int n0 = blockIdx.x * 32;

    #pragma unroll
    for (int it = 0; it < 4; ++it) {
        const int f4 = it * 256 + tid;
        ((float4*)xs)[f4] = ((const float4*)(xin + (size_t)n0 * HDIM))[f4];
    }
    __syncthreads();

    {
        const int row = tid >> 3, q = tid & 7;
        float s = 0.f, s2 = 0.f;
        #pragma unroll
        for (int c = 0; c < 16; ++c) { const float v = xs[row * HDIM + q * 16 + c]; s += v; s2 += v * v; }
        #pragma unroll
        for (int o = 1; o < 8; o <<= 1) { s += __shfl_xor(s, o); s2 += __shfl_xor(s2, o); }
        if (q == 0) {
            const float m = s * (1.0f / HDIM);
            mu_s[row] = m;
            rs_s[row] = rsqrtf(s2 * (1.0f / HDIM) - m * m + LN_EPS);
        }
    }
    __syncthreads();

    #pragma unroll
    for (int it = 0; it < 2; ++it) {
        const int g = it * 256 + tid;
        const int row = g >> 4, col = (g & 15) * 8;
        const float mu = mu_s[row], rs = rs_s[row];
        union { bf16x8 v; ushort_t u[8]; } c;
        #pragma unroll
        for (int jj = 0; jj < 8; ++jj) {
            const float h1 = (xs[row * HDIM + col + jj] - mu) * rs * n1g[col + jj] + n1b[col + jj];
            c.u[jj] = f2bf(h1);
        }
        *(bf16x8*)(h1a + row * SY + col) = c.v;
    }
    __syncthreads();

    {
        f32x4 acc1[2][8];
        #pragma unroll
        for (int t = 0; t < 8; ++t) {
            const float bv = D1b[wave * 128 + t * 16 + l16];
            acc1[0][t] = (f32x4){bv, bv, bv, bv};
            acc1[1][t] = acc1[0][t];
        }
        #pragma unroll
        for (int s = 0; s < 4; ++s) {
            bf16x8 a[2];
            #pragma unroll
            for (int rt = 0; rt < 2; ++rt)
                a[rt] = *(const bf16x8*)(h1a + (rt * 16 + l16) * SY + s * 32 + quad * 8);
            #pragma unroll
            for (int t = 0; t < 8; ++t) {
                const bf16x8 b = *(const bf16x8*)(D1sw + (size_t)((s * 32 + wave * 8 + t) * 64 + lane) * 8);
                acc1[0][t] = mfma_bf16(a[0], b, acc1[0][t]);
                acc1[1][t] = mfma_bf16(a[1], b, acc1[1][t]);
            }
        }
        #pragma unroll
        for (int rt = 0; rt < 2; ++rt)
            #pragma unroll
            for (int t = 0; t < 8; ++t)
                #pragma unroll
                for (int r = 0; r < 4; ++r)
                    ua[(rt * 16 + quad * 4 + r) * 520 + wave * 128 + t * 16 + l16] =
                        f2bf(gelu_fast(acc1[rt][t][r]));
    }
    __syncthreads();

    f32x4 acc2[2][2];
    acc2[0][0] = (f32x4){0,0,0,0}; acc2[0][1] = acc2[0][0];
    acc2[1][0] = acc2[0][0];       acc2[1][1] = acc2[0][0];
    #pragma unroll
    for (int s = 0; s < 16; ++s) {
        bf16x8 a[2];
        #pragma unroll
        for (int rt = 0; rt < 2; ++rt)
            a[rt] = *(const bf16x8*)(ua + (rt * 16 + l16) * 520 + s * 32 + quad * 8);
        #pragma unroll
        for (int tt = 0; tt < 2; ++tt) {
            const bf16x8 b = *(const bf16x8*)(D2sw + (size_t)((s * 8 + wave * 2 + tt) * 64 + lane) * 8);
            acc2[0][tt] = mfma_bf16(a[0], b, acc2[0][tt]);
            acc2[1][tt] = mfma_bf16(a[1], b, acc2[1][tt]);
        }
    }
    __syncthreads();

    float* yf = (float*)ua;
    #pragma unroll
    for (int rt = 0; rt < 2; ++rt)
        #pragma unroll
        for (int tt = 0; tt < 2; ++tt)
            #pragma unroll
            for (int r = 0; r < 4; ++r) {
                const int row = rt * 16 + quad * 4 + r;
                const int col = wave * 32 + tt * 16 + l16;
                const float h1 = (xs[row * HDIM + col] - mu_s[row]) * rs_s[row] * n1g[col] + n1b[col];
                yf[row * HDIM + col] = h1 + acc2[rt][tt][r] + D2b[col];
            }
    __syncthreads();

    {
        const int row = tid >> 3, q = tid & 7;
        float s = 0.f, s2 = 0.f;
        #pragma unroll
        for (int c = 0; c < 16; ++c) { const float v = yf[row * HDIM + q * 16 + c]; s += v; s2 += v * v; }
        #pragma unroll
        for (int o = 1; o < 8; o <<= 1) { s += __shfl_xor(s, o); s2 += __shfl_xor(s2, o); }
        if (q == 0) {
            const float m = s * (1.0f / HDIM);
            mu_s[row] = m;
            rs_s[row] = rsqrtf(s2 * (1.0f / HDIM) - m * m + LN_EPS);
        }
    }
    __syncthreads();

    #pragma unroll
    for (int it = 0; it < 4; ++it) {
        const int f4 = it * 256 + tid;
        const int row = f4 >> 5, col = (f4 & 31) * 4;
        const float4 y = ((const float4*)yf)[f4];
        const float mu = mu_s[row], rs = rs_s[row];
        float4 o;
        o.x = (y.x - mu) * rs * n2g[col + 0] + n2b[col + 0];
        o.y = (y.y - mu) * rs * n2g[col + 1] + n2b[col + 1];
        o.z = (y.z - mu) * rs * n2g[col + 2] + n2b[col + 2];
        o.w = (y.w - mu) * rs * n2g[col + 3] + n2b[col + 3];
        ((float4*)(out + (size_t)n0 * HDIM))[f4] = o;
    }
}

// ---------------------------------------------------------------------------
// Tier-2: packed-fp16 atomic scatter edge kernel (uses the NEW W3 perm:
// frag pair (2u, 2u+1) = adjacent cols) + node kernel reading dh.
// ---------------------------------------------------------------------------
__launch_bounds__(256, 4)
__global__ void edge_mlp_mfma(const float* __restrict__ hE,
                              const int* __restrict__ edge_idx,
                              const ushort_t* __restrict__ Wsw,
                              const float* __restrict__ b1,
                              const float* __restrict__ b2,
                              const float* __restrict__ b3,
                              _Float16* __restrict__ dh) {
    __shared__ ushort_t A2[4][32 * SY];

    const int tid = threadIdx.x;
    const int wave = tid >> 6, lane = tid & 63;
    const int quad = lane >> 4, l16 = lane & 15;
    const size_t e0 = (size_t)blockIdx.x * 128 + wave * 32;
    ushort_t* Aw = A2[wave];

    f32x4 acc[2][8];

    #pragma unroll
    for (int t = 0; t < 8; ++t) {
        const float bv = b1[t * 16 + l16];
        acc[0][t] = (f32x4){bv, bv, bv, bv};
        acc[1][t] = acc[0][t];
    }
    #pragma unroll
    for (int s = 0; s < 8; ++s) {
        bf16x8 a[2];
        #pragma unroll
        for (int rt = 0; rt < 2; ++rt) {
            const float4* p = (const float4*)(hE + (e0 + rt * 16 + l16) * INDIM + s * 32 + quad * 8);
            const float4 v0 = p[0], v1 = p[1];
            bf16x8 av; CVT8(av, v0, v1);
            a[rt] = av;
        }
        #pragma unroll
        for (int t = 0; t < 8; ++t) {
            const bf16x8 b = *(const bf16x8*)(Wsw + (size_t)((s * 8 + t) * 64 + lane) * 8);
            acc[0][t] = mfma_bf16(a[0], b, acc[0][t]);
            acc[1][t] = mfma_bf16(a[1], b, acc[1][t]);
        }
    }
    #pragma unroll
    for (int rt = 0; rt < 2; ++rt)
        #pragma unroll
        for (int t = 0; t < 8; ++t)
            #pragma unroll
            for (int r = 0; r < 4; ++r)
                Aw[(rt * 16 + quad * 4 + r) * SY + t * 16 + l16] = f2bf(gelu_fast(acc[rt][t][r]));

    #pragma unroll
    for (int t = 0; t < 8; ++t) {
        const float bv = b2[t * 16 + l16];
        acc[0][t] = (f32x4){bv, bv, bv, bv};
        acc[1][t] = acc[0][t];
    }
    #pragma unroll
    for (int s = 0; s < 4; ++s) {
        bf16x8 a[2];
        #pragma unroll
        for (int rt = 0; rt < 2; ++rt)
            a[rt] = *(const bf16x8*)(Aw + (rt * 16 + l16) * SY + s * 32 + quad * 8);
        #pragma unroll
        for (int t = 0; t < 8; ++t) {
            const bf16x8 b = *(const bf16x8*)(Wsw + 32768 + (size_t)((s * 8 + t) * 64 + lane) * 8);
            acc[0][t] = mfma_bf16(a[0], b, acc[0][t]);
            acc[1][t] = mfma_bf16(a[1], b, acc[1][t]);
        }
    }
    #pragma unroll
    for (int rt = 0; rt < 2; ++rt)
        #pragma unroll
        for (int t = 0; t < 8; ++t)
            #pragma unroll
            for (int r = 0; r < 4; ++r)
                Aw[(rt * 16 + quad * 4 + r) * SY + t * 16 + l16] = f2bf(gelu_fast(acc[rt][t][r]));

    #pragma unroll
    for (int t = 0; t < 8; ++t) {
        const float bv = b3[2 * ((t >> 1) * 16 + l16) + (t & 1)];
        acc[0][t] = (f32x4){bv, bv, bv, bv};
        acc[1][t] = acc[0][t];
    }
    #pragma unroll
    for (int s = 0; s < 4; ++s) {
        bf16x8 a[2];
        #pragma unroll
        for (int rt = 0; rt < 2; ++rt)
            a[rt] = *(const bf16x8*)(Aw + (rt * 16 + l16) * SY + s * 32 + quad * 8);
        #pragma unroll
        for (int t = 0; t < 8; ++t) {
            const bf16x8 b = *(const bf16x8*)(Wsw + 49152 + (size_t)((s * 8 + t) * 64 + lane) * 8);
            acc[0][t] = mfma_bf16(a[0], b, acc[0][t]);
            acc[1][t] = mfma_bf16(a[1], b, acc[1][t]);
        }
    }

    #pragma unroll
    for (int rt = 0; rt < 2; ++rt)
        #pragma unroll
        for (int r = 0; r < 4; ++r) {
            const int e = (int)e0 + rt * 16 + quad * 4 + r;
            const int s = edge_idx[e];
            _Float16* dst = dh + (size_t)s * HDIM;
            #pragma unroll
            for (int u = 0; u < 4; ++u) {
                const int c = 2 * (u * 16 + l16);
                union { _Float16 h[2]; unsigned int u32; } pk;
                pk.h[0] = (_Float16)acc[rt][2 * u][r];
                pk.h[1] = (_Float16)acc[rt][2 * u + 1][r];
                asm volatile("global_atomic_pk_add_f16 %0, %1, off"
                             :: "v"(dst + c), "v"(pk.u32) : "memory");
            }
        }
}

__launch_bounds__(256)
__global__ void node_mfma(const float* __restrict__ hV, const _Float16* __restrict__ dh,
                          const float* __restrict__ n1g, const float* __restrict__ n1b,
                          const ushort_t* __restrict__ D1sw, const float* __restrict__ D1b,
                          const ushort_t* __restrict__ D2sw, const float* __restrict__ D2b,
                          const float* __restrict__ n2g, const float* __restrict__ n2b,
                          float* __restrict__ out) {
    __shared__ __align__(16) float xs[32 * HDIM];
    __shared__ __align__(16) ushort_t h1a[32 * SY];
    __shared__ __align__(16) ushort_t ua[32 * 520];
    __shared__ float mu_s[32], rs_s[32];

    const int tid = threadIdx.x;
    const int wave = tid >> 6, lane = tid & 63;
    const int quad = lane >> 4, l16 = lane & 15;
    const int n0 = blockIdx.x * 32;

    #pragma unroll
    for (int it = 0; it < 4; ++it) {
        const int f4 = it * 256 + tid;
        const float4 hv = ((const float4*)(hV + (size_t)n0 * HDIM))[f4];
        const half4_t dv = ((const half4_t*)(dh + (size_t)n0 * HDIM))[f4];
        ((float4*)xs)[f4] = (float4){hv.x + (float)dv[0] * INV_SCALE,
                                     hv.y + (float)dv[1] * INV_SCALE,
                                     hv.z + (float)dv[2] * INV_SCALE,
                                     hv.w + (float)dv[3] * INV_SCALE};
    }
    __syncthreads();

    {
        const int row = tid >> 3, q = tid & 7;
        float s = 0.f, s2 = 0.f;
        #pragma unroll
        for (int c = 0; c < 16; ++c) { const float v = xs[row * HDIM + q * 16 + c]; s += v; s2 += v * v; }
        #pragma unroll
        for (int o = 1; o < 8; o <<= 1) { s += __shfl_xor(s, o); s2 += __shfl_xor(s2, o); }
        if (q == 0) {
            const float m = s * (1.0f / HDIM);
            mu_s[row] = m;
            rs_s[row] = rsqrtf(s2 * (1.0f / HDIM) - m * m + LN_EPS);
        }
    }
    __syncthreads();

    #pragma unroll
    for (int it = 0; it < 2; ++it) {
        const int g = it * 256 + tid;
        const int row = g >> 4, col = (g & 15) * 8;
        const float mu = mu_s[row], rs = rs_s[row];
        union { bf16x8 v; ushort_t u[8]; } c;
        #pragma unroll
        for (int jj = 0; jj < 8; ++jj) {
            const float h1 = (xs[row * HDIM + col + jj] - mu) * rs * n1g[col + jj] + n1b[col + jj];
            c.u[jj] = f2bf(h1);
        }
        *(bf16x8*)(h1a + row * SY + col) = c.v;
    }
    __syncthreads();

    {
        f32x4 acc1[2][8];
        #pragma unroll
        for (int t = 0; t < 8; ++t) {
            const float bv = D1b[wave * 128 + t * 16 + l16];
            acc1[0][t] = (f32x4){bv, bv, bv, bv};
            acc1[1][t] = acc1[0][t];
        }
        #pragma unroll
        for (int s = 0; s < 4; ++s) {
            bf16x8 a[2];
            #pragma unroll
            for (int rt = 0; rt < 2; ++rt)
                a[rt] = *(const bf16x8*)(h1a + (rt * 16 + l16) * SY + s * 32 + quad * 8);
            #pragma unroll
            for (int t = 0; t < 8; ++t) {
                const bf16x8 b = *(const bf16x8*)(D1sw + (size_t)((s * 32 + wave * 8 + t) * 64 + lane) * 8);
                acc1[0][t] = mfma_bf16(a[0], b, acc1[0][t]);
                acc1[1][t] = mfma_bf16(a[1], b, acc1[1][t]);
            }
        }
        #pragma unroll
        for (int rt = 0; rt < 2; ++rt)
            #pragma unroll
            for (int t = 0; t < 8; ++t)
                #pragma unroll
                for (int r = 0; r < 4; ++r)
                    ua[(rt * 16 + quad * 4 + r) * 520 + wave * 128 + t * 16 + l16] =
                        f2bf(gelu_fast(acc1[rt][t][r]));
    }
    __syncthreads();

    f32x4 acc2[2][2];
    acc2[0][0] = (f32x4){0,0,0,0}; acc2[0][1] = acc2[0][0];
    acc2[1][0] = acc2[0][0];       acc2[1][1] = acc2[0][0];
    #pragma unroll
    for (int s = 0; s < 16; ++s) {
        bf16x8 a[2];
        #pragma unroll
        for (int rt = 0; rt < 2; ++rt)
            a[rt] = *(const bf16x8*)(ua + (rt * 16 + l16) * 520 + s * 32 + quad * 8);
        #pragma unroll
        for (int tt = 0; tt < 2; ++tt) {
            const bf16x8 b = *(const bf16x8*)(D2sw + (size_t)((s * 8 + wave * 2 + tt) * 64 + lane) * 8);
            acc2[0][tt] = mfma_bf16(a[0], b, acc2[0][tt]);
            acc2[1][tt] = mfma_bf16(a[1], b, acc2[1][tt]);
        }
    }
    __syncthreads();

    float* yf = (float*)ua;
    #pragma unroll
    for (int rt = 0; rt < 2; ++rt)
        #pragma unroll
        for (int tt = 0; tt < 2; ++tt)
            #pragma unroll
            for (int r = 0; r < 4; ++r) {
                const int row = rt * 16 + quad * 4 + r;
                const int col = wave * 32 + tt * 16 + l16;
                const float h1 = (xs[row * HDIM + col] - mu_s[row]) * rs_s[row] * n1g[col] + n1b[col];
                yf[row * HDIM + col] = h1 + acc2[rt][tt][r] + D2b[col];
            }
    __syncthreads();

    {
        const int row = tid >> 3, q = tid & 7;
        float s = 0.f, s2 = 0.f;
        #pragma unroll
        for (int c = 0; c < 16; ++c) { const float v = yf[row * HDIM + q * 16 + c]; s += v; s2 += v * v; }
        #pragma unroll
        for (int o = 1; o < 8; o <<= 1) { s += __shfl_xor(s, o); s2 += __shfl_xor(s2, o); }
        if (q == 0) {
            const float m = s * (1.0f / HDIM);
            mu_s[row] = m;
            rs_s[row] = rsqrtf(s2 * (1.0f / HDIM) - m * m + LN_EPS);
        }
    }
    __syncthreads();

    #pragma unroll
    for (int it = 0; it < 4; ++it) {
        const int f4 = it * 256 + tid;
        const int row = f4 >> 5, col = (f4 & 31) * 4;
        const float4 y = ((const float4*)yf)[f4];
        const float mu = mu_s[row], rs = rs_s[row];
        float4 o;
        o.x = (y.x - mu) * rs * n2g[col + 0] + n2b[col + 0];
        o.y = (y.y - mu) * rs * n2g[col + 1] + n2b[col + 1];
        o.z = (y.z - mu) * rs * n2g[col + 2] + n2b[col + 2];
        o.w = (y.w - mu) * rs * n2g[col + 3] + n2b[col + 3];
        ((float4*)(out + (size_t)n0 * HDIM))[f4] = o;
    }
}

// ---------------------------------------------------------------------------
// Tier-3 fp32 node fallback.
// ---------------------------------------------------------------------------
#define NT 8
__device__ __forceinline__ void ln_stats32(const float* __restrict__ buf,
                                           float* __restrict__ mu_s,
                                           float* __restrict__ rs_s, int tid) {
    const int g = tid >> 5, lane = tid & 31;
    float s = 0.f, s2 = 0.f;
    #pragma unroll
    for (int c = lane; c < HDIM; c += 32) { const float v = buf[g * HDIM + c]; s += v; s2 += v * v; }
    #pragma unroll
    for (int o = 16; o; o >>= 1) { s += __shfl_xor(s, o, 32); s2 += __shfl_xor(s2, o, 32); }
    if (lane == 0) {
        const float m = s * (1.0f / HDIM);
        mu_s[g] = m;
        rs_s[g] = rsqrtf(s2 * (1.0f / HDIM) - m * m + LN_EPS);
    }
}

__launch_bounds__(256)
__global__ void node_update_f32(const float* __restrict__ hV, const _Float16* __restrict__ dh,
                                const float* __restrict__ n1g, const float* __restrict__ n1b,
                                const float* __restrict__ D1w, const float* __restrict__ D1b,
                                const float* __restrict__ D2w, const float* __restrict__ D2b,
                                const float* __restrict__ n2g, const float* __restrict__ n2b,
                                float* __restrict__ out) {
    __shared__ float h1s[NT * HDIM];
    __shared__ float us[NT * 512];
    __shared__ float vs[2 * NT * HDIM];
    __shared__ float mu_s[NT], rs_s[NT];
    const int tid = threadIdx.x;
    const int n0 = blockIdx.x * NT;
    for (int idx = tid; idx < NT * HDIM; idx += 256) {
        const int i = idx >> 7, c = idx & 127;
        const size_t g = (size_t)(n0 + i) * HDIM + c;
        h1s[idx] = hV[g] + (float)dh[g] * INV_SCALE;
    }
    __syncthreads();
    ln_stats32(h1s, mu_s, rs_s, tid);
    __syncthreads();
    for (int idx = tid; idx < NT * HDIM; idx += 256) {
        const int i = idx >> 7, c = idx & 127;
        h1s[idx] = (h1s[idx] - mu_s[i]) * rs_s[i] * n1g[c] + n1b[c];
    }
    __syncthreads();
    {
        const int o = 2 * tid;
        const float2 bv = *(const float2*)(D1b + o);
        float a0[NT], a1[NT];
        #pragma unroll
        for (int i = 0; i < NT; ++i) { a0[i] = bv.x; a1[i] = bv.y; }
        for (int k = 0; k < HDIM; ++k) {
            const float2 w = *(const float2*)(D1w + (size_t)k * 512 + o);
            #pragma unroll
            for (int i = 0; i < NT; ++i) {
                const float xv = h1s[i * HDIM + k];
                a0[i] += xv * w.x; a1[i] += xv * w.y;
            }
        }
        #pragma unroll
        for (int i = 0; i < NT; ++i) {
            us[i * 512 + o]     = gelu_fast(a0[i]);
            us[i * 512 + o + 1] = gelu_fast(a1[i]);
        }
    }
    __syncthreads();
    {
        const int o = tid & 127, half = tid >> 7;
        float a[NT];
        #pragma unroll
        for (int i = 0; i < NT; ++i) a[i] = 0.f;
        const int k0 = half * 256;
        for (int k = k0; k < k0 + 256; ++k) {
            const float w = D2w[(size_t)k * HDIM + o];
            #pragma unroll
            for (int i = 0; i < NT; ++i) a[i] += us[i * 512 + k] * w;
        }
        #pragma unroll
        for (int i = 0; i < NT; ++i) vs[(half * NT + i) * HDIM + o] = a[i];
    }
    __syncthreads();
    float* ys = us;
    for (int idx = tid; idx < NT * HDIM; idx += 256) {
        const int i = idx >> 7, c = idx & 127;
        ys[idx] = h1s[idx] + vs[i * HDIM + c] + vs[(NT + i) * HDIM + c] + D2b[c];
    }
    __syncthreads();
    ln_stats32(ys, mu_s, rs_s, tid);
    __syncthreads();
    for (int idx = tid; idx < NT * HDIM; idx += 256) {
        const int i = idx >> 7, c = idx & 127;
        out[(size_t)(n0 + i) * HDIM + c] = (ys[idx] - mu_s[i]) * rs_s[i] * n2g[c] + n2b[c];
    }
}

extern "C" void kernel_launch(void* const* d_in, const int* in_sizes, int n_in,
                              void* d_out, int out_size, void* d_ws, size_t ws_size,
                              hipStream_t stream) {
    const float* hV  = (const float*)d_in[0];
    const float* hE  = (const float*)d_in[1];
    const int*  eidx = (const int*)d_in[2];
    const float* W1w = (const float*)d_in[3];
    const float* W1b = (const float*)d_in[4];
    const float* W2w = (const float*)d_in[5];
    const float* W2b = (const float*)d_in[6];
    const float* W3w = (const float*)d_in[7];
    const float* W3b = (const float*)d_in[8];
    const float* n1g = (const float*)d_in[9];
    const float* n1b = (const float*)d_in[10];
    const float* D1w = (const float*)d_in[11];
    const float* D1b = (const float*)d_in[12];
    const float* D2w = (const float*)d_in[13];
    const float* D2b = (const float*)d_in[14];
    const float* n2g = (const float*)d_in[15];
    const float* n2b = (const float*)d_in[16];
    float* out = (float*)d_out;

    // tier-1 layout: msg | WswE | D1sw | D2sw | perm | cnt | off | off2
    // (x-buffer lives in d_out: gather_sum writes it, node_mfma_x rewrites it)
    const size_t MSG_BYTES = (size_t)NEDGES * HDIM * sizeof(_Float16);  // 81,920,000
    const size_t EW_BYTES  = 65536 * 2;
    const size_t T1_BYTES  = MSG_BYTES + 3 * EW_BYTES
                           + (size_t)NEDGES * 4 + (size_t)NNODES * 4
                           + (size_t)(NNODES + 1) * 4 + (size_t)NNODES * 4;
    const size_t DH_BYTES  = (size_t)NNODES * HDIM * sizeof(_Float16);  // 5,120,000
    const size_t T2_BYTES  = DH_BYTES + 3 * EW_BYTES;

    if (ws_size >= T1_BYTES) {
        char* p = (char*)d_ws;
        _Float16* msg  = (_Float16*)p;            p += MSG_BYTES;
        ushort_t* WswE = (ushort_t*)p;            p += EW_BYTES;
        ushort_t* D1sw = (ushort_t*)p;            p += EW_BYTES;
        ushort_t* D2sw = (ushort_t*)p;            p += EW_BYTES;
        int* perm = (int*)p;                      p += (size_t)NEDGES * 4;
        int* cnt  = (int*)p;                      p += (size_t)NNODES * 4;
        int* off  = (int*)p;                      p += (size_t)(NNODES + 1) * 4;
        int* off2 = (int*)p;

        hipMemsetAsync(cnt, 0, (size_t)NNODES * 4, stream);
        prep_all<<<2019, 256, 0, stream>>>(W1w, W2w, W3w, WswE, D1w, D2w, D1sw, D2sw, eidx, cnt);
        scan_counts<<<1, 1024, 0, stream>>>(cnt, off, off2);
        fill_perm<<<(NEDGES + 255) / 256, 256, 0, stream>>>(eidx, off2, perm);
        edge_mlp_v2<<<NEDGES / 64, 256, 0, stream>>>(hE, WswE, W1b, W2b, W3b, msg);
        gather_sum<<<NNODES / 8, 256, 0, stream>>>(msg, perm, off, hV, out);
        node_mfma_x<<<NNODES / 32, 256, 0, stream>>>(out, n1g, n1b,
                                                     D1sw, D1b, D2sw, D2b, n2g, n2b, out);
    } else if (ws_size >= T2_BYTES) {
        _Float16* dh = (_Float16*)d_ws;
        ushort_t* WswE = (ushort_t*)((char*)d_ws + DH_BYTES);
        ushort_t* D1sw = (ushort_t*)((char*)d_ws + DH_BYTES + EW_BYTES);
        ushort_t* D2sw = (ushort_t*)((char*)d_ws + DH_BYTES + 2 * EW_BYTES);
        hipMemsetAsync(dh, 0, DH_BYTES, stream);
        prep_all<<<2019, 256, 0, stream>>>(W1w, W2w, W3w, WswE, D1w, D2w, D1sw, D2sw, eidx, (int*)WswE /*unused cnt target; hist writes guarded below*/);
        // NOTE: tier-2 does not need cnt/hist — re-run prep without hist side effects is
        // harmless only if cnt pointer is valid; point it at dh scratch instead:
        edge_mlp_mfma<<<NEDGES / 128, 256, 0, stream>>>(hE, eidx, WswE, W1b, W2b, W3b, dh);
        node_mfma<<<NNODES / 32, 256, 0, stream>>>(hV, dh, n1g, n1b, D1sw, D1b, D2sw, D2b, n2g, n2b, out);
    } else {
        _Float16* dh = (_Float16*)d_ws;
        ushort_t* WswE = (ushort_t*)((char*)d_out + (size_t)out_size * 4 - EW_BYTES);
        hipMemsetAsync(dh, 0, DH_BYTES, stream);
        prep_all<<<2019, 256, 0, stream>>>(W1w, W2w, W3w, WswE, D1w, D2w,
                                           /*D1sw,D2sw scratch -> reuse dh tail*/ (ushort_t*)dh, (ushort_t*)dh,
                                           eidx, (int*)dh);
        hipMemsetAsync(dh, 0, DH_BYTES, stream);   // re-zero dh after scratch abuse
        edge_mlp_mfma<<<NEDGES / 128, 256, 0, stream>>>(hE, eidx, WswE, W1b, W2b, W3b, dh);
        node_update_f32<<<NNODES / NT, 256, 0, stream>>>(hV, dh, n1g, n1b, D1w, D1b, D2w, D2b, n2g, n2b, out);
    }
}

// Round 6
// 615.449 us; speedup vs baseline: 1.1236x; 1.0201x over previous
//
#include <hip/hip_runtime.h>
#include <hip/hip_bf16.h>
#include <math.h>

#define NNODES 20000
#define NEDGES 320000
#define HDIM   128
#define INDIM  256
#define INV_SCALE (1.0f/30.0f)
#define LN_EPS 1e-5f

typedef __bf16 bf16x8 __attribute__((ext_vector_type(8)));
typedef float  f32x4  __attribute__((ext_vector_type(4)));
typedef _Float16 half4_t __attribute__((ext_vector_type(4)));
typedef _Float16 half8_t __attribute__((ext_vector_type(8)));
typedef unsigned short ushort_t;

__device__ __forceinline__ unsigned short f2bf(float f) {
    union { __hip_bfloat16 h; unsigned short u; } c;
    c.h = __float2bfloat16(f);
    return c.u;
}

// Fast gelu: x * sigmoid(1.5957691*x + 0.0713548*x^3)  (tanh-form, max |err| ~1e-3)
__device__ __forceinline__ float gelu_fast(float x) {
    const float z = x * (1.595769122f + 0.071354816f * x * x);
    return x / (1.0f + __expf(-z));
}

__device__ __forceinline__ f32x4 mfma_bf16(bf16x8 a, bf16x8 b, f32x4 c) {
    return __builtin_amdgcn_mfma_f32_16x16x32_bf16(a, b, c, 0, 0, 0);
}

#define CVT8(dst, v0, v1) { union { bf16x8 v; ushort_t u[8]; } c_; \
    c_.u[0] = f2bf((v0).x); c_.u[1] = f2bf((v0).y); c_.u[2] = f2bf((v0).z); c_.u[3] = f2bf((v0).w); \
    c_.u[4] = f2bf((v1).x); c_.u[5] = f2bf((v1).y); c_.u[6] = f2bf((v1).z); c_.u[7] = f2bf((v1).w); \
    (dst) = c_.v; }

// ---------------------------------------------------------------------------
// Combined prep: edge weights + node weights + edge histogram in one launch.
// B-fragment order for mfma_f32_16x16x32_bf16: frag (s,T), lane L, elem j holds
// W[k = s*32 + (L>>4)*8 + j][n], lane's 8 bf16 contiguous. Frag f at
// Wsw[(f*64+L)*8+j], f = s*8+T. W1 base 0, W2 base 32768, W3 base 49152.
//
// W3 col permutation (dword-packed msg stores, wave-sliced edge kernel):
// frag T, fragment col l16 -> actual col n3 = 2*((T>>1)*16 + l16) + (T&1).
// So frag pair (2u, 2u+1) = adjacent actual cols (2*(u*16+l16), +1).
// D1sw/D2sw/cnt may be nullptr (tier fallbacks) -> those parts are skipped.
// ---------------------------------------------------------------------------
__global__ void prep_all(const float* __restrict__ W1, const float* __restrict__ W2,
                         const float* __restrict__ W3, ushort_t* __restrict__ WswE,
                         const float* __restrict__ D1, const float* __restrict__ D2,
                         ushort_t* __restrict__ D1sw, ushort_t* __restrict__ D2sw,
                         const int* __restrict__ src, int* __restrict__ cnt) {
    const int id = blockIdx.x * 256 + threadIdx.x;
    if (id < 65536) {
        const float* W; int base, idx; bool perm = false;
        if (id < 32768)      { W = W1; base = 0;     idx = id; }
        else if (id < 49152) { W = W2; base = 32768; idx = id - 32768; }
        else                 { W = W3; base = 49152; idx = id - 49152; perm = true; }
        const int j = idx & 7, lane = (idx >> 3) & 63, t = (idx >> 9) & 7, s = idx >> 12;
        const int k = s * 32 + (lane >> 4) * 8 + j;
        const int n = perm ? (2 * ((t >> 1) * 16 + (lane & 15)) + (t & 1))
                           : (t * 16 + (lane & 15));
        WswE[base + idx] = f2bf(W[k * HDIM + n]);
    } else if (id < 196608) {
        if (!D1sw) return;
        const int nid = id - 65536;   // 0..131071
        if (nid < 65536) {
            const int idx = nid;
            const int j = idx & 7, lane = (idx >> 3) & 63, f = idx >> 9;   // f = s*32+t
            const int t = f & 31, s = f >> 5;
            const int k = s * 32 + (lane >> 4) * 8 + j;
            const int n = t * 16 + (lane & 15);
            D1sw[idx] = f2bf(D1[k * 512 + n]);
        } else {
            const int idx = nid - 65536;
            const int j = idx & 7, lane = (idx >> 3) & 63, f = idx >> 9;   // f = s*8+t
            const int t = f & 7, s = f >> 3;
            const int k = s * 32 + (lane >> 4) * 8 + j;
            const int n = t * 16 + (lane & 15);
            D2sw[idx] = f2bf(D2[k * HDIM + n]);
        }
    } else {
        if (!cnt) return;
        const int e = id - 196608;
        if (e < NEDGES) atomicAdd(&cnt[src[e]], 1);
    }
}

// ---------------------------------------------------------------------------
// CSR scan + perm fill.
// ---------------------------------------------------------------------------
__launch_bounds__(1024)
__global__ void scan_counts(const int* __restrict__ cnt,
                            int* __restrict__ off, int* __restrict__ off2) {
    __shared__ int tot[1024];
    const int t = threadIdx.x;
    const int base = t * 20;                 // 1024*20 = 20480 >= NNODES
    int local[20]; int s = 0;
    #pragma unroll
    for (int i = 0; i < 20; ++i) {
        const int v = (base + i < NNODES) ? cnt[base + i] : 0;
        local[i] = s; s += v;
    }
    tot[t] = s;
    __syncthreads();
    for (int d = 1; d < 1024; d <<= 1) {
        const int v = (t >= d) ? tot[t - d] : 0;
        __syncthreads();
        tot[t] += v;
        __syncthreads();
    }
    const int excl = (t == 0) ? 0 : tot[t - 1];
    #pragma unroll
    for (int i = 0; i < 20; ++i)
        if (base + i < NNODES) { off[base + i] = excl + local[i]; off2[base + i] = excl + local[i]; }
    if (t == 1023) off[NNODES] = NEDGES;
}

__global__ void fill_perm(const int* __restrict__ src, int* __restrict__ off2,
                          int* __restrict__ perm) {
    const int e = blockIdx.x * 256 + threadIdx.x;
    if (e < NEDGES) {
        const int p = atomicAdd(&off2[src[e]], 1);
        perm[p] = e;
    }
}

// ---------------------------------------------------------------------------
// Edge MLP v3: block = 64 edges, 4 waves; wave owns a 32-col output slice for
// ALL 64 edges (B-frags reused 4x, double-buffered). hE staged in TWO K=128
// chunks through ONE 17.4 KB LDS buffer; chunk-1 loads are issued into
// registers BEFORE the first barrier so their HBM latency hides under the
// first 4 MFMA K-steps. LDS 34.8 KB -> 4 blocks/CU (16 waves). Zero atomics.
// ---------------------------------------------------------------------------
#define A1H 136   // staging chunk row stride (bf16): 128 + 8 pad (2-way banks, free)
#define SY  136   // A2 row stride (bf16)

__launch_bounds__(256, 4)
__global__ void edge_mlp_v3(const float* __restrict__ hE,
                            const ushort_t* __restrict__ Wsw,
                            const float* __restrict__ b1,
                            const float* __restrict__ b2,
                            const float* __restrict__ b3,
                            _Float16* __restrict__ msg) {
    __shared__ __align__(16) ushort_t A1h[64 * A1H];  // 17408 B (K-chunk)
    __shared__ __align__(16) ushort_t A2[64 * SY];    // 17408 B

    const int tid = threadIdx.x;
    const int wave = tid >> 6, lane = tid & 63;
    const int quad = lane >> 4, l16 = lane & 15;
    const size_t e0 = (size_t)blockIdx.x * 64;
    const int T0 = wave * 2;                 // wave's two col-frags: T0, T0+1

    // staging mapping: thread = (row, quarter of 128ch chunk)
    const int srow = tid >> 2, sq = tid & 3;
    const float4* sp = (const float4*)(hE + (e0 + srow) * INDIM) + sq * 8;
    ushort_t* sd = A1h + srow * A1H + sq * 32;

    // ---- chunk0 -> regs -> LDS; chunk1 -> regs (left in flight) ----
    float4 rg[8];
    #pragma unroll
    for (int i = 0; i < 8; ++i) rg[i] = sp[i];
    #pragma unroll
    for (int i = 0; i < 4; ++i) {
        bf16x8 v; CVT8(v, rg[2 * i], rg[2 * i + 1]);
        *(bf16x8*)(sd + i * 8) = v;
    }
    #pragma unroll
    for (int i = 0; i < 8; ++i) rg[i] = sp[32 + i];   // chunk1 (ch 128..255)

    f32x4 acc[4][2];
    bf16x8 bcur[2], bnxt[2];

    #pragma unroll
    for (int t = 0; t < 2; ++t) {
        const float bv = b1[(T0 + t) * 16 + l16];
        #pragma unroll
        for (int rt = 0; rt < 4; ++rt) acc[rt][t] = (f32x4){bv, bv, bv, bv};
    }
    bcur[0] = *(const bf16x8*)(Wsw + (size_t)((T0 + 0) * 64 + lane) * 8);
    bcur[1] = *(const bf16x8*)(Wsw + (size_t)((T0 + 1) * 64 + lane) * 8);
    __syncthreads();

    // ---- L1 part A: s = 0..3 (chunk0) ----
    #pragma unroll
    for (int s = 0; s < 4; ++s) {
        bnxt[0] = *(const bf16x8*)(Wsw + (size_t)(((s + 1) * 8 + T0 + 0) * 64 + lane) * 8);
        bnxt[1] = *(const bf16x8*)(Wsw + (size_t)(((s + 1) * 8 + T0 + 1) * 64 + lane) * 8);
        bf16x8 a[4];
        #pragma unroll
        for (int rt = 0; rt < 4; ++rt)
            a[rt] = *(const bf16x8*)(A1h + (rt * 16 + l16) * A1H + s * 32 + quad * 8);
        #pragma unroll
        for (int rt = 0; rt < 4; ++rt) {
            acc[rt][0] = mfma_bf16(a[rt], bcur[0], acc[rt][0]);
            acc[rt][1] = mfma_bf16(a[rt], bcur[1], acc[rt][1]);
        }
        bcur[0] = bnxt[0]; bcur[1] = bnxt[1];
    }
    __syncthreads();   // chunk0 reads done

    // ---- write chunk1 (rg loads have had 4 K-steps to land) ----
    #pragma unroll
    for (int i = 0; i < 4; ++i) {
        bf16x8 v; CVT8(v, rg[2 * i], rg[2 * i + 1]);
        *(bf16x8*)(sd + i * 8) = v;
    }
    __syncthreads();   // chunk1 ready

    // ---- L1 part B: s = 4..7 ----
    #pragma unroll
    for (int s = 4; s < 8; ++s) {
        if (s < 7) {
            bnxt[0] = *(const bf16x8*)(Wsw + (size_t)(((s + 1) * 8 + T0 + 0) * 64 + lane) * 8);
            bnxt[1] = *(const bf16x8*)(Wsw + (size_t)(((s + 1) * 8 + T0 + 1) * 64 + lane) * 8);
        }
        bf16x8 a[4];
        #pragma unroll
        for (int rt = 0; rt < 4; ++rt)
            a[rt] = *(const bf16x8*)(A1h + (rt * 16 + l16) * A1H + (s - 4) * 32 + quad * 8);
        #pragma unroll
        for (int rt = 0; rt < 4; ++rt) {
            acc[rt][0] = mfma_bf16(a[rt], bcur[0], acc[rt][0]);
            acc[rt][1] = mfma_bf16(a[rt], bcur[1], acc[rt][1]);
        }
        bcur[0] = bnxt[0]; bcur[1] = bnxt[1];
    }
    // gelu(h1) slice -> A2
    #pragma unroll
    for (int rt = 0; rt < 4; ++rt)
        #pragma unroll
        for (int t = 0; t < 2; ++t)
            #pragma unroll
            for (int r = 0; r < 4; ++r)
                A2[(rt * 16 + quad * 4 + r) * SY + (T0 + t) * 16 + l16] =
                    f2bf(gelu_fast(acc[rt][t][r]));
    __syncthreads();

    // ---- layer 2: [64x128] x [128 x 32-slice] ----
    #pragma unroll
    for (int t = 0; t < 2; ++t) {
        const float bv = b2[(T0 + t) * 16 + l16];
        #pragma unroll
        for (int rt = 0; rt < 4; ++rt) acc[rt][t] = (f32x4){bv, bv, bv, bv};
    }
    bcur[0] = *(const bf16x8*)(Wsw + 32768 + (size_t)((T0 + 0) * 64 + lane) * 8);
    bcur[1] = *(const bf16x8*)(Wsw + 32768 + (size_t)((T0 + 1) * 64 + lane) * 8);
    #pragma unroll
    for (int s = 0; s < 4; ++s) {
        if (s < 3) {
            bnxt[0] = *(const bf16x8*)(Wsw + 32768 + (size_t)(((s + 1) * 8 + T0 + 0) * 64 + lane) * 8);
            bnxt[1] = *(const bf16x8*)(Wsw + 32768 + (size_t)(((s + 1) * 8 + T0 + 1) * 64 + lane) * 8);
        }
        bf16x8 a[4];
        #pragma unroll
        for (int rt = 0; rt < 4; ++rt)
            a[rt] = *(const bf16x8*)(A2 + (rt * 16 + l16) * SY + s * 32 + quad * 8);
        #pragma unroll
        for (int rt = 0; rt < 4; ++rt) {
            acc[rt][0] = mfma_bf16(a[rt], bcur[0], acc[rt][0]);
            acc[rt][1] = mfma_bf16(a[rt], bcur[1], acc[rt][1]);
        }
        bcur[0] = bnxt[0]; bcur[1] = bnxt[1];
    }
    __syncthreads();   // all waves' h1 reads complete before overwrite
    #pragma unroll
    for (int rt = 0; rt < 4; ++rt)
        #pragma unroll
        for (int t = 0; t < 2; ++t)
            #pragma unroll
            for (int r = 0; r < 4; ++r)
                A2[(rt * 16 + quad * 4 + r) * SY + (T0 + t) * 16 + l16] =
                    f2bf(gelu_fast(acc[rt][t][r]));
    __syncthreads();

    // ---- layer 3: PERMUTED cols; acc[.][0]/acc[.][1] = adjacent actual cols ----
    #pragma unroll
    for (int t = 0; t < 2; ++t) {
        const float bv = b3[2 * (wave * 16 + l16) + t];
        #pragma unroll
        for (int rt = 0; rt < 4; ++rt) acc[rt][t] = (f32x4){bv, bv, bv, bv};
    }
    bcur[0] = *(const bf16x8*)(Wsw + 49152 + (size_t)((T0 + 0) * 64 + lane) * 8);
    bcur[1] = *(const bf16x8*)(Wsw + 49152 + (size_t)((T0 + 1) * 64 + lane) * 8);
    #pragma unroll
    for (int s = 0; s < 4; ++s) {
        if (s < 3) {
            bnxt[0] = *(const bf16x8*)(Wsw + 49152 + (size_t)(((s + 1) * 8 + T0 + 0) * 64 + lane) * 8);
            bnxt[1] = *(const bf16x8*)(Wsw + 49152 + (size_t)(((s + 1) * 8 + T0 + 1) * 64 + lane) * 8);
        }
        bf16x8 a[4];
        #pragma unroll
        for (int rt = 0; rt < 4; ++rt)
            a[rt] = *(const bf16x8*)(A2 + (rt * 16 + l16) * SY + s * 32 + quad * 8);
        #pragma unroll
        for (int rt = 0; rt < 4; ++rt) {
            acc[rt][0] = mfma_bf16(a[rt], bcur[0], acc[rt][0]);
            acc[rt][1] = mfma_bf16(a[rt], bcur[1], acc[rt][1]);
        }
        bcur[0] = bnxt[0]; bcur[1] = bnxt[1];
    }

    // ---- store msg: dword (cols 2*(wave*16+l16), +1) per (rt,r) row ----
    #pragma unroll
    for (int rt = 0; rt < 4; ++rt)
        #pragma unroll
        for (int r = 0; r < 4; ++r) {
            const size_t row = e0 + rt * 16 + quad * 4 + r;
            union { _Float16 h[2]; unsigned int u; } pk;
            pk.h[0] = (_Float16)acc[rt][0][r];
            pk.h[1] = (_Float16)acc[rt][1][r];
            ((unsigned int*)(msg + row * HDIM))[wave * 16 + l16] = pk.u;
        }
}

// ---------------------------------------------------------------------------
// Segment-sum gather: x = hV + (sum of node's msg rows)/30, written to xout.
// 32 lanes per node (4 ch/lane), 8 nodes/block, zero LDS -> high occupancy.
// ---------------------------------------------------------------------------
__launch_bounds__(256)
__global__ void gather_sum(const _Float16* __restrict__ msg,
                           const int* __restrict__ perm,
                           const int* __restrict__ off,
                           const float* __restrict__ hV,
                           float* __restrict__ xout) {
    const int tid = threadIdx.x;
    const int slot = tid >> 5, l32 = tid & 31;
    const int node = blockIdx.x * 8 + slot;
    const int j0 = off[node], j1 = off[node + 1];
    float a0 = 0.f, a1 = 0.f, a2 = 0.f, a3 = 0.f;
    int j = j0;
    for (; j + 1 < j1; j += 2) {
        const int ea = perm[j], eb = perm[j + 1];
        const half4_t ma = *(const half4_t*)(msg + (size_t)ea * HDIM + l32 * 4);
        const half4_t mb = *(const half4_t*)(msg + (size_t)eb * HDIM + l32 * 4);
        a0 += (float)ma[0] + (float)mb[0];
        a1 += (float)ma[1] + (float)mb[1];
        a2 += (float)ma[2] + (float)mb[2];
        a3 += (float)ma[3] + (float)mb[3];
    }
    if (j < j1) {
        const int ea = perm[j];
        const half4_t ma = *(const half4_t*)(msg + (size_t)ea * HDIM + l32 * 4);
        a0 += (float)ma[0]; a1 += (float)ma[1]; a2 += (float)ma[2]; a3 += (float)ma[3];
    }
    const float4 hv = *(const float4*)(hV + (size_t)node * HDIM + l32 * 4);
    const float4 o = {hv.x + a0 * INV_SCALE, hv.y + a1 * INV_SCALE,
                      hv.z + a2 * INV_SCALE, hv.w + a3 * INV_SCALE};
    *(float4*)(xout + (size_t)node * HDIM + l32 * 4) = o;
}

// ---------------------------------------------------------------------------
// Node update reading precomputed x (= hV + dh/30) from xin. xin aliases out:
// each block reads only its own 32 rows, then overwrites them at the end.
// ---------------------------------------------------------------------------
__launch_bounds__(256)
__global__ void node_mfma_x(const float* __restrict__ xin,
                            const float* __restrict__ n1g, const float* __restrict__ n1b,
                            const ushort_t* __restrict__ D1sw, const float* __restrict__ D1b,
                            const ushort_t* __restrict__ D2sw, const float* __restrict__ D2b,
                            const float* __restrict__ n2g, const float* __restrict__ n2b,
                            float* __restrict__ out) {
    __shared__ __align__(16) float xs[32 * HDIM];
    __shared__ __align__(16) ushort_t h1a[32 * SY];
    __shared__ __align__(16) ushort_t ua[32 * 520];
    __shared__ float mu_s[32], rs_s[32];

    const int tid = threadIdx.x;
    const int wave = tid >> 6, lane = tid & 63;
    const int quad = lane >> 4, l16 = lane & 15;
    const int n0 = blockIdx.x * 32;

    #pragma unroll
    for (int it = 0; it < 4; ++it) {
        const int f4 = it * 256 + tid;
        ((float4*)xs)[f4] = ((const float4*)(xin + (size_t)n0 * HDIM))[f4];
    }
    __syncthreads();

    {
        const int row = tid >> 3, q = tid & 7;
        float s = 0.f, s2 = 0.f;
        #pragma unroll
        for (int c = 0; c < 16; ++c) { const float v = xs[row * HDIM + q * 16 + c]; s += v; s2 += v * v; }
        #pragma unroll
        for (int o = 1; o < 8; o <<= 1) { s += __shfl_xor(s, o); s2 += __shfl_xor(s2, o); }
        if (q == 0) {
            const float m = s * (1.0f / HDIM);
            mu_s[row] = m;
            rs_s[row] = rsqrtf(s2 * (1.0f / HDIM) - m * m + LN_EPS);
        }
    }
    __syncthreads();

    #pragma unroll
    for (int it = 0; it < 2; ++it) {
        const int g = it * 256 + tid;
        const int row = g >> 4, col = (g & 15) * 8;
        const float mu = mu_s[row], rs = rs_s[row];
        union { bf16x8 v; ushort_t u[8]; } c;
        #pragma unroll
        for (int jj = 0; jj < 8; ++jj) {
            const float h1 = (xs[row * HDIM + col + jj] - mu) * rs * n1g[col + jj] + n1b[col + jj];
            c.u[jj] = f2bf(h1);
        }
        *(bf16x8*)(h1a + row * SY + col) = c.v;
    }
    __syncthreads();

    {
        f32x4 acc1[2][8];
        #pragma unroll
        for (int t = 0; t < 8; ++t) {
            const float bv = D1b[wave * 128 + t * 16 + l16];
            acc1[0][t] = (f32x4){bv, bv, bv, bv};
            acc1[1][t] = acc1[0][t];
        }
        #pragma unroll
        for (int s = 0; s < 4; ++s) {
            bf16x8 a[2];
            #pragma unroll
            for (int rt = 0; rt < 2; ++rt)
                a[rt] = *(const bf16x8*)(h1a + (rt * 16 + l16) * SY + s * 32 + quad * 8);
            #pragma unroll
            for (int t = 0; t < 8; ++t) {
                const bf16x8 b = *(const bf16x8*)(D1sw + (size_t)((s * 32 + wave * 8 + t) * 64 + lane) * 8);
                acc1[0][t] = mfma_bf16(a[0], b, acc1[0][t]);
                acc1[1][t] = mfma_bf16(a[1], b, acc1[1][t]);
            }
        }
        #pragma unroll
        for (int rt = 0; rt < 2; ++rt)
            #pragma unroll
            for (int t = 0; t < 8; ++t)
                #pragma unroll
                for (int r = 0; r < 4; ++r)
                    ua[(rt * 16 + quad * 4 + r) * 520 + wave * 128 + t * 16 + l16] =
                        f2bf(gelu_fast(acc1[rt][t][r]));
    }
    __syncthreads();

    f32x4 acc2[2][2];
    acc2[0][0] = (f32x4){0,0,0,0}; acc2[0][1] = acc2[0][0];
    acc2[1][0] = acc2[0][0];       acc2[1][1] = acc2[0][0];
    #pragma unroll
    for (int s = 0; s < 16; ++s) {
        bf16x8 a[2];
        #pragma unroll
        for (int rt = 0; rt < 2; ++rt)
            a[rt] = *(const bf16x8*)(ua + (rt * 16 + l16) * 520 + s * 32 + quad * 8);
        #pragma unroll
        for (int tt = 0; tt < 2; ++tt) {
            const bf16x8 b = *(const bf16x8*)(D2sw + (size_t)((s * 8 + wave * 2 + tt) * 64 + lane) * 8);
            acc2[0][tt] = mfma_bf16(a[0], b, acc2[0][tt]);
            acc2[1][tt] = mfma_bf16(a[1], b, acc2[1][tt]);
        }
    }
    __syncthreads();

    float* yf = (float*)ua;
    #pragma unroll
    for (int rt = 0; rt < 2; ++rt)
        #pragma unroll
        for (int tt = 0; tt < 2; ++tt)
            #pragma unroll
            for (int r = 0; r < 4; ++r) {
                const int row = rt * 16 + quad * 4 + r;
                const int col = wave * 32 + tt * 16 + l16;
                const float h1 = (xs[row * HDIM + col] - mu_s[row]) * rs_s[row] * n1g[col] + n1b[col];
                yf[row * HDIM + col] = h1 + acc2[rt][tt][r] + D2b[col];
            }
    __syncthreads();

    {
        const int row = tid >> 3, q = tid & 7;
        float s = 0.f, s2 = 0.f;
        #pragma unroll
        for (int c = 0; c < 16; ++c) { const float v = yf[row * HDIM + q * 16 + c]; s += v; s2 += v * v; }
        #pragma unroll
        for (int o = 1; o < 8; o <<= 1) { s += __shfl_xor(s, o); s2 += __shfl_xor(s2, o); }
        if (q == 0) {
            const float m = s * (1.0f / HDIM);
            mu_s[row] = m;
            rs_s[row] = rsqrtf(s2 * (1.0f / HDIM) - m * m + LN_EPS);
        }
    }
    __syncthreads();

    #pragma unroll
    for (int it = 0; it < 4; ++it) {
        const int f4 = it * 256 + tid;
        const int row = f4 >> 5, col = (f4 & 31) * 4;
        const float4 y = ((const float4*)yf)[f4];
        const float mu = mu_s[row], rs = rs_s[row];
        float4 o;
        o.x = (y.x - mu) * rs * n2g[col + 0] + n2b[col + 0];
        o.y = (y.y - mu) * rs * n2g[col + 1] + n2b[col + 1];
        o.z = (y.z - mu) * rs * n2g[col + 2] + n2b[col + 2];
        o.w = (y.w - mu) * rs * n2g[col + 3] + n2b[col + 3];
        ((float4*)(out + (size_t)n0 * HDIM))[f4] = o;
    }
}

// ---------------------------------------------------------------------------
// Tier-2: packed-fp16 atomic scatter edge kernel (W3 perm: frag pair (2u,2u+1)
// = adjacent cols) + node kernel reading dh.
// ---------------------------------------------------------------------------
__launch_bounds__(256, 4)
__global__ void edge_mlp_mfma(const float* __restrict__ hE,
                              const int* __restrict__ edge_idx,
                              const ushort_t* __restrict__ Wsw,
                              const float* __restrict__ b1,
                              const float* __restrict__ b2,
                              const float* __restrict__ b3,
                              _Float16* __restrict__ dh) {
    __shared__ ushort_t A2[4][32 * SY];

    const int tid = threadIdx.x;
    const int wave = tid >> 6, lane = tid & 63;
    const int quad = lane >> 4, l16 = lane & 15;
    const size_t e0 = (size_t)blockIdx.x * 128 + wave * 32;
    ushort_t* Aw = A2[wave];

    f32x4 acc[2][8];

    #pragma unroll
    for (int t = 0; t < 8; ++t) {
        const float bv = b1[t * 16 + l16];
        acc[0][t] = (f32x4){bv, bv, bv, bv};
        acc[1][t] = acc[0][t];
    }
    #pragma unroll
    for (int s = 0; s < 8; ++s) {
        bf16x8 a[2];
        #pragma unroll
        for (int rt = 0; rt < 2; ++rt) {
            const float4* p = (const float4*)(hE + (e0 + rt * 16 + l16) * INDIM + s * 32 + quad * 8);
            const float4 v0 = p[0], v1 = p[1];
            bf16x8 av; CVT8(av, v0, v1);
            a[rt] = av;
        }
        #pragma unroll
        for (int t = 0; t < 8; ++t) {
            const bf16x8 b = *(const bf16x8*)(Wsw + (size_t)((s * 8 + t) * 64 + lane) * 8);
            acc[0][t] = mfma_bf16(a[0], b, acc[0][t]);
            acc[1][t] = mfma_bf16(a[1], b, acc[1][t]);
        }
    }
    #pragma unroll
    for (int rt = 0; rt < 2; ++rt)
        #pragma unroll
        for (int t = 0; t < 8; ++t)
            #pragma unroll
            for (int r = 0; r < 4; ++r)
                Aw[(rt * 16 + quad * 4 + r) * SY + t * 16 + l16] = f2bf(gelu_fast(acc[rt][t][r]));

    #pragma unroll
    for (int t = 0; t < 8; ++t) {
        const float bv = b2[t * 16 + l16];
        acc[0][t] = (f32x4){bv, bv, bv, bv};
        acc[1][t] = acc[0][t];
    }
    #pragma unroll
    for (int s = 0; s < 4; ++s) {
        bf16x8 a[2];
        #pragma unroll
        for (int rt = 0; rt < 2; ++rt)
            a[rt] = *(const bf16x8*)(Aw + (rt * 16 + l16) * SY + s * 32 + quad * 8);
        #pragma unroll
        for (int t = 0; t < 8; ++t) {
            const bf16x8 b = *(const bf16x8*)(Wsw + 32768 + (size_t)((s * 8 + t) * 64 + lane) * 8);
            acc[0][t] = mfma_bf16(a[0], b, acc[0][t]);
            acc[1][t] = mfma_bf16(a[1], b, acc[1][t]);
        }
    }
    #pragma unroll
    for (int rt = 0; rt < 2; ++rt)
        #pragma unroll
        for (int t = 0; t < 8; ++t)
            #pragma unroll
            for (int r = 0; r < 4; ++r)
                Aw[(rt * 16 + quad * 4 + r) * SY + t * 16 + l16] = f2bf(gelu_fast(acc[rt][t][r]));

    #pragma unroll
    for (int t = 0; t < 8; ++t) {
        const float bv = b3[2 * ((t >> 1) * 16 + l16) + (t & 1)];
        acc[0][t] = (f32x4){bv, bv, bv, bv};
        acc[1][t] = acc[0][t];
    }
    #pragma unroll
    for (int s = 0; s < 4; ++s) {
        bf16x8 a[2];
        #pragma unroll
        for (int rt = 0; rt < 2; ++rt)
            a[rt] = *(const bf16x8*)(Aw + (rt * 16 + l16) * SY + s * 32 + quad * 8);
        #pragma unroll
        for (int t = 0; t < 8; ++t) {
            const bf16x8 b = *(const bf16x8*)(Wsw + 49152 + (size_t)((s * 8 + t) * 64 + lane) * 8);
            acc[0][t] = mfma_bf16(a[0], b, acc[0][t]);
            acc[1][t] = mfma_bf16(a[1], b, acc[1][t]);
        }
    }

    #pragma unroll
    for (int rt = 0; rt < 2; ++rt)
        #pragma unroll
        for (int r = 0; r < 4; ++r) {
            const int e = (int)e0 + rt * 16 + quad * 4 + r;
            const int s = edge_idx[e];
            _Float16* dst = dh + (size_t)s * HDIM;
            #pragma unroll
            for (int u = 0; u < 4; ++u) {
                const int c = 2 * (u * 16 + l16);
                union { _Float16 h[2]; unsigned int u32; } pk;
                pk.h[0] = (_Float16)acc[rt][2 * u][r];
                pk.h[1] = (_Float16)acc[rt][2 * u + 1][r];
                asm volatile("global_atomic_pk_add_f16 %0, %1, off"
                             :: "v"(dst + c), "v"(pk.u32) : "memory");
            }
        }
}

__launch_bounds__(256)
__global__ void node_mfma(const float* __restrict__ hV, const _Float16* __restrict__ dh,
                          const float* __restrict__ n1g, const float* __restrict__ n1b,
                          const ushort_t* __restrict__ D1sw, const float* __restrict__ D1b,
                          const ushort_t* __restrict__ D2sw, const float* __restrict__ D2b,
                          const float* __restrict__ n2g, const float* __restrict__ n2b,
                          float* __restrict__ out) {
    __shared__ __align__(16) float xs[32 * HDIM];
    __shared__ __align__(16) ushort_t h1a[32 * SY];
    __shared__ __align__(16) ushort_t ua[32 * 520];
    __shared__ float mu_s[32], rs_s[32];

    const int tid = threadIdx.x;
    const int wave = tid >> 6, lane = tid & 63;
    const int quad = lane >> 4, l16 = lane & 15;
    const int n0 = blockIdx.x * 32;

    #pragma unroll
    for (int it = 0; it < 4; ++it) {
        const int f4 = it * 256 + tid;
        const float4 hv = ((const float4*)(hV + (size_t)n0 * HDIM))[f4];
        const half4_t dv = ((const half4_t*)(dh + (size_t)n0 * HDIM))[f4];
        ((float4*)xs)[f4] = (float4){hv.x + (float)dv[0] * INV_SCALE,
                                     hv.y + (float)dv[1] * INV_SCALE,
                                     hv.z + (float)dv[2] * INV_SCALE,
                                     hv.w + (float)dv[3] * INV_SCALE};
    }
    __syncthreads();

    {
        const int row = tid >> 3, q = tid & 7;
        float s = 0.f, s2 = 0.f;
        #pragma unroll
        for (int c = 0; c < 16; ++c) { const float v = xs[row * HDIM + q * 16 + c]; s += v; s2 += v * v; }
        #pragma unroll
        for (int o = 1; o < 8; o <<= 1) { s += __shfl_xor(s, o); s2 += __shfl_xor(s2, o); }
        if (q == 0) {
            const float m = s * (1.0f / HDIM);
            mu_s[row] = m;
            rs_s[row] = rsqrtf(s2 * (1.0f / HDIM) - m * m + LN_EPS);
        }
    }
    __syncthreads();

    #pragma unroll
    for (int it = 0; it < 2; ++it) {
        const int g = it * 256 + tid;
        const int row = g >> 4, col = (g & 15) * 8;
        const float mu = mu_s[row], rs = rs_s[row];
        union { bf16x8 v; ushort_t u[8]; } c;
        #pragma unroll
        for (int jj = 0; jj < 8; ++jj) {
            const float h1 = (xs[row * HDIM + col + jj] - mu) * rs * n1g[col + jj] + n1b[col + jj];
            c.u[jj] = f2bf(h1);
        }
        *(bf16x8*)(h1a + row * SY + col) = c.v;
    }
    __syncthreads();

    {
        f32x4 acc1[2][8];
        #pragma unroll
        for (int t = 0; t < 8; ++t) {
            const float bv = D1b[wave * 128 + t * 16 + l16];
            acc1[0][t] = (f32x4){bv, bv, bv, bv};
            acc1[1][t] = acc1[0][t];
        }
        #pragma unroll
        for (int s = 0; s < 4; ++s) {
            bf16x8 a[2];
            #pragma unroll
            for (int rt = 0; rt < 2; ++rt)
                a[rt] = *(const bf16x8*)(h1a + (rt * 16 + l16) * SY + s * 32 + quad * 8);
            #pragma unroll
            for (int t = 0; t < 8; ++t) {
                const bf16x8 b = *(const bf16x8*)(D1sw + (size_t)((s * 32 + wave * 8 + t) * 64 + lane) * 8);
                acc1[0][t] = mfma_bf16(a[0], b, acc1[0][t]);
                acc1[1][t] = mfma_bf16(a[1], b, acc1[1][t]);
            }
        }
        #pragma unroll
        for (int rt = 0; rt < 2; ++rt)
            #pragma unroll
            for (int t = 0; t < 8; ++t)
                #pragma unroll
                for (int r = 0; r < 4; ++r)
                    ua[(rt * 16 + quad * 4 + r) * 520 + wave * 128 + t * 16 + l16] =
                        f2bf(gelu_fast(acc1[rt][t][r]));
    }
    __syncthreads();

    f32x4 acc2[2][2];
    acc2[0][0] = (f32x4){0,0,0,0}; acc2[0][1] = acc2[0][0];
    acc2[1][0] = acc2[0][0];       acc2[1][1] = acc2[0][0];
    #pragma unroll
    for (int s = 0; s < 16; ++s) {
        bf16x8 a[2];
        #pragma unroll
        for (int rt = 0; rt < 2; ++rt)
            a[rt] = *(const bf16x8*)(ua + (rt * 16 + l16) * 520 + s * 32 + quad * 8);
        #pragma unroll
        for (int tt = 0; tt < 2; ++tt) {
            const bf16x8 b = *(const bf16x8*)(D2sw + (size_t)((s * 8 + wave * 2 + tt) * 64 + lane) * 8);
            acc2[0][tt] = mfma_bf16(a[0], b, acc2[0][tt]);
            acc2[1][tt] = mfma_bf16(a[1], b, acc2[1][tt]);
        }
    }
    __syncthreads();

    float* yf = (float*)ua;
    #pragma unroll
    for (int rt = 0; rt < 2; ++rt)
        #pragma unroll
        for (int tt = 0; tt < 2; ++tt)
            #pragma unroll
            for (int r = 0; r < 4; ++r) {
                const int row = rt * 16 + quad * 4 + r;
                const int col = wave * 32 + tt * 16 + l16;
                const float h1 = (xs[row * HDIM + col] - mu_s[row]) * rs_s[row] * n1g[col] + n1b[col];
                yf[row * HDIM + col] = h1 + acc2[rt][tt][r] + D2b[col];
            }
    __syncthreads();

    {
        const int row = tid >> 3, q = tid & 7;
        float s = 0.f, s2 = 0.f;
        #pragma unroll
        for (int c = 0; c < 16; ++c) { const float v = yf[row * HDIM + q * 16 + c]; s += v; s2 += v * v; }
        #pragma unroll
        for (int o = 1; o < 8; o <<= 1) { s += __shfl_xor(s, o); s2 += __shfl_xor(s2, o); }
        if (q == 0) {
            const float m = s * (1.0f / HDIM);
            mu_s[row] = m;
            rs_s[row] = rsqrtf(s2 * (1.0f / HDIM) - m * m + LN_EPS);
        }
    }
    __syncthreads();

    #pragma unroll
    for (int it = 0; it < 4; ++it) {
        const int f4 = it * 256 + tid;
        const int row = f4 >> 5, col = (f4 & 31) * 4;
        const float4 y = ((const float4*)yf)[f4];
        const float mu = mu_s[row], rs = rs_s[row];
        float4 o;
        o.x = (y.x - mu) * rs * n2g[col + 0] + n2b[col + 0];
        o.y = (y.y - mu) * rs * n2g[col + 1] + n2b[col + 1];
        o.z = (y.z - mu) * rs * n2g[col + 2] + n2b[col + 2];
        o.w = (y.w - mu) * rs * n2g[col + 3] + n2b[col + 3];
        ((float4*)(out + (size_t)n0 * HDIM))[f4] = o;
    }
}

// ---------------------------------------------------------------------------
// Tier-3 fp32 node fallback.
// ---------------------------------------------------------------------------
#define NT 8
__device__ __forceinline__ void ln_stats32(const float* __restrict__ buf,
                                           float* __restrict__ mu_s,
                                           float* __restrict__ rs_s, int tid) {
    const int g = tid >> 5, lane = tid & 31;
    float s = 0.f, s2 = 0.f;
    #pragma unroll
    for (int c = lane; c < HDIM; c += 32) { const float v = buf[g * HDIM + c]; s += v; s2 += v * v; }
    #pragma unroll
    for (int o = 16; o; o >>= 1) { s += __shfl_xor(s, o, 32); s2 += __shfl_xor(s2, o, 32); }
    if (lane == 0) {
        const float m = s * (1.0f / HDIM);
        mu_s[g] = m;
        rs_s[g] = rsqrtf(s2 * (1.0f / HDIM) - m * m + LN_EPS);
    }
}

__launch_bounds__(256)
__global__ void node_update_f32(const float* __restrict__ hV, const _Float16* __restrict__ dh,
                                const float* __restrict__ n1g, const float* __restrict__ n1b,
                                const float* __restrict__ D1w, const float* __restrict__ D1b,
                                const float* __restrict__ D2w, const float* __restrict__ D2b,
                                const float* __restrict__ n2g, const float* __restrict__ n2b,
                                float* __restrict__ out) {
    __shared__ float h1s[NT * HDIM];
    __shared__ float us[NT * 512];
    __shared__ float vs[2 * NT * HDIM];
    __shared__ float mu_s[NT], rs_s[NT];
    const int tid = threadIdx.x;
    const int n0 = blockIdx.x * NT;
    for (int idx = tid; idx < NT * HDIM; idx += 256) {
        const int i = idx >> 7, c = idx & 127;
        const size_t g = (size_t)(n0 + i) * HDIM + c;
        h1s[idx] = hV[g] + (float)dh[g] * INV_SCALE;
    }
    __syncthreads();
    ln_stats32(h1s, mu_s, rs_s, tid);
    __syncthreads();
    for (int idx = tid; idx < NT * HDIM; idx += 256) {
        const int i = idx >> 7, c = idx & 127;
        h1s[idx] = (h1s[idx] - mu_s[i]) * rs_s[i] * n1g[c] + n1b[c];
    }
    __syncthreads();
    {
        const int o = 2 * tid;
        const float2 bv = *(const float2*)(D1b + o);
        float a0[NT], a1[NT];
        #pragma unroll
        for (int i = 0; i < NT; ++i) { a0[i] = bv.x; a1[i] = bv.y; }
        for (int k = 0; k < HDIM; ++k) {
            const float2 w = *(const float2*)(D1w + (size_t)k * 512 + o);
            #pragma unroll
            for (int i = 0; i < NT; ++i) {
                const float xv = h1s[i * HDIM + k];
                a0[i] += xv * w.x; a1[i] += xv * w.y;
            }
        }
        #pragma unroll
        for (int i = 0; i < NT; ++i) {
            us[i * 512 + o]     = gelu_fast(a0[i]);
            us[i * 512 + o + 1] = gelu_fast(a1[i]);
        }
    }
    __syncthreads();
    {
        const int o = tid & 127, half = tid >> 7;
        float a[NT];
        #pragma unroll
        for (int i = 0; i < NT; ++i) a[i] = 0.f;
        const int k0 = half * 256;
        for (int k = k0; k < k0 + 256; ++k) {
            const float w = D2w[(size_t)k * HDIM + o];
            #pragma unroll
            for (int i = 0; i < NT; ++i) a[i] += us[i * 512 + k] * w;
        }
        #pragma unroll
        for (int i = 0; i < NT; ++i) vs[(half * NT + i) * HDIM + o] = a[i];
    }
    __syncthreads();
    float* ys = us;
    for (int idx = tid; idx < NT * HDIM; idx += 256) {
        const int i = idx >> 7, c = idx & 127;
        ys[idx] = h1s[idx] + vs[i * HDIM + c] + vs[(NT + i) * HDIM + c] + D2b[c];
    }
    __syncthreads();
    ln_stats32(ys, mu_s, rs_s, tid);
    __syncthreads();
    for (int idx = tid; idx < NT * HDIM; idx += 256) {
        const int i = idx >> 7, c = idx & 127;
        out[(size_t)(n0 + i) * HDIM + c] = (ys[idx] - mu_s[i]) * rs_s[i] * n2g[c] + n2b[c];
    }
}

extern "C" void kernel_launch(void* const* d_in, const int* in_sizes, int n_in,
                              void* d_out, int out_size, void* d_ws, size_t ws_size,
                              hipStream_t stream) {
    const float* hV  = (const float*)d_in[0];
    const float* hE  = (const float*)d_in[1];
    const int*  eidx = (const int*)d_in[2];
    const float* W1w = (const float*)d_in[3];
    const float* W1b = (const float*)d_in[4];
    const float* W2w = (const float*)d_in[5];
    const float* W2b = (const float*)d_in[6];
    const float* W3w = (const float*)d_in[7];
    const float* W3b = (const float*)d_in[8];
    const float* n1g = (const float*)d_in[9];
    const float* n1b = (const float*)d_in[10];
    const float* D1w = (const float*)d_in[11];
    const float* D1b = (const float*)d_in[12];
    const float* D2w = (const float*)d_in[13];
    const float* D2b = (const float*)d_in[14];
    const float* n2g = (const float*)d_in[15];
    const float* n2b = (const float*)d_in[16];
    float* out = (float*)d_out;

    // tier-1 layout: msg | WswE | D1sw | D2sw | perm | cnt | off | off2
    // (x-buffer lives in d_out: gather_sum writes it, node_mfma_x rewrites it)
    const size_t MSG_BYTES = (size_t)NEDGES * HDIM * sizeof(_Float16);  // 81,920,000
    const size_t EW_BYTES  = 65536 * 2;
    const size_t T1_BYTES  = MSG_BYTES + 3 * EW_BYTES
                           + (size_t)NEDGES * 4 + (size_t)NNODES * 4
                           + (size_t)(NNODES + 1) * 4 + (size_t)NNODES * 4;
    const size_t DH_BYTES  = (size_t)NNODES * HDIM * sizeof(_Float16);  // 5,120,000
    const size_t T2_BYTES  = DH_BYTES + 3 * EW_BYTES;

    if (ws_size >= T1_BYTES) {
        char* p = (char*)d_ws;
        _Float16* msg  = (_Float16*)p;            p += MSG_BYTES;
        ushort_t* WswE = (ushort_t*)p;            p += EW_BYTES;
        ushort_t* D1sw = (ushort_t*)p;            p += EW_BYTES;
        ushort_t* D2sw = (ushort_t*)p;            p += EW_BYTES;
        int* perm = (int*)p;                      p += (size_t)NEDGES * 4;
        int* cnt  = (int*)p;                      p += (size_t)NNODES * 4;
        int* off  = (int*)p;                      p += (size_t)(NNODES + 1) * 4;
        int* off2 = (int*)p;

        hipMemsetAsync(cnt, 0, (size_t)NNODES * 4, stream);
        prep_all<<<2019, 256, 0, stream>>>(W1w, W2w, W3w, WswE, D1w, D2w, D1sw, D2sw, eidx, cnt);
        scan_counts<<<1, 1024, 0, stream>>>(cnt, off, off2);
        fill_perm<<<(NEDGES + 255) / 256, 256, 0, stream>>>(eidx, off2, perm);
        edge_mlp_v3<<<NEDGES / 64, 256, 0, stream>>>(hE, WswE, W1b, W2b, W3b, msg);
        gather_sum<<<NNODES / 8, 256, 0, stream>>>(msg, perm, off, hV, out);
        node_mfma_x<<<NNODES / 32, 256, 0, stream>>>(out, n1g, n1b,
                                                     D1sw, D1b, D2sw, D2b, n2g, n2b, out);
    } else if (ws_size >= T2_BYTES) {
        _Float16* dh = (_Float16*)d_ws;
        ushort_t* WswE = (ushort_t*)((char*)d_ws + DH_BYTES);
        ushort_t* D1sw = (ushort_t*)((char*)d_ws + DH_BYTES + EW_BYTES);
        ushort_t* D2sw = (ushort_t*)((char*)d_ws + DH_BYTES + 2 * EW_BYTES);
        hipMemsetAsync(dh, 0, DH_BYTES, stream);
        prep_all<<<2019, 256, 0, stream>>>(W1w, W2w, W3w, WswE, D1w, D2w, D1sw, D2sw,
                                           eidx, nullptr);
        edge_mlp_mfma<<<NEDGES / 128, 256, 0, stream>>>(hE, eidx, WswE, W1b, W2b, W3b, dh);
        node_mfma<<<NNODES / 32, 256, 0, stream>>>(hV, dh, n1g, n1b, D1sw, D1b, D2sw, D2b, n2g, n2b, out);
    } else {
        _Float16* dh = (_Float16*)d_ws;
        ushort_t* WswE = (ushort_t*)((char*)d_out + (size_t)out_size * 4 - EW_BYTES);
        hipMemsetAsync(dh, 0, DH_BYTES, stream);
        prep_all<<<2019, 256, 0, stream>>>(W1w, W2w, W3w, WswE, D1w, D2w, nullptr, nullptr,
                                           eidx, nullptr);
        edge_mlp_mfma<<<NEDGES / 128, 256, 0, stream>>>(hE, eidx, WswE, W1b, W2b, W3b, dh);
        node_update_f32<<<NNODES / NT, 256, 0, stream>>>(hV, dh, n1g, n1b, D1w, D1b, D2w, D2b, n2g, n2b, out);
    }
}

// Round 7
// 553.059 us; speedup vs baseline: 1.2503x; 1.1128x over previous
//
#include <hip/hip_runtime.h>
#include <hip/hip_bf16.h>
#include <math.h>

#define NNODES 20000
#define NEDGES 320000
#define HDIM   128
#define INDIM  256
#define INV_SCALE (1.0f/30.0f)
#define LN_EPS 1e-5f

typedef __bf16 bf16x8 __attribute__((ext_vector_type(8)));
typedef float  f32x4  __attribute__((ext_vector_type(4)));
typedef _Float16 half4_t __attribute__((ext_vector_type(4)));
typedef unsigned short ushort_t;

__device__ __forceinline__ unsigned short f2bf(float f) {
    union { __hip_bfloat16 h; unsigned short u; } c;
    c.h = __float2bfloat16(f);
    return c.u;
}

// Fast gelu: x * sigmoid(1.5957691*x + 0.0713548*x^3)  (tanh-form, max |err| ~1e-3)
__device__ __forceinline__ float gelu_fast(float x) {
    const float z = x * (1.595769122f + 0.071354816f * x * x);
    return x / (1.0f + __expf(-z));
}

__device__ __forceinline__ f32x4 mfma_bf16(bf16x8 a, bf16x8 b, f32x4 c) {
    return __builtin_amdgcn_mfma_f32_16x16x32_bf16(a, b, c, 0, 0, 0);
}

#define CVT8(dst, v0, v1) { union { bf16x8 v; ushort_t u[8]; } c_; \
    c_.u[0] = f2bf((v0).x); c_.u[1] = f2bf((v0).y); c_.u[2] = f2bf((v0).z); c_.u[3] = f2bf((v0).w); \
    c_.u[4] = f2bf((v1).x); c_.u[5] = f2bf((v1).y); c_.u[6] = f2bf((v1).z); c_.u[7] = f2bf((v1).w); \
    (dst) = c_.v; }

// ---------------------------------------------------------------------------
// Weight prep only (no histogram — CSR path removed).
// B-fragment order for mfma_f32_16x16x32_bf16: frag (s,T), lane L, elem j holds
// W[k = s*32 + (L>>4)*8 + j][n], lane's 8 bf16 contiguous. Frag f at
// Wsw[(f*64+L)*8+j], f = s*8+T. W1 base 0, W2 base 32768, W3 base 49152.
//
// W3 col permutation (dword-packed atomic scatter, wave-sliced edge kernel):
// frag T, fragment col l16 -> actual col n3 = 2*((T>>1)*16 + l16) + (T&1).
// So frag pair (2u, 2u+1) = adjacent actual cols (2*(u*16+l16), +1).
// D1sw/D2sw may be nullptr (tier-3) -> node-weight part skipped.
// ---------------------------------------------------------------------------
__global__ void prep_weights(const float* __restrict__ W1, const float* __restrict__ W2,
                             const float* __restrict__ W3, ushort_t* __restrict__ WswE,
                             const float* __restrict__ D1, const float* __restrict__ D2,
                             ushort_t* __restrict__ D1sw, ushort_t* __restrict__ D2sw) {
    const int id = blockIdx.x * 256 + threadIdx.x;
    if (id < 65536) {
        const float* W; int base, idx; bool perm = false;
        if (id < 32768)      { W = W1; base = 0;     idx = id; }
        else if (id < 49152) { W = W2; base = 32768; idx = id - 32768; }
        else                 { W = W3; base = 49152; idx = id - 49152; perm = true; }
        const int j = idx & 7, lane = (idx >> 3) & 63, t = (idx >> 9) & 7, s = idx >> 12;
        const int k = s * 32 + (lane >> 4) * 8 + j;
        const int n = perm ? (2 * ((t >> 1) * 16 + (lane & 15)) + (t & 1))
                           : (t * 16 + (lane & 15));
        WswE[base + idx] = f2bf(W[k * HDIM + n]);
    } else {
        if (!D1sw) return;
        const int nid = id - 65536;   // 0..131071
        if (nid < 65536) {
            const int idx = nid;
            const int j = idx & 7, lane = (idx >> 3) & 63, f = idx >> 9;   // f = s*32+t
            const int t = f & 31, s = f >> 5;
            const int k = s * 32 + (lane >> 4) * 8 + j;
            const int n = t * 16 + (lane & 15);
            D1sw[idx] = f2bf(D1[k * 512 + n]);
        } else {
            const int idx = nid - 65536;
            const int j = idx & 7, lane = (idx >> 3) & 63, f = idx >> 9;   // f = s*8+t
            const int t = f & 7, s = f >> 3;
            const int k = s * 32 + (lane >> 4) * 8 + j;
            const int n = t * 16 + (lane & 15);
            D2sw[idx] = f2bf(D2[k * HDIM + n]);
        }
    }
}

// ---------------------------------------------------------------------------
// Edge MLP v4: v3's verified MFMA body (block = 64 edges, 4 waves, wave owns a
// 32-col slice; hE staged in two K=128 chunks, chunk-1 loads in flight across
// the first 4 K-steps; B-frags double-buffered) + packed-fp16 ATOMIC scatter
// directly into dh (2 adjacent cols per op thanks to the W3 permutation).
// No msg buffer, no CSR, no gather kernel. LDS 34.8 KB -> 4 blocks/CU.
// ---------------------------------------------------------------------------
#define A1H 136   // staging chunk row stride (bf16): 128 + 8 pad (2-way banks, free)
#define SY  136   // A2 row stride (bf16)

__launch_bounds__(256, 4)
__global__ void edge_mlp_v4(const float* __restrict__ hE,
                            const int* __restrict__ edge_idx,
                            const ushort_t* __restrict__ Wsw,
                            const float* __restrict__ b1,
                            const float* __restrict__ b2,
                            const float* __restrict__ b3,
                            _Float16* __restrict__ dh) {
    __shared__ __align__(16) ushort_t A1h[64 * A1H];  // 17408 B (K-chunk)
    __shared__ __align__(16) ushort_t A2[64 * SY];    // 17408 B

    const int tid = threadIdx.x;
    const int wave = tid >> 6, lane = tid & 63;
    const int quad = lane >> 4, l16 = lane & 15;
    const size_t e0 = (size_t)blockIdx.x * 64;
    const int T0 = wave * 2;                 // wave's two col-frags: T0, T0+1

    // staging mapping: thread = (row, quarter of 128ch chunk)
    const int srow = tid >> 2, sq = tid & 3;
    const float4* sp = (const float4*)(hE + (e0 + srow) * INDIM) + sq * 8;
    ushort_t* sd = A1h + srow * A1H + sq * 32;

    // ---- chunk0 -> regs -> LDS; chunk1 -> regs (left in flight) ----
    float4 rg[8];
    #pragma unroll
    for (int i = 0; i < 8; ++i) rg[i] = sp[i];
    #pragma unroll
    for (int i = 0; i < 4; ++i) {
        bf16x8 v; CVT8(v, rg[2 * i], rg[2 * i + 1]);
        *(bf16x8*)(sd + i * 8) = v;
    }
    #pragma unroll
    for (int i = 0; i < 8; ++i) rg[i] = sp[32 + i];   // chunk1 (ch 128..255)

    f32x4 acc[4][2];
    bf16x8 bcur[2], bnxt[2];

    #pragma unroll
    for (int t = 0; t < 2; ++t) {
        const float bv = b1[(T0 + t) * 16 + l16];
        #pragma unroll
        for (int rt = 0; rt < 4; ++rt) acc[rt][t] = (f32x4){bv, bv, bv, bv};
    }
    bcur[0] = *(const bf16x8*)(Wsw + (size_t)((T0 + 0) * 64 + lane) * 8);
    bcur[1] = *(const bf16x8*)(Wsw + (size_t)((T0 + 1) * 64 + lane) * 8);
    __syncthreads();

    // ---- L1 part A: s = 0..3 (chunk0) ----
    #pragma unroll
    for (int s = 0; s < 4; ++s) {
        bnxt[0] = *(const bf16x8*)(Wsw + (size_t)(((s + 1) * 8 + T0 + 0) * 64 + lane) * 8);
        bnxt[1] = *(const bf16x8*)(Wsw + (size_t)(((s + 1) * 8 + T0 + 1) * 64 + lane) * 8);
        bf16x8 a[4];
        #pragma unroll
        for (int rt = 0; rt < 4; ++rt)
            a[rt] = *(const bf16x8*)(A1h + (rt * 16 + l16) * A1H + s * 32 + quad * 8);
        #pragma unroll
        for (int rt = 0; rt < 4; ++rt) {
            acc[rt][0] = mfma_bf16(a[rt], bcur[0], acc[rt][0]);
            acc[rt][1] = mfma_bf16(a[rt], bcur[1], acc[rt][1]);
        }
        bcur[0] = bnxt[0]; bcur[1] = bnxt[1];
    }
    __syncthreads();   // chunk0 reads done

    // ---- write chunk1 (rg loads have had 4 K-steps to land) ----
    #pragma unroll
    for (int i = 0; i < 4; ++i) {
        bf16x8 v; CVT8(v, rg[2 * i], rg[2 * i + 1]);
        *(bf16x8*)(sd + i * 8) = v;
    }
    __syncthreads();   // chunk1 ready

    // ---- L1 part B: s = 4..7 ----
    #pragma unroll
    for (int s = 4; s < 8; ++s) {
        if (s < 7) {
            bnxt[0] = *(const bf16x8*)(Wsw + (size_t)(((s + 1) * 8 + T0 + 0) * 64 + lane) * 8);
            bnxt[1] = *(const bf16x8*)(Wsw + (size_t)(((s + 1) * 8 + T0 + 1) * 64 + lane) * 8);
        }
        bf16x8 a[4];
        #pragma unroll
        for (int rt = 0; rt < 4; ++rt)
            a[rt] = *(const bf16x8*)(A1h + (rt * 16 + l16) * A1H + (s - 4) * 32 + quad * 8);
        #pragma unroll
        for (int rt = 0; rt < 4; ++rt) {
            acc[rt][0] = mfma_bf16(a[rt], bcur[0], acc[rt][0]);
            acc[rt][1] = mfma_bf16(a[rt], bcur[1], acc[rt][1]);
        }
        bcur[0] = bnxt[0]; bcur[1] = bnxt[1];
    }
    // gelu(h1) slice -> A2
    #pragma unroll
    for (int rt = 0; rt < 4; ++rt)
        #pragma unroll
        for (int t = 0; t < 2; ++t)
            #pragma unroll
            for (int r = 0; r < 4; ++r)
                A2[(rt * 16 + quad * 4 + r) * SY + (T0 + t) * 16 + l16] =
                    f2bf(gelu_fast(acc[rt][t][r]));
    __syncthreads();

    // ---- layer 2: [64x128] x [128 x 32-slice] ----
    #pragma unroll
    for (int t = 0; t < 2; ++t) {
        const float bv = b2[(T0 + t) * 16 + l16];
        #pragma unroll
        for (int rt = 0; rt < 4; ++rt) acc[rt][t] = (f32x4){bv, bv, bv, bv};
    }
    bcur[0] = *(const bf16x8*)(Wsw + 32768 + (size_t)((T0 + 0) * 64 + lane) * 8);
    bcur[1] = *(const bf16x8*)(Wsw + 32768 + (size_t)((T0 + 1) * 64 + lane) * 8);
    #pragma unroll
    for (int s = 0; s < 4; ++s) {
        if (s < 3) {
            bnxt[0] = *(const bf16x8*)(Wsw + 32768 + (size_t)(((s + 1) * 8 + T0 + 0) * 64 + lane) * 8);
            bnxt[1] = *(const bf16x8*)(Wsw + 32768 + (size_t)(((s + 1) * 8 + T0 + 1) * 64 + lane) * 8);
        }
        bf16x8 a[4];
        #pragma unroll
        for (int rt = 0; rt < 4; ++rt)
            a[rt] = *(const bf16x8*)(A2 + (rt * 16 + l16) * SY + s * 32 + quad * 8);
        #pragma unroll
        for (int rt = 0; rt < 4; ++rt) {
            acc[rt][0] = mfma_bf16(a[rt], bcur[0], acc[rt][0]);
            acc[rt][1] = mfma_bf16(a[rt], bcur[1], acc[rt][1]);
        }
        bcur[0] = bnxt[0]; bcur[1] = bnxt[1];
    }
    __syncthreads();   // all waves' h1 reads complete before overwrite
    #pragma unroll
    for (int rt = 0; rt < 4; ++rt)
        #pragma unroll
        for (int t = 0; t < 2; ++t)
            #pragma unroll
            for (int r = 0; r < 4; ++r)
                A2[(rt * 16 + quad * 4 + r) * SY + (T0 + t) * 16 + l16] =
                    f2bf(gelu_fast(acc[rt][t][r]));
    __syncthreads();

    // ---- layer 3: PERMUTED cols; acc[.][0]/acc[.][1] = adjacent actual cols ----
    #pragma unroll
    for (int t = 0; t < 2; ++t) {
        const float bv = b3[2 * (wave * 16 + l16) + t];
        #pragma unroll
        for (int rt = 0; rt < 4; ++rt) acc[rt][t] = (f32x4){bv, bv, bv, bv};
    }
    bcur[0] = *(const bf16x8*)(Wsw + 49152 + (size_t)((T0 + 0) * 64 + lane) * 8);
    bcur[1] = *(const bf16x8*)(Wsw + 49152 + (size_t)((T0 + 1) * 64 + lane) * 8);
    #pragma unroll
    for (int s = 0; s < 4; ++s) {
        if (s < 3) {
            bnxt[0] = *(const bf16x8*)(Wsw + 49152 + (size_t)(((s + 1) * 8 + T0 + 0) * 64 + lane) * 8);
            bnxt[1] = *(const bf16x8*)(Wsw + 49152 + (size_t)(((s + 1) * 8 + T0 + 1) * 64 + lane) * 8);
        }
        bf16x8 a[4];
        #pragma unroll
        for (int rt = 0; rt < 4; ++rt)
            a[rt] = *(const bf16x8*)(A2 + (rt * 16 + l16) * SY + s * 32 + quad * 8);
        #pragma unroll
        for (int rt = 0; rt < 4; ++rt) {
            acc[rt][0] = mfma_bf16(a[rt], bcur[0], acc[rt][0]);
            acc[rt][1] = mfma_bf16(a[rt], bcur[1], acc[rt][1]);
        }
        bcur[0] = bnxt[0]; bcur[1] = bnxt[1];
    }

    // ---- packed-fp16 atomic scatter: cols (2*(wave*16+l16), +1) per row ----
    const int ccol = 2 * (wave * 16 + l16);
    #pragma unroll
    for (int rt = 0; rt < 4; ++rt)
        #pragma unroll
        for (int r = 0; r < 4; ++r) {
            const int row = (int)e0 + rt * 16 + quad * 4 + r;
            const int s = edge_idx[row];
            _Float16* dst = dh + (size_t)s * HDIM + ccol;
            union { _Float16 h[2]; unsigned int u; } pk;
            pk.h[0] = (_Float16)acc[rt][0][r];
            pk.h[1] = (_Float16)acc[rt][1][r];
            asm volatile("global_atomic_pk_add_f16 %0, %1, off"
                         :: "v"(dst), "v"(pk.u) : "memory");
        }
}

// ---------------------------------------------------------------------------
// Node update: x = hV + dh/30 (dh fp16), LN1, FFN (MFMA), LN2 -> out.
// Block = 32 nodes, 4 waves; wave w does all 32 rows for its N-slice.
// ---------------------------------------------------------------------------
__launch_bounds__(256)
__global__ void node_mfma(const float* __restrict__ hV, const _Float16* __restrict__ dh,
                          const float* __restrict__ n1g, const float* __restrict__ n1b,
                          const ushort_t* __restrict__ D1sw, const float* __restrict__ D1b,
                          const ushort_t* __restrict__ D2sw, const float* __restrict__ D2b,
                          const float* __restrict__ n2g, const float* __restrict__ n2b,
                          float* __restrict__ out) {
    __shared__ __align__(16) float xs[32 * HDIM];
    __shared__ __align__(16) ushort_t h1a[32 * SY];
    __shared__ __align__(16) ushort_t ua[32 * 520];
    __shared__ float mu_s[32], rs_s[32];

    const int tid = threadIdx.x;
    const int wave = tid >> 6, lane = tid & 63;
    const int quad = lane >> 4, l16 = lane & 15;
    const int n0 = blockIdx.x * 32;

    #pragma unroll
    for (int it = 0; it < 4; ++it) {
        const int f4 = it * 256 + tid;
        const float4 hv = ((const float4*)(hV + (size_t)n0 * HDIM))[f4];
        const half4_t dv = ((const half4_t*)(dh + (size_t)n0 * HDIM))[f4];
        ((float4*)xs)[f4] = (float4){hv.x + (float)dv[0] * INV_SCALE,
                                     hv.y + (float)dv[1] * INV_SCALE,
                                     hv.z + (float)dv[2] * INV_SCALE,
                                     hv.w + (float)dv[3] * INV_SCALE};
    }
    __syncthreads();

    {
        const int row = tid >> 3, q = tid & 7;
        float s = 0.f, s2 = 0.f;
        #pragma unroll
        for (int c = 0; c < 16; ++c) { const float v = xs[row * HDIM + q * 16 + c]; s += v; s2 += v * v; }
        #pragma unroll
        for (int o = 1; o < 8; o <<= 1) { s += __shfl_xor(s, o); s2 += __shfl_xor(s2, o); }
        if (q == 0) {
            const float m = s * (1.0f / HDIM);
            mu_s[row] = m;
            rs_s[row] = rsqrtf(s2 * (1.0f / HDIM) - m * m + LN_EPS);
        }
    }
    __syncthreads();

    #pragma unroll
    for (int it = 0; it < 2; ++it) {
        const int g = it * 256 + tid;
        const int row = g >> 4, col = (g & 15) * 8;
        const float mu = mu_s[row], rs = rs_s[row];
        union { bf16x8 v; ushort_t u[8]; } c;
        #pragma unroll
        for (int jj = 0; jj < 8; ++jj) {
            const float h1 = (xs[row * HDIM + col + jj] - mu) * rs * n1g[col + jj] + n1b[col + jj];
            c.u[jj] = f2bf(h1);
        }
        *(bf16x8*)(h1a + row * SY + col) = c.v;
    }
    __syncthreads();

    {
        f32x4 acc1[2][8];
        #pragma unroll
        for (int t = 0; t < 8; ++t) {
            const float bv = D1b[wave * 128 + t * 16 + l16];
            acc1[0][t] = (f32x4){bv, bv, bv, bv};
            acc1[1][t] = acc1[0][t];
        }
        #pragma unroll
        for (int s = 0; s < 4; ++s) {
            bf16x8 a[2];
            #pragma unroll
            for (int rt = 0; rt < 2; ++rt)
                a[rt] = *(const bf16x8*)(h1a + (rt * 16 + l16) * SY + s * 32 + quad * 8);
            #pragma unroll
            for (int t = 0; t < 8; ++t) {
                const bf16x8 b = *(const bf16x8*)(D1sw + (size_t)((s * 32 + wave * 8 + t) * 64 + lane) * 8);
                acc1[0][t] = mfma_bf16(a[0], b, acc1[0][t]);
                acc1[1][t] = mfma_bf16(a[1], b, acc1[1][t]);
            }
        }
        #pragma unroll
        for (int rt = 0; rt < 2; ++rt)
            #pragma unroll
            for (int t = 0; t < 8; ++t)
                #pragma unroll
                for (int r = 0; r < 4; ++r)
                    ua[(rt * 16 + quad * 4 + r) * 520 + wave * 128 + t * 16 + l16] =
                        f2bf(gelu_fast(acc1[rt][t][r]));
    }
    __syncthreads();

    f32x4 acc2[2][2];
    acc2[0][0] = (f32x4){0,0,0,0}; acc2[0][1] = acc2[0][0];
    acc2[1][0] = acc2[0][0];       acc2[1][1] = acc2[0][0];
    #pragma unroll
    for (int s = 0; s < 16; ++s) {
        bf16x8 a[2];
        #pragma unroll
        for (int rt = 0; rt < 2; ++rt)
            a[rt] = *(const bf16x8*)(ua + (rt * 16 + l16) * 520 + s * 32 + quad * 8);
        #pragma unroll
        for (int tt = 0; tt < 2; ++tt) {
            const bf16x8 b = *(const bf16x8*)(D2sw + (size_t)((s * 8 + wave * 2 + tt) * 64 + lane) * 8);
            acc2[0][tt] = mfma_bf16(a[0], b, acc2[0][tt]);
            acc2[1][tt] = mfma_bf16(a[1], b, acc2[1][tt]);
        }
    }
    __syncthreads();

    float* yf = (float*)ua;
    #pragma unroll
    for (int rt = 0; rt < 2; ++rt)
        #pragma unroll
        for (int tt = 0; tt < 2; ++tt)
            #pragma unroll
            for (int r = 0; r < 4; ++r) {
                const int row = rt * 16 + quad * 4 + r;
                const int col = wave * 32 + tt * 16 + l16;
                const float h1 = (xs[row * HDIM + col] - mu_s[row]) * rs_s[row] * n1g[col] + n1b[col];
                yf[row * HDIM + col] = h1 + acc2[rt][tt][r] + D2b[col];
            }
    __syncthreads();

    {
        const int row = tid >> 3, q = tid & 7;
        float s = 0.f, s2 = 0.f;
        #pragma unroll
        for (int c = 0; c < 16; ++c) { const float v = yf[row * HDIM + q * 16 + c]; s += v; s2 += v * v; }
        #pragma unroll
        for (int o = 1; o < 8; o <<= 1) { s += __shfl_xor(s, o); s2 += __shfl_xor(s2, o); }
        if (q == 0) {
            const float m = s * (1.0f / HDIM);
            mu_s[row] = m;
            rs_s[row] = rsqrtf(s2 * (1.0f / HDIM) - m * m + LN_EPS);
        }
    }
    __syncthreads();

    #pragma unroll
    for (int it = 0; it < 4; ++it) {
        const int f4 = it * 256 + tid;
        const int row = f4 >> 5, col = (f4 & 31) * 4;
        const float4 y = ((const float4*)yf)[f4];
        const float mu = mu_s[row], rs = rs_s[row];
        float4 o;
        o.x = (y.x - mu) * rs * n2g[col + 0] + n2b[col + 0];
        o.y = (y.y - mu) * rs * n2g[col + 1] + n2b[col + 1];
        o.z = (y.z - mu) * rs * n2g[col + 2] + n2b[col + 2];
        o.w = (y.w - mu) * rs * n2g[col + 3] + n2b[col + 3];
        ((float4*)(out + (size_t)n0 * HDIM))[f4] = o;
    }
}

// ---------------------------------------------------------------------------
// Tier-3 fp32 node fallback (reads dh fp16).
// ---------------------------------------------------------------------------
#define NT 8
__device__ __forceinline__ void ln_stats32(const float* __restrict__ buf,
                                           float* __restrict__ mu_s,
                                           float* __restrict__ rs_s, int tid) {
    const int g = tid >> 5, lane = tid & 31;
    float s = 0.f, s2 = 0.f;
    #pragma unroll
    for (int c = lane; c < HDIM; c += 32) { const float v = buf[g * HDIM + c]; s += v; s2 += v * v; }
    #pragma unroll
    for (int o = 16; o; o >>= 1) { s += __shfl_xor(s, o, 32); s2 += __shfl_xor(s2, o, 32); }
    if (lane == 0) {
        const float m = s * (1.0f / HDIM);
        mu_s[g] = m;
        rs_s[g] = rsqrtf(s2 * (1.0f / HDIM) - m * m + LN_EPS);
    }
}

__launch_bounds__(256)
__global__ void node_update_f32(const float* __restrict__ hV, const _Float16* __restrict__ dh,
                                const float* __restrict__ n1g, const float* __restrict__ n1b,
                                const float* __restrict__ D1w, const float* __restrict__ D1b,
                                const float* __restrict__ D2w, const float* __restrict__ D2b,
                                const float* __restrict__ n2g, const float* __restrict__ n2b,
                                float* __restrict__ out) {
    __shared__ float h1s[NT * HDIM];
    __shared__ float us[NT * 512];
    __shared__ float vs[2 * NT * HDIM];
    __shared__ float mu_s[NT], rs_s[NT];
    const int tid = threadIdx.x;
    const int n0 = blockIdx.x * NT;
    for (int idx = tid; idx < NT * HDIM; idx += 256) {
        const int i = idx >> 7, c = idx & 127;
        const size_t g = (size_t)(n0 + i) * HDIM + c;
        h1s[idx] = hV[g] + (float)dh[g] * INV_SCALE;
    }
    __syncthreads();
    ln_stats32(h1s, mu_s, rs_s, tid);
    __syncthreads();
    for (int idx = tid; idx < NT * HDIM; idx += 256) {
        const int i = idx >> 7, c = idx & 127;
        h1s[idx] = (h1s[idx] - mu_s[i]) * rs_s[i] * n1g[c] + n1b[c];
    }
    __syncthreads();
    {
        const int o = 2 * tid;
        const float2 bv = *(const float2*)(D1b + o);
        float a0[NT], a1[NT];
        #pragma unroll
        for (int i = 0; i < NT; ++i) { a0[i] = bv.x; a1[i] = bv.y; }
        for (int k = 0; k < HDIM; ++k) {
            const float2 w = *(const float2*)(D1w + (size_t)k * 512 + o);
            #pragma unroll
            for (int i = 0; i < NT; ++i) {
                const float xv = h1s[i * HDIM + k];
                a0[i] += xv * w.x; a1[i] += xv * w.y;
            }
        }
        #pragma unroll
        for (int i = 0; i < NT; ++i) {
            us[i * 512 + o]     = gelu_fast(a0[i]);
            us[i * 512 + o + 1] = gelu_fast(a1[i]);
        }
    }
    __syncthreads();
    {
        const int o = tid & 127, half = tid >> 7;
        float a[NT];
        #pragma unroll
        for (int i = 0; i < NT; ++i) a[i] = 0.f;
        const int k0 = half * 256;
        for (int k = k0; k < k0 + 256; ++k) {
            const float w = D2w[(size_t)k * HDIM + o];
            #pragma unroll
            for (int i = 0; i < NT; ++i) a[i] += us[i * 512 + k] * w;
        }
        #pragma unroll
        for (int i = 0; i < NT; ++i) vs[(half * NT + i) * HDIM + o] = a[i];
    }
    __syncthreads();
    float* ys = us;
    for (int idx = tid; idx < NT * HDIM; idx += 256) {
        const int i = idx >> 7, c = idx & 127;
        ys[idx] = h1s[idx] + vs[i * HDIM + c] + vs[(NT + i) * HDIM + c] + D2b[c];
    }
    __syncthreads();
    ln_stats32(ys, mu_s, rs_s, tid);
    __syncthreads();
    for (int idx = tid; idx < NT * HDIM; idx += 256) {
        const int i = idx >> 7, c = idx & 127;
        out[(size_t)(n0 + i) * HDIM + c] = (ys[idx] - mu_s[i]) * rs_s[i] * n2g[c] + n2b[c];
    }
}

extern "C" void kernel_launch(void* const* d_in, const int* in_sizes, int n_in,
                              void* d_out, int out_size, void* d_ws, size_t ws_size,
                              hipStream_t stream) {
    const float* hV  = (const float*)d_in[0];
    const float* hE  = (const float*)d_in[1];
    const int*  eidx = (const int*)d_in[2];
    const float* W1w = (const float*)d_in[3];
    const float* W1b = (const float*)d_in[4];
    const float* W2w = (const float*)d_in[5];
    const float* W2b = (const float*)d_in[6];
    const float* W3w = (const float*)d_in[7];
    const float* W3b = (const float*)d_in[8];
    const float* n1g = (const float*)d_in[9];
    const float* n1b = (const float*)d_in[10];
    const float* D1w = (const float*)d_in[11];
    const float* D1b = (const float*)d_in[12];
    const float* D2w = (const float*)d_in[13];
    const float* D2b = (const float*)d_in[14];
    const float* n2g = (const float*)d_in[15];
    const float* n2b = (const float*)d_in[16];
    float* out = (float*)d_out;

    // layout: dh (fp16, 5.12 MB) | WswE | D1sw | D2sw
    const size_t DH_BYTES = (size_t)NNODES * HDIM * sizeof(_Float16);   // 5,120,000
    const size_t EW_BYTES = 65536 * 2;
    const size_t T_MAIN   = DH_BYTES + 3 * EW_BYTES;

    _Float16* dh = (_Float16*)d_ws;
    hipMemsetAsync(dh, 0, DH_BYTES, stream);

    if (ws_size >= T_MAIN) {
        ushort_t* WswE = (ushort_t*)((char*)d_ws + DH_BYTES);
        ushort_t* D1sw = (ushort_t*)((char*)d_ws + DH_BYTES + EW_BYTES);
        ushort_t* D2sw = (ushort_t*)((char*)d_ws + DH_BYTES + 2 * EW_BYTES);
        prep_weights<<<768, 256, 0, stream>>>(W1w, W2w, W3w, WswE, D1w, D2w, D1sw, D2sw);
        edge_mlp_v4<<<NEDGES / 64, 256, 0, stream>>>(hE, eidx, WswE, W1b, W2b, W3b, dh);
        node_mfma<<<NNODES / 32, 256, 0, stream>>>(hV, dh, n1g, n1b, D1sw, D1b, D2sw, D2b, n2g, n2b, out);
    } else {
        // edge weights in d_out tail (node kernel rewrites all of d_out afterwards)
        ushort_t* WswE = (ushort_t*)((char*)d_out + (size_t)out_size * 4 - EW_BYTES);
        prep_weights<<<256, 256, 0, stream>>>(W1w, W2w, W3w, WswE, D1w, D2w, nullptr, nullptr);
        edge_mlp_v4<<<NEDGES / 64, 256, 0, stream>>>(hE, eidx, WswE, W1b, W2b, W3b, dh);
        node_update_f32<<<NNODES / NT, 256, 0, stream>>>(hV, dh, n1g, n1b, D1w, D1b, D2w, D2b, n2g, n2b, out);
    }
}